// Round 7
// baseline (337.838 us; speedup 1.0000x reference)
//
#include <hip/hip_runtime.h>
#include <hip/hip_bf16.h>
#include <math.h>

typedef __hip_bfloat16 bf16;
typedef __bf16 v8bf __attribute__((ext_vector_type(8)));
typedef float v4f __attribute__((ext_vector_type(4)));

#define BN_SCALE 0.9999950000374997f
#define NPTS 1024
#define NB 4
#define CH5 ((size_t)4 * 1024 * 512)   // conv5 partial-chunk stride (floats)

__device__ __forceinline__ float b2f(bf16 v) { return __bfloat162float(v); }
__device__ __forceinline__ bf16 f2b(float v) { return __float2bfloat16(v); }
__device__ __forceinline__ float ldw(const void* p, size_t i, int isf) {
    return isf ? ((const float*)p)[i] : b2f(((const bf16*)p)[i]);
}
__device__ __forceinline__ unsigned ordf(float f) {
    unsigned u = __float_as_uint(f);
    return (u & 0x80000000u) ? ~u : (u | 0x80000000u);
}
__device__ __forceinline__ float iordf(unsigned u) {
    return (u & 0x80000000u) ? __uint_as_float(u ^ 0x80000000u) : __uint_as_float(~u);
}

// per-block dtype detect from first 512 shorts of x (fp32 ~113/256 implausible, bf16 ~0)
__device__ __forceinline__ int detect_isf(const void* xraw, int* cnt) {
    const unsigned short* u = (const unsigned short*)xraw;
    int t = threadIdx.x, c = 0;
    for (int i = t; i < 512; i += 256) {
        unsigned short v = u[i];
        int e = (v >> 7) & 0xFF;
        int m = v & 0x7F;
        if (e == 0xFF || e >= 141 || (e == 0 && m != 0)) c++;
    }
    cnt[t] = c;
    __syncthreads();
    for (int off = 128; off > 0; off >>= 1) {
        if (t < off) cnt[t] += cnt[t + off];
        __syncthreads();
    }
    int isf = (cnt[0] > 30) ? 1 : 0;
    __syncthreads();
    return isf;
}

// ---------------- fused prep: dtype flag + pooled init + weight splits + x pad + sq ----------------
__global__ void k_prep(const void* __restrict__ W1, const void* __restrict__ W2,
                       const void* __restrict__ W3, const void* __restrict__ W4,
                       const void* __restrict__ W5, const void* __restrict__ x,
                       bf16* __restrict__ Whi, bf16* __restrict__ Wlo,
                       bf16* __restrict__ xph, bf16* __restrict__ xpl, float* __restrict__ sq,
                       int* __restrict__ flag, unsigned* __restrict__ pooledU) {
    __shared__ int cnt[256];
    int isf = detect_isf(x, cnt);
    if (blockIdx.x == 0) {
        if (threadIdx.x == 0) *flag = isf;
        for (int i = threadIdx.x; i < 2048; i += 256) pooledU[i] = 0u;  // 0 < ordf(any finite)
    }
    int idx = blockIdx.x * 256 + threadIdx.x;
    if (idx < 839680) {
        const void* src; int C, O, Kpad, two, local;
        if (idx < 4096)        { src = W1; C = 3;   O = 64;  Kpad = 32;  two = 1; local = idx; }
        else if (idx < 20480)  { src = W2; C = 64;  O = 128; Kpad = 64;  two = 1; local = idx - 4096; }
        else if (idx < 86016)  { src = W3; C = 128; O = 256; Kpad = 128; two = 1; local = idx - 20480; }
        else if (idx < 348160) { src = W4; C = 256; O = 512; Kpad = 256; two = 1; local = idx - 86016; }
        else                   { src = W5; C = 960; O = 512; Kpad = 960; two = 0; local = idx - 348160; }
        int r = local / Kpad, c = local % Kpad;
        float wv = 0.f;
        if (c < C) {
            size_t off;
            if (two) off = (r < O) ? (size_t)r * 2 * C + c : (size_t)(r - O) * 2 * C + C + c;
            else     off = (size_t)r * C + c;
            wv = ldw(src, off, isf);
        }
        bf16 h = f2b(wv);
        Whi[idx] = h;
        Wlo[idx] = f2b(wv - b2f(h));
    } else if (idx < 843776) {
        int p = idx - 839680;       // point index: z*1024 + n
        int z = p >> 10, n = p & 1023;
        bf16* ph = xph + (size_t)z * NPTS * 32;
        bf16* pl = xpl + (size_t)z * NPTS * 32;
        float s = 0.f;
        for (int c = 0; c < 32; c++) {
            float v = (c < 3) ? ldw(x, (size_t)z * NPTS * 3 + n * 3 + c, isf) : 0.f;
            bf16 h = f2b(v);
            ph[n * 32 + c] = h;
            pl[n * 32 + c] = f2b(v - b2f(h));
            s += v * v;
        }
        sq[z * NPTS + n] = s;
    }
}

// ---- conflict-free LDS layout: k-quad-major [kq][row][8] 16B units, XOR-swizzled ----
// unit U holds (plane = U>>7, row = (U&127)^(plane<<1)); reads conflict-free (16 consecutive
// units per quad). Staged via global_load_lds: LDS dest linear (wave base + lane*16), the
// per-lane GLOBAL source is pre-swizzled to the (plane,row) owning that unit (HK pattern).
__device__ __forceinline__ int lidx(int plane, int row) {
    return ((((plane << 7) | row)) ^ (plane << 1)) << 3;
}
#define GLDS(gp, lp) __builtin_amdgcn_global_load_lds( \
    (const __attribute__((address_space(1))) void*)(gp), \
    (__attribute__((address_space(3))) void*)(lp), 16, 0, 0)
// fill a 128x32 bf16 tile (rows stride ld) into LDS [4][128][8] via direct-to-LDS DMA
__device__ __forceinline__ void fill128(bf16* dst, const bf16* src, int ld) {
    int t = threadIdx.x;
    int w64 = t & ~63;                 // wave-uniform base lane-block
#pragma unroll
    for (int c = 0; c < 2; c++) {
        int unit = c * 256 + t;
        int kq = unit >> 7;
        int row = (unit & 127) ^ (kq << 1);
        GLDS(src + (size_t)row * ld + kq * 8, dst + (size_t)(c * 256 + w64) * 8);
    }
}
// MFMA fragment: sub-tile 'sub' (16 rows of 128), lane l: row=sub*16+(l&15), k=(l>>4)*8..+7
__device__ __forceinline__ v8bf ldf(const bf16* tile, int sub, int l) {
    return *(const v8bf*)(tile + lidx(l >> 4, sub * 16 + (l & 15)));
}

// ---------------- fused layer stage A: dist (upper-tri 128x128 tiles) + st ----------------
// 1D grid, XCD-pinned: z = (i>>1)&3, bi = ((i>>3)<<1)|(i&1)  (batch z -> XCDs {2z,2z+1})
// 128x128 output tile, 4 waves in 2x2, each wave 64x64 (acc[4][4])
__global__ __launch_bounds__(256) void k_layer_a(const bf16* __restrict__ Xhi, const bf16* __restrict__ Xlo,
                                                 int ld, int Kpad, size_t xstride,
                                                 const bf16* __restrict__ Whi, const bf16* __restrict__ Wlo,
                                                 int O, const float* __restrict__ sqg,
                                                 float* __restrict__ Dg, float* __restrict__ Pg,
                                                 const int* __restrict__ flag) {
    int i = blockIdx.x;
    int z = (i >> 1) & 3;
    int bi = ((i >> 3) << 1) | (i & 1);
    const bf16* Xh = Xhi + (size_t)z * xstride;
    const bf16* Xl = Xlo + (size_t)z * xstride;
    __shared__ alignas(16) bf16 Ah[4096], Al[4096], Bh[4096], Bl[4096];
    int w = threadIdx.x >> 6, l = threadIdx.x & 63;
    int wr = w >> 1, wc = w & 1;
    int quad = l >> 4, col = l & 15;
    v4f zero = {0.f, 0.f, 0.f, 0.f};
    v4f acc[4][4] = {{zero, zero, zero, zero}, {zero, zero, zero, zero},
                     {zero, zero, zero, zero}, {zero, zero, zero, zero}};

    if (bi < 36) {
        // ---- dist tile: triangular decode over 8x8, bx >= by ----
        int bx = 0;
        while ((((bx + 1) * (bx + 2)) >> 1) <= bi) bx++;
        int by = bi - ((bx * (bx + 1)) >> 1);
        const float* sq = sqg + z * NPTS;
        float* D = Dg + (size_t)z * NPTS * NPTS;
        int n0 = by * 128, m0 = bx * 128;
        for (int k0 = 0; k0 < Kpad; k0 += 32) {
            __syncthreads();
            fill128(Ah, Xh + (size_t)n0 * ld + k0, ld);
            fill128(Bh, Xh + (size_t)m0 * ld + k0, ld);
            fill128(Al, Xl + (size_t)n0 * ld + k0, ld);
            fill128(Bl, Xl + (size_t)m0 * ld + k0, ld);
            __syncthreads();
            v8bf ah[4], al[4];
#pragma unroll
            for (int mi = 0; mi < 4; mi++) {
                ah[mi] = ldf(Ah, wr * 4 + mi, l);
                al[mi] = ldf(Al, wr * 4 + mi, l);
            }
#pragma unroll
            for (int ni = 0; ni < 4; ni++) {
                v8bf bh = ldf(Bh, wc * 4 + ni, l);
                v8bf bl = ldf(Bl, wc * 4 + ni, l);
#pragma unroll
                for (int mi = 0; mi < 4; mi++) {
                    acc[mi][ni] = __builtin_amdgcn_mfma_f32_16x16x32_bf16(ah[mi], bh, acc[mi][ni], 0, 0, 0);
                    acc[mi][ni] = __builtin_amdgcn_mfma_f32_16x16x32_bf16(ah[mi], bl, acc[mi][ni], 0, 0, 0);
                    acc[mi][ni] = __builtin_amdgcn_mfma_f32_16x16x32_bf16(al[mi], bh, acc[mi][ni], 0, 0, 0);
                }
            }
        }
        int rb = n0 + wr * 64 + quad * 4;
        int cb = m0 + wc * 64 + col;
        float sm[4];
#pragma unroll
        for (int ni = 0; ni < 4; ni++) sm[ni] = sq[cb + ni * 16];
#pragma unroll
        for (int mi = 0; mi < 4; mi++) {
#pragma unroll
            for (int r = 0; r < 4; r++) {
                int row = rb + mi * 16 + r;
                float sn = sq[row];
#pragma unroll
                for (int ni = 0; ni < 4; ni++) {
                    float d = 2.f * acc[mi][ni][r] - sn - sm[ni];
                    int c = cb + ni * 16;
                    D[(size_t)row * NPTS + c] = d;
                    if (bx != by) D[(size_t)c * NPTS + row] = d;
                }
            }
        }
    } else {
        // ---- st tile: P[point m, weight-row n] over 2O cols ----
        int isf = *flag;
        int nCol = (2 * O) >> 7;
        int s = bi - 36;
        int n0 = (s % nCol) * 128;   // weight-row tile (over 2O)
        int m0 = (s / nCol) * 128;   // point tile (over 1024)
        int N2 = 2 * O;
        float* P = Pg + (size_t)z * NPTS * N2;
        for (int k0 = 0; k0 < Kpad; k0 += 32) {
            __syncthreads();
            fill128(Ah, Xh + (size_t)m0 * ld + k0, ld);
            fill128(Al, Xl + (size_t)m0 * ld + k0, ld);
            fill128(Bh, Whi + (size_t)n0 * Kpad + k0, Kpad);
            if (isf) fill128(Bl, Wlo + (size_t)n0 * Kpad + k0, Kpad);
            __syncthreads();
            v8bf ah[4], al[4];
#pragma unroll
            for (int mi = 0; mi < 4; mi++) {
                ah[mi] = ldf(Ah, wr * 4 + mi, l);
                al[mi] = ldf(Al, wr * 4 + mi, l);
            }
#pragma unroll
            for (int ni = 0; ni < 4; ni++) {
                v8bf bh = ldf(Bh, wc * 4 + ni, l);
#pragma unroll
                for (int mi = 0; mi < 4; mi++) {
                    acc[mi][ni] = __builtin_amdgcn_mfma_f32_16x16x32_bf16(ah[mi], bh, acc[mi][ni], 0, 0, 0);
                    acc[mi][ni] = __builtin_amdgcn_mfma_f32_16x16x32_bf16(al[mi], bh, acc[mi][ni], 0, 0, 0);
                }
                if (isf) {
                    v8bf bl = ldf(Bl, wc * 4 + ni, l);
#pragma unroll
                    for (int mi = 0; mi < 4; mi++)
                        acc[mi][ni] = __builtin_amdgcn_mfma_f32_16x16x32_bf16(ah[mi], bl, acc[mi][ni], 0, 0, 0);
                }
            }
        }
        int rb = m0 + wr * 64 + quad * 4;
        int cb = n0 + wc * 64 + col;
#pragma unroll
        for (int mi = 0; mi < 4; mi++)
#pragma unroll
            for (int r = 0; r < 4; r++) {
                int row = rb + mi * 16 + r;
#pragma unroll
                for (int ni = 0; ni < 4; ni++)
                    P[(size_t)row * N2 + cb + ni * 16] = acc[mi][ni][r];
            }
    }
}

// ---- argmax combine steps: (max val, min idx) is associative+commutative ----
template<int PAT>
__device__ __forceinline__ void swz_step(float& bv, int& bi) {
    float ov = __int_as_float(__builtin_amdgcn_ds_swizzle(__float_as_int(bv), PAT));
    int   oi = __builtin_amdgcn_ds_swizzle(bi, PAT);
    if (ov > bv || (ov == bv && oi < bi)) { bv = ov; bi = oi; }
}
__device__ __forceinline__ void shfl_step(float& bv, int& bi, int mask) {
    float ov = __shfl_xor(bv, mask);
    int   oi = __shfl_xor(bi, mask);
    if (ov > bv || (ov == bv && oi < bi)) { bv = ov; bi = oi; }
}
#define PICK(va, ja, vb, jb, vo, jo) { bool t_ = (vb) > (va); vo = t_ ? (vb) : (va); jo = t_ ? (jb) : (ja); }

// ---------------- fused stage B: top-20 (wave per row, 4 rows/block) + gather-max ----------------
// 1D grid 1024, XCD-pinned: z = (i>>1)&3, local = ((i>>3)<<1)|(i&1); rows local*4+q (wave q)
// Selection: group-cached argmax; outcome identical to full rescan. Gather: wave-uniform row
// offsets hoisted to SGPRs; affine/lrelu after max (exact FP-monotone commute).
__global__ __launch_bounds__(256) void k_layer_b(const float* __restrict__ Dg, const float* __restrict__ Pg,
                                                 const void* __restrict__ g, const void* __restrict__ bias,
                                                 int O, bf16* __restrict__ xhOut, bf16* __restrict__ xlOut,
                                                 float* __restrict__ sqOut, int writeSq,
                                                 const int* __restrict__ flag) {
    __shared__ int ids[4][20];
    __shared__ float sqP[4][8];
    int isf = *flag;
    int i = blockIdx.x;
    int z = (i >> 1) & 3;
    int local = ((i >> 3) << 1) | (i & 1);
    int tid = threadIdx.x;
    int wq = tid >> 6, l = tid & 63;
    int row = local * 4 + wq;

    // ---- per-wave register-resident top-20 (lane->index map bi = jj*256+l*4+q bijective
    //      over [0,1024), monotone per lane in scan order -> min-index tie-break) ----
    {
        const float* Dr = Dg + (size_t)z * NPTS * NPTS + (size_t)row * NPTS;
        float v[16];
#pragma unroll
        for (int jj = 0; jj < 4; jj++) {
            float4 f4 = *(const float4*)(Dr + jj * 256 + l * 4);
            v[jj * 4 + 0] = f4.x; v[jj * 4 + 1] = f4.y;
            v[jj * 4 + 2] = f4.z; v[jj * 4 + 3] = f4.w;
        }
        float bmv[4]; int bmj[4];
#pragma unroll
        for (int gg = 0; gg < 4; gg++) {
            float a0, a1; int j0, j1;
            PICK(v[4 * gg + 0], 4 * gg + 0, v[4 * gg + 1], 4 * gg + 1, a0, j0);
            PICK(v[4 * gg + 2], 4 * gg + 2, v[4 * gg + 3], 4 * gg + 3, a1, j1);
            PICK(a0, j0, a1, j1, bmv[gg], bmj[gg]);
        }
        for (int s = 0; s < 20; s++) {
            float t0, t1, bv; int s0, s1, bj;
            PICK(bmv[0], bmj[0], bmv[1], bmj[1], t0, s0);
            PICK(bmv[2], bmj[2], bmv[3], bmj[3], t1, s1);
            PICK(t0, s0, t1, s1, bv, bj);
            int bi = (bj >> 2) * 256 + l * 4 + (bj & 3);
            swz_step<0x041F>(bv, bi);   // xor 1
            swz_step<0x081F>(bv, bi);   // xor 2
            swz_step<0x101F>(bv, bi);   // xor 4
            swz_step<0x201F>(bv, bi);   // xor 8
            swz_step<0x401F>(bv, bi);   // xor 16
            shfl_step(bv, bi, 32);      // xor 32 -> all 64 lanes converged
            if (l == 0) ids[wq][s] = bi;
            if (((bi >> 2) & 63) == l) {               // owning lane: evict + rebuild its group
                int ej = (bi >> 8) * 4 + (bi & 3);
                int eg = ej >> 2, ek = ej & 3;
#pragma unroll
                for (int gg = 0; gg < 4; gg++) if (gg == eg) {
#pragma unroll
                    for (int kk = 0; kk < 4; kk++)
                        if (kk == ek) v[4 * gg + kk] = -__builtin_inff();
                    float a0, a1; int j0, j1;
                    PICK(v[4 * gg + 0], 4 * gg + 0, v[4 * gg + 1], 4 * gg + 1, a0, j0);
                    PICK(v[4 * gg + 2], 4 * gg + 2, v[4 * gg + 3], 4 * gg + 3, a1, j1);
                    PICK(a0, j0, a1, j1, bmv[gg], bmj[gg]);
                }
            }
        }
    }
    __syncthreads();

    // ---- gather + max (affine/lrelu AFTER max: exact FP-monotone commute) ----
    int N2 = 2 * O;
    const float* P = Pg + (size_t)z * NPTS * N2;
#pragma unroll
    for (int r = 0; r < 4; r++) {
        int offj[20];
#pragma unroll
        for (int j = 0; j < 20; j++)
            offj[j] = __builtin_amdgcn_readfirstlane(ids[r][j]) * N2;  // SGPR row bases
        int n = local * 4 + r;
        const float* Pn = P + (size_t)n * N2;
        for (int o = tid; o < O; o += 256) {
            float tv = Pn[O + o] - Pn[o];
            float mx = -__builtin_inff(), mn = __builtin_inff();
#pragma unroll
            for (int j = 0; j < 20; j++) {
                float vv = P[offj[j] + o];
                mx = fmaxf(mx, vv);
                mn = fminf(mn, vv);
            }
            float scl = ldw(g, o, isf) * BN_SCALE;
            float bb = ldw(bias, o, isf);
            float base = (scl >= 0.f ? mx : mn) + tv;
            float acc = base * scl + bb;
            acc = acc > 0.f ? acc : 0.2f * acc;
            bf16 hi = f2b(acc);
            bf16 lo = f2b(acc - b2f(hi));
            xhOut[(size_t)z * NPTS * 960 + (size_t)n * 960 + o] = hi;
            xlOut[(size_t)z * NPTS * 960 + (size_t)n * 960 + o] = lo;
            if (writeSq) {
                float xv = b2f(hi) + b2f(lo);
                float s2 = xv * xv;
#pragma unroll
                for (int off = 32; off > 0; off >>= 1) s2 += __shfl_down(s2, off);
                if (l == 0) sqP[r][o >> 6] = s2;   // o>>6 wave-uniform: fixed chunk slot
            }
        }
    }
    if (writeSq) {
        __syncthreads();
        if (tid < 4) {
            int nc = O >> 6;
            float tot = 0.f;
            for (int c = 0; c < nc; c++) tot += sqP[tid][c];
            sqOut[z * NPTS + local * 4 + tid] = tot;
        }
    }
}

// ---------------- conv5 via MFMA, K-split x6 (chunks of 160) -> f32 partials ----------------
// 1D grid 768, XCD-pinned: z=(i>>1)&3, rest=((i>>3)<<1)|(i&1) in [0,192):
//   ks = rest>>5 (K-chunk), tile = rest&31: m0=(tile>>2)*128, o0=(tile&3)*128
__global__ __launch_bounds__(256) void k_conv5(const bf16* __restrict__ Xhi, const bf16* __restrict__ Xlo,
                                               const bf16* __restrict__ Whi, const bf16* __restrict__ Wlo,
                                               float* __restrict__ P5,
                                               const int* __restrict__ flag) {
    int isf = *flag;
    int i = blockIdx.x;
    int z = (i >> 1) & 3;
    int rest = ((i >> 3) << 1) | (i & 1);
    int ks = rest >> 5;
    int tile = rest & 31;
    int m0 = (tile >> 2) * 128, o0 = (tile & 3) * 128;
    const bf16* Xh = Xhi + (size_t)z * NPTS * 960;
    const bf16* Xl = Xlo + (size_t)z * NPTS * 960;
    __shared__ alignas(16) bf16 Ah[4096], Al[4096], Bh[4096], Bl[4096];
    int w = threadIdx.x >> 6, l = threadIdx.x & 63;
    int wr = w >> 1, wc = w & 1;
    int quad = l >> 4, col = l & 15;
    v4f zero = {0.f, 0.f, 0.f, 0.f};
    v4f acc[4][4] = {{zero, zero, zero, zero}, {zero, zero, zero, zero},
                     {zero, zero, zero, zero}, {zero, zero, zero, zero}};
    int kbeg = ks * 160, kend = kbeg + 160;
    for (int k0 = kbeg; k0 < kend; k0 += 32) {
        __syncthreads();
        fill128(Ah, Xh + (size_t)m0 * 960 + k0, 960);
        fill128(Al, Xl + (size_t)m0 * 960 + k0, 960);
        fill128(Bh, Whi + (size_t)o0 * 960 + k0, 960);
        if (isf) fill128(Bl, Wlo + (size_t)o0 * 960 + k0, 960);
        __syncthreads();
        v8bf ah[4], al[4];
#pragma unroll
        for (int mi = 0; mi < 4; mi++) {
            ah[mi] = ldf(Ah, wr * 4 + mi, l);
            al[mi] = ldf(Al, wr * 4 + mi, l);
        }
#pragma unroll
        for (int ni = 0; ni < 4; ni++) {
            v8bf bh = ldf(Bh, wc * 4 + ni, l);
#pragma unroll
            for (int mi = 0; mi < 4; mi++) {
                acc[mi][ni] = __builtin_amdgcn_mfma_f32_16x16x32_bf16(ah[mi], bh, acc[mi][ni], 0, 0, 0);
                acc[mi][ni] = __builtin_amdgcn_mfma_f32_16x16x32_bf16(al[mi], bh, acc[mi][ni], 0, 0, 0);
            }
            if (isf) {
                v8bf bl = ldf(Bl, wc * 4 + ni, l);
#pragma unroll
                for (int mi = 0; mi < 4; mi++)
                    acc[mi][ni] = __builtin_amdgcn_mfma_f32_16x16x32_bf16(ah[mi], bl, acc[mi][ni], 0, 0, 0);
            }
        }
    }
    // write f32 partial tile (disjoint per (ks,z,tile) -> no atomics)
    float* Pw = P5 + (size_t)ks * CH5 + (size_t)z * NPTS * 512;
    int rb = m0 + wr * 64 + quad * 4;
    int cb = o0 + wc * 64 + col;
#pragma unroll
    for (int mi = 0; mi < 4; mi++)
#pragma unroll
        for (int r = 0; r < 4; r++) {
            int row = rb + mi * 16 + r;
#pragma unroll
            for (int ni = 0; ni < 4; ni++)
                Pw[(size_t)row * 512 + cb + ni * 16] = acc[mi][ni][r];
        }
}

// ---------------- pool5: sum 6 K-chunks + affine + lrelu + max over rows -> pooled ----------------
// 1D grid 512, XCD-pinned: z=(i>>1)&3, rest=((i>>3)<<1)|(i&1) in [0,128):
//   oc=(rest&3)*128 cols, mc=(rest>>2)*32 rows; thread: col=t&127, half=t>>7 (16 rows each)
__global__ __launch_bounds__(256) void k_pool5(const float* __restrict__ P5,
                                               const void* __restrict__ g, const void* __restrict__ bias,
                                               unsigned* __restrict__ pooledU,
                                               const int* __restrict__ flag) {
    __shared__ float red2[128];
    int isf = *flag;
    int i = blockIdx.x;
    int z = (i >> 1) & 3;
    int rest = ((i >> 3) << 1) | (i & 1);
    int oc = (rest & 3) * 128, mc = (rest >> 2) * 32;
    int t = threadIdx.x;
    int c = t & 127, h = t >> 7;
    int o = oc + c;
    float scl = ldw(g, o, isf) * BN_SCALE;
    float bb = ldw(bias, o, isf);
    const float* p0 = P5 + (size_t)z * NPTS * 512 + (size_t)(mc + h * 16) * 512 + o;
    float ym = -__builtin_inff();
    for (int r = 0; r < 16; r++) {
        const float* p = p0 + (size_t)r * 512;
        float s = p[0];
#pragma unroll
        for (int ks = 1; ks < 6; ks++) s += p[(size_t)ks * CH5];
        float v = s * scl + bb;
        v = v > 0.f ? v : 0.2f * v;
        ym = fmaxf(ym, v);
    }
    if (h == 1) red2[c] = ym;
    __syncthreads();
    if (h == 0) {
        float m = fmaxf(ym, red2[c]);
        atomicMax(&pooledU[z * 512 + o], ordf(m));
    }
}

// ---------------- final linear: coalesced wave-per-output ----------------
__global__ void k_final(const unsigned* __restrict__ pooledU, const void* __restrict__ We,
                        void* __restrict__ out, const int* __restrict__ flag) {
    __shared__ float p[512];
    int isf = *flag;
    int b = blockIdx.x >> 2, fb = blockIdx.x & 3;
    int t = threadIdx.x, w = t >> 6, l = t & 63;
    for (int i = t; i < 512; i += 256) p[i] = iordf(pooledU[b * 512 + i]);
    __syncthreads();
    for (int it = 0; it < 16; it++) {
        int f = fb * 64 + w * 16 + it;
        float s = 0.f;
        size_t base = (size_t)f * 512 + l * 8;
#pragma unroll
        for (int j = 0; j < 8; j++) s += p[l * 8 + j] * ldw(We, base + j, isf);
#pragma unroll
        for (int off = 32; off > 0; off >>= 1) s += __shfl_down(s, off);
        if (l == 0) {
            if (isf) ((float*)out)[b * 256 + f] = s;
            else     ((bf16*)out)[b * 256 + f] = f2b(s);
        }
    }
}

extern "C" void kernel_launch(void* const* d_in, const int* in_sizes, int n_in,
                              void* d_out, int out_size, void* d_ws, size_t ws_size,
                              hipStream_t stream) {
    const void* x  = d_in[0];
    const void* Wl[4] = { d_in[1], d_in[4], d_in[7], d_in[10] };
    const void* gl[4] = { d_in[2], d_in[5], d_in[8], d_in[11] };
    const void* bl[4] = { d_in[3], d_in[6], d_in[9], d_in[12] };
    const void* W5 = d_in[13];
    const void* g5 = d_in[14];
    const void* b5 = d_in[15];
    const void* We = d_in[16];

    // workspace layout (bytes), ~101.5 MB total (ws ~256 MiB per round-9 fill evidence)
    char* base = (char*)d_ws;
    bf16*     xc_hi   = (bf16*)(base);                  // 7,864,320
    bf16*     xc_lo   = (bf16*)(base + 7864320);        // 7,864,320
    bf16*     xpadh   = (bf16*)(base + 15728640);       // 262,144
    bf16*     xpadl   = (bf16*)(base + 15990784);       // 262,144
    float*    Dbuf    = (float*)(base + 16252928);      // 16,777,216
    float*    Pbuf    = (float*)(base + 33030144);      // 16,777,216
    bf16*     Whi     = (bf16*)(base + 49807360);       // 1,679,360
    bf16*     Wlo     = (bf16*)(base + 51486720);       // 1,679,360
    unsigned* pooledU = (unsigned*)(base + 53493760);   // 8,192
    float*    sq      = (float*)(base + 53501952);      // 16,384
    int*      flag    = (int*)(base + 53518336);        // 4
    float*    P5      = (float*)(base + 53520384);      // 50,331,648 (6 x 8 MB conv5 partials)

    const int Kpad[4]   = { 32, 64, 128, 256 };
    const int Os[4]     = { 64, 128, 256, 512 };
    const int Woff[5]   = { 0, 4096, 20480, 86016, 348160 };
    const int colIn[4]  = { 0, 0, 64, 192 };
    const int colOut[4] = { 0, 64, 192, 448 };

    k_prep<<<3296, 256, 0, stream>>>(Wl[0], Wl[1], Wl[2], Wl[3], W5, x,
                                     Whi, Wlo, xpadh, xpadl, sq, flag, pooledU);

    for (int l = 0; l < 4; l++) {
        int O = Os[l];
        int nCol = (2 * O) >> 7;
        int nBlk = 36 + 8 * nCol;  // 44/52/68/100 -> *4 divisible by 8 for XCD decode
        const bf16* Xh = (l == 0) ? xpadh : (xc_hi + colIn[l]);
        const bf16* Xl = (l == 0) ? xpadl : (xc_lo + colIn[l]);
        int ld = (l == 0) ? 32 : 960;
        size_t xstr = (l == 0) ? (size_t)NPTS * 32 : (size_t)NPTS * 960;
        k_layer_a<<<nBlk * NB, 256, 0, stream>>>(
            Xh, Xl, ld, Kpad[l], xstr, Whi + Woff[l], Wlo + Woff[l], O, sq, Dbuf, Pbuf, flag);
        k_layer_b<<<NPTS * NB / 4, 256, 0, stream>>>(
            Dbuf, Pbuf, gl[l], bl[l], O, xc_hi + colOut[l], xc_lo + colOut[l], sq, l < 3, flag);
    }
    k_conv5<<<768, 256, 0, stream>>>(xc_hi, xc_lo, Whi + Woff[4], Wlo + Woff[4], P5, flag);
    k_pool5<<<512, 256, 0, stream>>>(P5, g5, b5, pooledU, flag);
    k_final<<<16, 256, 0, stream>>>(pooledU, We, d_out, flag);
}

// Round 8
// 327.875 us; speedup vs baseline: 1.0304x; 1.0304x over previous
//
#include <hip/hip_runtime.h>
#include <hip/hip_bf16.h>
#include <math.h>

typedef __hip_bfloat16 bf16;
typedef __bf16 v8bf __attribute__((ext_vector_type(8)));
typedef float v4f __attribute__((ext_vector_type(4)));

#define BN_SCALE 0.9999950000374997f
#define NPTS 1024
#define NB 4
#define CH5 ((size_t)4 * 1024 * 512)   // conv5 partial-chunk stride (floats)

__device__ __forceinline__ float b2f(bf16 v) { return __bfloat162float(v); }
__device__ __forceinline__ bf16 f2b(float v) { return __float2bfloat16(v); }
__device__ __forceinline__ float ldw(const void* p, size_t i, int isf) {
    return isf ? ((const float*)p)[i] : b2f(((const bf16*)p)[i]);
}
__device__ __forceinline__ unsigned ordf(float f) {
    unsigned u = __float_as_uint(f);
    return (u & 0x80000000u) ? ~u : (u | 0x80000000u);
}
__device__ __forceinline__ float iordf(unsigned u) {
    return (u & 0x80000000u) ? __uint_as_float(u ^ 0x80000000u) : __uint_as_float(~u);
}

// per-block dtype detect from first 512 shorts of x (fp32 ~113/256 implausible, bf16 ~0)
__device__ __forceinline__ int detect_isf(const void* xraw, int* cnt) {
    const unsigned short* u = (const unsigned short*)xraw;
    int t = threadIdx.x, c = 0;
    for (int i = t; i < 512; i += 256) {
        unsigned short v = u[i];
        int e = (v >> 7) & 0xFF;
        int m = v & 0x7F;
        if (e == 0xFF || e >= 141 || (e == 0 && m != 0)) c++;
    }
    cnt[t] = c;
    __syncthreads();
    for (int off = 128; off > 0; off >>= 1) {
        if (t < off) cnt[t] += cnt[t + off];
        __syncthreads();
    }
    int isf = (cnt[0] > 30) ? 1 : 0;
    __syncthreads();
    return isf;
}

// ---------------- fused prep: dtype flag + pooled init + weight splits + x pad + sq ----------------
__global__ void k_prep(const void* __restrict__ W1, const void* __restrict__ W2,
                       const void* __restrict__ W3, const void* __restrict__ W4,
                       const void* __restrict__ W5, const void* __restrict__ x,
                       bf16* __restrict__ Whi, bf16* __restrict__ Wlo,
                       bf16* __restrict__ xph, bf16* __restrict__ xpl, float* __restrict__ sq,
                       int* __restrict__ flag, unsigned* __restrict__ pooledU) {
    __shared__ int cnt[256];
    int isf = detect_isf(x, cnt);
    if (blockIdx.x == 0) {
        if (threadIdx.x == 0) *flag = isf;
        for (int i = threadIdx.x; i < 2048; i += 256) pooledU[i] = 0u;  // 0 < ordf(any finite)
    }
    int idx = blockIdx.x * 256 + threadIdx.x;
    if (idx < 839680) {
        const void* src; int C, O, Kpad, two, local;
        if (idx < 4096)        { src = W1; C = 3;   O = 64;  Kpad = 32;  two = 1; local = idx; }
        else if (idx < 20480)  { src = W2; C = 64;  O = 128; Kpad = 64;  two = 1; local = idx - 4096; }
        else if (idx < 86016)  { src = W3; C = 128; O = 256; Kpad = 128; two = 1; local = idx - 20480; }
        else if (idx < 348160) { src = W4; C = 256; O = 512; Kpad = 256; two = 1; local = idx - 86016; }
        else                   { src = W5; C = 960; O = 512; Kpad = 960; two = 0; local = idx - 348160; }
        int r = local / Kpad, c = local % Kpad;
        float wv = 0.f;
        if (c < C) {
            size_t off;
            if (two) off = (r < O) ? (size_t)r * 2 * C + c : (size_t)(r - O) * 2 * C + C + c;
            else     off = (size_t)r * C + c;
            wv = ldw(src, off, isf);
        }
        bf16 h = f2b(wv);
        Whi[idx] = h;
        Wlo[idx] = f2b(wv - b2f(h));
    } else if (idx < 843776) {
        int p = idx - 839680;       // point index: z*1024 + n
        int z = p >> 10, n = p & 1023;
        bf16* ph = xph + (size_t)z * NPTS * 32;
        bf16* pl = xpl + (size_t)z * NPTS * 32;
        float s = 0.f;
        for (int c = 0; c < 32; c++) {
            float v = (c < 3) ? ldw(x, (size_t)z * NPTS * 3 + n * 3 + c, isf) : 0.f;
            bf16 h = f2b(v);
            ph[n * 32 + c] = h;
            pl[n * 32 + c] = f2b(v - b2f(h));
            s += v * v;
        }
        sq[z * NPTS + n] = s;
    }
}

// ---- conflict-free LDS layout: k-quad-major [kq][row][8] 16B units, XOR-swizzled ----
// 128-row tiles: unit = ((kq<<7)|row) ^ (kq<<1).  64-row tiles: unit = ((kq<<6)|row) ^ (kq<<1).
// Reads: each quad's 16 lanes hit 16 consecutive units -> conflict-free. Writes linear.
__device__ __forceinline__ int lidx(int plane, int row) {
    return ((((plane << 7) | row)) ^ (plane << 1)) << 3;
}
__device__ __forceinline__ int lidx64(int plane, int row) {
    return ((((plane << 6) | row)) ^ (plane << 1)) << 3;
}
// fill a 128x32 bf16 tile (rows stride ld) into LDS [4][128][8]; 256 threads x 2 x 16B
__device__ __forceinline__ void fill128(bf16* dst, const bf16* src, int ld) {
    int t = threadIdx.x;
    int r = t >> 2, kq = t & 3;
    *(float4*)(dst + lidx(kq, r))      = *(const float4*)(src + (size_t)r * ld + kq * 8);
    *(float4*)(dst + lidx(kq, r + 64)) = *(const float4*)(src + (size_t)(r + 64) * ld + kq * 8);
}
// fill a 64x32 bf16 tile into LDS [4][64][8]; 256 threads x 1 x 16B (unit = tid, inverse swizzle)
__device__ __forceinline__ void fill64(bf16* dst, const bf16* src, int ld) {
    int t = threadIdx.x;
    int kq = t >> 6, row = (t & 63) ^ (kq << 1);
    *(float4*)(dst + (t << 3)) = *(const float4*)(src + (size_t)row * ld + kq * 8);
}
// MFMA fragment from 128-row tile: sub (16 rows), lane l: row=sub*16+(l&15), k=(l>>4)*8..+7
__device__ __forceinline__ v8bf ldf(const bf16* tile, int sub, int l) {
    return *(const v8bf*)(tile + lidx(l >> 4, sub * 16 + (l & 15)));
}
// MFMA fragment from 64-row tile
__device__ __forceinline__ v8bf ldf64(const bf16* tile, int sub, int l) {
    return *(const v8bf*)(tile + lidx64(l >> 4, sub * 16 + (l & 15)));
}

// ---------------- fused layer stage A: dist (upper-tri 128x128) + st (64x128 tiles) ----------------
// 1D grid, XCD-pinned: z = (i>>1)&3, bi = ((i>>3)<<1)|(i&1)  (batch z -> XCDs {2z,2z+1})
// dist: 4 waves 2x2, each 64x64 (acc[4][4]). st: 64 rows x 128 cols, 4 waves 2x2, each 32x64
// (acc[2][4]) -> 2x the st grid for occupancy; MFMA count unchanged.
__global__ __launch_bounds__(256) void k_layer_a(const bf16* __restrict__ Xhi, const bf16* __restrict__ Xlo,
                                                 int ld, int Kpad, size_t xstride,
                                                 const bf16* __restrict__ Whi, const bf16* __restrict__ Wlo,
                                                 int O, const float* __restrict__ sqg,
                                                 float* __restrict__ Dg, float* __restrict__ Pg,
                                                 const int* __restrict__ flag) {
    int i = blockIdx.x;
    int z = (i >> 1) & 3;
    int bi = ((i >> 3) << 1) | (i & 1);
    const bf16* Xh = Xhi + (size_t)z * xstride;
    const bf16* Xl = Xlo + (size_t)z * xstride;
    __shared__ alignas(16) bf16 Ah[4096], Al[4096], Bh[4096], Bl[4096];
    int w = threadIdx.x >> 6, l = threadIdx.x & 63;
    int wr = w >> 1, wc = w & 1;
    int quad = l >> 4, col = l & 15;
    v4f zero = {0.f, 0.f, 0.f, 0.f};

    if (bi < 36) {
        // ---- dist tile: triangular decode over 8x8, bx >= by ----
        v4f acc[4][4] = {{zero, zero, zero, zero}, {zero, zero, zero, zero},
                         {zero, zero, zero, zero}, {zero, zero, zero, zero}};
        int bx = 0;
        while ((((bx + 1) * (bx + 2)) >> 1) <= bi) bx++;
        int by = bi - ((bx * (bx + 1)) >> 1);
        const float* sq = sqg + z * NPTS;
        float* D = Dg + (size_t)z * NPTS * NPTS;
        int n0 = by * 128, m0 = bx * 128;
        for (int k0 = 0; k0 < Kpad; k0 += 32) {
            __syncthreads();
            fill128(Ah, Xh + (size_t)n0 * ld + k0, ld);
            fill128(Bh, Xh + (size_t)m0 * ld + k0, ld);
            fill128(Al, Xl + (size_t)n0 * ld + k0, ld);
            fill128(Bl, Xl + (size_t)m0 * ld + k0, ld);
            __syncthreads();
            v8bf ah[4], al[4];
#pragma unroll
            for (int mi = 0; mi < 4; mi++) {
                ah[mi] = ldf(Ah, wr * 4 + mi, l);
                al[mi] = ldf(Al, wr * 4 + mi, l);
            }
#pragma unroll
            for (int ni = 0; ni < 4; ni++) {
                v8bf bh = ldf(Bh, wc * 4 + ni, l);
                v8bf bl = ldf(Bl, wc * 4 + ni, l);
#pragma unroll
                for (int mi = 0; mi < 4; mi++) {
                    acc[mi][ni] = __builtin_amdgcn_mfma_f32_16x16x32_bf16(ah[mi], bh, acc[mi][ni], 0, 0, 0);
                    acc[mi][ni] = __builtin_amdgcn_mfma_f32_16x16x32_bf16(ah[mi], bl, acc[mi][ni], 0, 0, 0);
                    acc[mi][ni] = __builtin_amdgcn_mfma_f32_16x16x32_bf16(al[mi], bh, acc[mi][ni], 0, 0, 0);
                }
            }
        }
        int rb = n0 + wr * 64 + quad * 4;
        int cb = m0 + wc * 64 + col;
        float sm[4];
#pragma unroll
        for (int ni = 0; ni < 4; ni++) sm[ni] = sq[cb + ni * 16];
#pragma unroll
        for (int mi = 0; mi < 4; mi++) {
#pragma unroll
            for (int r = 0; r < 4; r++) {
                int row = rb + mi * 16 + r;
                float sn = sq[row];
#pragma unroll
                for (int ni = 0; ni < 4; ni++) {
                    float d = 2.f * acc[mi][ni][r] - sn - sm[ni];
                    int c = cb + ni * 16;
                    D[(size_t)row * NPTS + c] = d;
                    if (bx != by) D[(size_t)c * NPTS + row] = d;
                }
            }
        }
    } else {
        // ---- st tile (64 rows x 128 weight-cols): P[point m, weight-row n] ----
        v4f acc[2][4] = {{zero, zero, zero, zero}, {zero, zero, zero, zero}};
        int isf = *flag;
        int nCol = (2 * O) >> 7;
        int s = bi - 36;
        int n0 = (s % nCol) * 128;   // weight-row tile (over 2O)
        int m0 = (s / nCol) * 64;    // point tile (over 1024, 16 tiles)
        int N2 = 2 * O;
        float* P = Pg + (size_t)z * NPTS * N2;
        for (int k0 = 0; k0 < Kpad; k0 += 32) {
            __syncthreads();
            fill64(Ah, Xh + (size_t)m0 * ld + k0, ld);
            fill64(Al, Xl + (size_t)m0 * ld + k0, ld);
            fill128(Bh, Whi + (size_t)n0 * Kpad + k0, Kpad);
            if (isf) fill128(Bl, Wlo + (size_t)n0 * Kpad + k0, Kpad);
            __syncthreads();
            v8bf ah[2], al[2];
#pragma unroll
            for (int mi = 0; mi < 2; mi++) {
                ah[mi] = ldf64(Ah, wr * 2 + mi, l);
                al[mi] = ldf64(Al, wr * 2 + mi, l);
            }
#pragma unroll
            for (int ni = 0; ni < 4; ni++) {
                v8bf bh = ldf(Bh, wc * 4 + ni, l);
#pragma unroll
                for (int mi = 0; mi < 2; mi++) {
                    acc[mi][ni] = __builtin_amdgcn_mfma_f32_16x16x32_bf16(ah[mi], bh, acc[mi][ni], 0, 0, 0);
                    acc[mi][ni] = __builtin_amdgcn_mfma_f32_16x16x32_bf16(al[mi], bh, acc[mi][ni], 0, 0, 0);
                }
                if (isf) {
                    v8bf bl = ldf(Bl, wc * 4 + ni, l);
#pragma unroll
                    for (int mi = 0; mi < 2; mi++)
                        acc[mi][ni] = __builtin_amdgcn_mfma_f32_16x16x32_bf16(ah[mi], bl, acc[mi][ni], 0, 0, 0);
                }
            }
        }
        int rb = m0 + wr * 32 + quad * 4;
        int cb = n0 + wc * 64 + col;
#pragma unroll
        for (int mi = 0; mi < 2; mi++)
#pragma unroll
            for (int r = 0; r < 4; r++) {
                int row = rb + mi * 16 + r;
#pragma unroll
                for (int ni = 0; ni < 4; ni++)
                    P[(size_t)row * N2 + cb + ni * 16] = acc[mi][ni][r];
            }
    }
}

// ---- argmax combine steps: (max val, min idx) is associative+commutative ----
template<int PAT>
__device__ __forceinline__ void swz_step(float& bv, int& bi) {
    float ov = __int_as_float(__builtin_amdgcn_ds_swizzle(__float_as_int(bv), PAT));
    int   oi = __builtin_amdgcn_ds_swizzle(bi, PAT);
    if (ov > bv || (ov == bv && oi < bi)) { bv = ov; bi = oi; }
}
__device__ __forceinline__ void shfl_step(float& bv, int& bi, int mask) {
    float ov = __shfl_xor(bv, mask);
    int   oi = __shfl_xor(bi, mask);
    if (ov > bv || (ov == bv && oi < bi)) { bv = ov; bi = oi; }
}
#define PICK(va, ja, vb, jb, vo, jo) { bool t_ = (vb) > (va); vo = t_ ? (vb) : (va); jo = t_ ? (jb) : (ja); }

// ---------------- fused stage B: top-20 (wave per row, 4 rows/block) + gather-max ----------------
// 1D grid 1024, XCD-pinned: z = (i>>1)&3, local = ((i>>3)<<1)|(i&1); rows local*4+q (wave q)
// Selection: group-cached argmax; outcome identical to full rescan. Gather: wave-uniform row
// offsets hoisted to SGPRs; affine/lrelu after max (exact FP-monotone commute).
__global__ __launch_bounds__(256) void k_layer_b(const float* __restrict__ Dg, const float* __restrict__ Pg,
                                                 const void* __restrict__ g, const void* __restrict__ bias,
                                                 int O, bf16* __restrict__ xhOut, bf16* __restrict__ xlOut,
                                                 float* __restrict__ sqOut, int writeSq,
                                                 const int* __restrict__ flag) {
    __shared__ int ids[4][20];
    __shared__ float sqP[4][8];
    int isf = *flag;
    int i = blockIdx.x;
    int z = (i >> 1) & 3;
    int local = ((i >> 3) << 1) | (i & 1);
    int tid = threadIdx.x;
    int wq = tid >> 6, l = tid & 63;
    int row = local * 4 + wq;

    // ---- per-wave register-resident top-20 (lane->index map bi = jj*256+l*4+q bijective
    //      over [0,1024), monotone per lane in scan order -> min-index tie-break) ----
    {
        const float* Dr = Dg + (size_t)z * NPTS * NPTS + (size_t)row * NPTS;
        float v[16];
#pragma unroll
        for (int jj = 0; jj < 4; jj++) {
            float4 f4 = *(const float4*)(Dr + jj * 256 + l * 4);
            v[jj * 4 + 0] = f4.x; v[jj * 4 + 1] = f4.y;
            v[jj * 4 + 2] = f4.z; v[jj * 4 + 3] = f4.w;
        }
        float bmv[4]; int bmj[4];
#pragma unroll
        for (int gg = 0; gg < 4; gg++) {
            float a0, a1; int j0, j1;
            PICK(v[4 * gg + 0], 4 * gg + 0, v[4 * gg + 1], 4 * gg + 1, a0, j0);
            PICK(v[4 * gg + 2], 4 * gg + 2, v[4 * gg + 3], 4 * gg + 3, a1, j1);
            PICK(a0, j0, a1, j1, bmv[gg], bmj[gg]);
        }
        for (int s = 0; s < 20; s++) {
            float t0, t1, bv; int s0, s1, bj;
            PICK(bmv[0], bmj[0], bmv[1], bmj[1], t0, s0);
            PICK(bmv[2], bmj[2], bmv[3], bmj[3], t1, s1);
            PICK(t0, s0, t1, s1, bv, bj);
            int bi = (bj >> 2) * 256 + l * 4 + (bj & 3);
            swz_step<0x041F>(bv, bi);   // xor 1
            swz_step<0x081F>(bv, bi);   // xor 2
            swz_step<0x101F>(bv, bi);   // xor 4
            swz_step<0x201F>(bv, bi);   // xor 8
            swz_step<0x401F>(bv, bi);   // xor 16
            shfl_step(bv, bi, 32);      // xor 32 -> all 64 lanes converged
            if (l == 0) ids[wq][s] = bi;
            if (((bi >> 2) & 63) == l) {               // owning lane: evict + rebuild its group
                int ej = (bi >> 8) * 4 + (bi & 3);
                int eg = ej >> 2, ek = ej & 3;
#pragma unroll
                for (int gg = 0; gg < 4; gg++) if (gg == eg) {
#pragma unroll
                    for (int kk = 0; kk < 4; kk++)
                        if (kk == ek) v[4 * gg + kk] = -__builtin_inff();
                    float a0, a1; int j0, j1;
                    PICK(v[4 * gg + 0], 4 * gg + 0, v[4 * gg + 1], 4 * gg + 1, a0, j0);
                    PICK(v[4 * gg + 2], 4 * gg + 2, v[4 * gg + 3], 4 * gg + 3, a1, j1);
                    PICK(a0, j0, a1, j1, bmv[gg], bmj[gg]);
                }
            }
        }
    }
    __syncthreads();

    // ---- gather + max (affine/lrelu AFTER max: exact FP-monotone commute) ----
    int N2 = 2 * O;
    const float* P = Pg + (size_t)z * NPTS * N2;
#pragma unroll
    for (int r = 0; r < 4; r++) {
        int offj[20];
#pragma unroll
        for (int j = 0; j < 20; j++)
            offj[j] = __builtin_amdgcn_readfirstlane(ids[r][j]) * N2;  // SGPR row bases
        int n = local * 4 + r;
        const float* Pn = P + (size_t)n * N2;
        for (int o = tid; o < O; o += 256) {
            float tv = Pn[O + o] - Pn[o];
            float mx = -__builtin_inff(), mn = __builtin_inff();
#pragma unroll
            for (int j = 0; j < 20; j++) {
                float vv = P[offj[j] + o];
                mx = fmaxf(mx, vv);
                mn = fminf(mn, vv);
            }
            float scl = ldw(g, o, isf) * BN_SCALE;
            float bb = ldw(bias, o, isf);
            float base = (scl >= 0.f ? mx : mn) + tv;
            float acc = base * scl + bb;
            acc = acc > 0.f ? acc : 0.2f * acc;
            bf16 hi = f2b(acc);
            bf16 lo = f2b(acc - b2f(hi));
            xhOut[(size_t)z * NPTS * 960 + (size_t)n * 960 + o] = hi;
            xlOut[(size_t)z * NPTS * 960 + (size_t)n * 960 + o] = lo;
            if (writeSq) {
                float xv = b2f(hi) + b2f(lo);
                float s2 = xv * xv;
#pragma unroll
                for (int off = 32; off > 0; off >>= 1) s2 += __shfl_down(s2, off);
                if (l == 0) sqP[r][o >> 6] = s2;   // o>>6 wave-uniform: fixed chunk slot
            }
        }
    }
    if (writeSq) {
        __syncthreads();
        if (tid < 4) {
            int nc = O >> 6;
            float tot = 0.f;
            for (int c = 0; c < nc; c++) tot += sqP[tid][c];
            sqOut[z * NPTS + local * 4 + tid] = tot;
        }
    }
}

// ---------------- conv5 via MFMA, K-split x6 (chunks of 160) -> f32 partials ----------------
// 1D grid 768, XCD-pinned: z=(i>>1)&3, rest=((i>>3)<<1)|(i&1) in [0,192):
//   ks = rest>>5 (K-chunk), tile = rest&31: m0=(tile>>2)*128, o0=(tile&3)*128
__global__ __launch_bounds__(256) void k_conv5(const bf16* __restrict__ Xhi, const bf16* __restrict__ Xlo,
                                               const bf16* __restrict__ Whi, const bf16* __restrict__ Wlo,
                                               float* __restrict__ P5,
                                               const int* __restrict__ flag) {
    int isf = *flag;
    int i = blockIdx.x;
    int z = (i >> 1) & 3;
    int rest = ((i >> 3) << 1) | (i & 1);
    int ks = rest >> 5;
    int tile = rest & 31;
    int m0 = (tile >> 2) * 128, o0 = (tile & 3) * 128;
    const bf16* Xh = Xhi + (size_t)z * NPTS * 960;
    const bf16* Xl = Xlo + (size_t)z * NPTS * 960;
    __shared__ alignas(16) bf16 Ah[4096], Al[4096], Bh[4096], Bl[4096];
    int w = threadIdx.x >> 6, l = threadIdx.x & 63;
    int wr = w >> 1, wc = w & 1;
    int quad = l >> 4, col = l & 15;
    v4f zero = {0.f, 0.f, 0.f, 0.f};
    v4f acc[4][4] = {{zero, zero, zero, zero}, {zero, zero, zero, zero},
                     {zero, zero, zero, zero}, {zero, zero, zero, zero}};
    int kbeg = ks * 160, kend = kbeg + 160;
    for (int k0 = kbeg; k0 < kend; k0 += 32) {
        __syncthreads();
        fill128(Ah, Xh + (size_t)m0 * 960 + k0, 960);
        fill128(Al, Xl + (size_t)m0 * 960 + k0, 960);
        fill128(Bh, Whi + (size_t)o0 * 960 + k0, 960);
        if (isf) fill128(Bl, Wlo + (size_t)o0 * 960 + k0, 960);
        __syncthreads();
        v8bf ah[4], al[4];
#pragma unroll
        for (int mi = 0; mi < 4; mi++) {
            ah[mi] = ldf(Ah, wr * 4 + mi, l);
            al[mi] = ldf(Al, wr * 4 + mi, l);
        }
#pragma unroll
        for (int ni = 0; ni < 4; ni++) {
            v8bf bh = ldf(Bh, wc * 4 + ni, l);
#pragma unroll
            for (int mi = 0; mi < 4; mi++) {
                acc[mi][ni] = __builtin_amdgcn_mfma_f32_16x16x32_bf16(ah[mi], bh, acc[mi][ni], 0, 0, 0);
                acc[mi][ni] = __builtin_amdgcn_mfma_f32_16x16x32_bf16(al[mi], bh, acc[mi][ni], 0, 0, 0);
            }
            if (isf) {
                v8bf bl = ldf(Bl, wc * 4 + ni, l);
#pragma unroll
                for (int mi = 0; mi < 4; mi++)
                    acc[mi][ni] = __builtin_amdgcn_mfma_f32_16x16x32_bf16(ah[mi], bl, acc[mi][ni], 0, 0, 0);
            }
        }
    }
    // write f32 partial tile (disjoint per (ks,z,tile) -> no atomics)
    float* Pw = P5 + (size_t)ks * CH5 + (size_t)z * NPTS * 512;
    int rb = m0 + wr * 64 + quad * 4;
    int cb = o0 + wc * 64 + col;
#pragma unroll
    for (int mi = 0; mi < 4; mi++)
#pragma unroll
        for (int r = 0; r < 4; r++) {
            int row = rb + mi * 16 + r;
#pragma unroll
            for (int ni = 0; ni < 4; ni++)
                Pw[(size_t)row * 512 + cb + ni * 16] = acc[mi][ni][r];
        }
}

// ---------------- pool5: sum 6 K-chunks + affine + lrelu + max over rows -> pooled ----------------
// 1D grid 512, XCD-pinned: z=(i>>1)&3, rest=((i>>3)<<1)|(i&1) in [0,128):
//   oc=(rest&3)*128 cols, mc=(rest>>2)*32 rows; thread: col=t&127, half=t>>7 (16 rows each)
__global__ __launch_bounds__(256) void k_pool5(const float* __restrict__ P5,
                                               const void* __restrict__ g, const void* __restrict__ bias,
                                               unsigned* __restrict__ pooledU,
                                               const int* __restrict__ flag) {
    __shared__ float red2[128];
    int isf = *flag;
    int i = blockIdx.x;
    int z = (i >> 1) & 3;
    int rest = ((i >> 3) << 1) | (i & 1);
    int oc = (rest & 3) * 128, mc = (rest >> 2) * 32;
    int t = threadIdx.x;
    int c = t & 127, h = t >> 7;
    int o = oc + c;
    float scl = ldw(g, o, isf) * BN_SCALE;
    float bb = ldw(bias, o, isf);
    const float* p0 = P5 + (size_t)z * NPTS * 512 + (size_t)(mc + h * 16) * 512 + o;
    float ym = -__builtin_inff();
    for (int r = 0; r < 16; r++) {
        const float* p = p0 + (size_t)r * 512;
        float s = p[0];
#pragma unroll
        for (int ks = 1; ks < 6; ks++) s += p[(size_t)ks * CH5];
        float v = s * scl + bb;
        v = v > 0.f ? v : 0.2f * v;
        ym = fmaxf(ym, v);
    }
    if (h == 1) red2[c] = ym;
    __syncthreads();
    if (h == 0) {
        float m = fmaxf(ym, red2[c]);
        atomicMax(&pooledU[z * 512 + o], ordf(m));
    }
}

// ---------------- final linear: coalesced wave-per-output ----------------
__global__ void k_final(const unsigned* __restrict__ pooledU, const void* __restrict__ We,
                        void* __restrict__ out, const int* __restrict__ flag) {
    __shared__ float p[512];
    int isf = *flag;
    int b = blockIdx.x >> 2, fb = blockIdx.x & 3;
    int t = threadIdx.x, w = t >> 6, l = t & 63;
    for (int i = t; i < 512; i += 256) p[i] = iordf(pooledU[b * 512 + i]);
    __syncthreads();
    for (int it = 0; it < 16; it++) {
        int f = fb * 64 + w * 16 + it;
        float s = 0.f;
        size_t base = (size_t)f * 512 + l * 8;
#pragma unroll
        for (int j = 0; j < 8; j++) s += p[l * 8 + j] * ldw(We, base + j, isf);
#pragma unroll
        for (int off = 32; off > 0; off >>= 1) s += __shfl_down(s, off);
        if (l == 0) {
            if (isf) ((float*)out)[b * 256 + f] = s;
            else     ((bf16*)out)[b * 256 + f] = f2b(s);
        }
    }
}

extern "C" void kernel_launch(void* const* d_in, const int* in_sizes, int n_in,
                              void* d_out, int out_size, void* d_ws, size_t ws_size,
                              hipStream_t stream) {
    const void* x  = d_in[0];
    const void* Wl[4] = { d_in[1], d_in[4], d_in[7], d_in[10] };
    const void* gl[4] = { d_in[2], d_in[5], d_in[8], d_in[11] };
    const void* bl[4] = { d_in[3], d_in[6], d_in[9], d_in[12] };
    const void* W5 = d_in[13];
    const void* g5 = d_in[14];
    const void* b5 = d_in[15];
    const void* We = d_in[16];

    // workspace layout (bytes), ~101.5 MB total (ws ~256 MiB per round-9 fill evidence)
    char* base = (char*)d_ws;
    bf16*     xc_hi   = (bf16*)(base);                  // 7,864,320
    bf16*     xc_lo   = (bf16*)(base + 7864320);        // 7,864,320
    bf16*     xpadh   = (bf16*)(base + 15728640);       // 262,144
    bf16*     xpadl   = (bf16*)(base + 15990784);       // 262,144
    float*    Dbuf    = (float*)(base + 16252928);      // 16,777,216
    float*    Pbuf    = (float*)(base + 33030144);      // 16,777,216
    bf16*     Whi     = (bf16*)(base + 49807360);       // 1,679,360
    bf16*     Wlo     = (bf16*)(base + 51486720);       // 1,679,360
    unsigned* pooledU = (unsigned*)(base + 53493760);   // 8,192
    float*    sq      = (float*)(base + 53501952);      // 16,384
    int*      flag    = (int*)(base + 53518336);        // 4
    float*    P5      = (float*)(base + 53520384);      // 50,331,648 (6 x 8 MB conv5 partials)

    const int Kpad[4]   = { 32, 64, 128, 256 };
    const int Os[4]     = { 64, 128, 256, 512 };
    const int Woff[5]   = { 0, 4096, 20480, 86016, 348160 };
    const int colIn[4]  = { 0, 0, 64, 192 };
    const int colOut[4] = { 0, 64, 192, 448 };

    k_prep<<<3296, 256, 0, stream>>>(Wl[0], Wl[1], Wl[2], Wl[3], W5, x,
                                     Whi, Wlo, xpadh, xpadl, sq, flag, pooledU);

    for (int l = 0; l < 4; l++) {
        int O = Os[l];
        int nCol = (2 * O) >> 7;
        int nBlk = 36 + 16 * nCol;  // 52/68/100/164 (even -> grid*4 divisible by 8)
        const bf16* Xh = (l == 0) ? xpadh : (xc_hi + colIn[l]);
        const bf16* Xl = (l == 0) ? xpadl : (xc_lo + colIn[l]);
        int ld = (l == 0) ? 32 : 960;
        size_t xstr = (l == 0) ? (size_t)NPTS * 32 : (size_t)NPTS * 960;
        k_layer_a<<<nBlk * NB, 256, 0, stream>>>(
            Xh, Xl, ld, Kpad[l], xstr, Whi + Woff[l], Wlo + Woff[l], O, sq, Dbuf, Pbuf, flag);
        k_layer_b<<<NPTS * NB / 4, 256, 0, stream>>>(
            Dbuf, Pbuf, gl[l], bl[l], O, xc_hi + colOut[l], xc_lo + colOut[l], sq, l < 3, flag);
    }
    k_conv5<<<768, 256, 0, stream>>>(xc_hi, xc_lo, Whi + Woff[4], Wlo + Woff[4], P5, flag);
    k_pool5<<<512, 256, 0, stream>>>(P5, g5, b5, pooledU, flag);
    k_final<<<16, 256, 0, stream>>>(pooledU, We, d_out, flag);
}

// Round 10
// 320.954 us; speedup vs baseline: 1.0526x; 1.0216x over previous
//
#include <hip/hip_runtime.h>
#include <hip/hip_bf16.h>
#include <math.h>

typedef __hip_bfloat16 bf16;
typedef __bf16 v8bf __attribute__((ext_vector_type(8)));
typedef float v4f __attribute__((ext_vector_type(4)));

#define BN_SCALE 0.9999950000374997f
#define NPTS 1024
#define NB 4
#define CH5 ((size_t)4 * 1024 * 512)   // conv5 partial-chunk stride (floats)

__device__ __forceinline__ float b2f(bf16 v) { return __bfloat162float(v); }
__device__ __forceinline__ bf16 f2b(float v) { return __float2bfloat16(v); }
__device__ __forceinline__ float ldw(const void* p, size_t i, int isf) {
    return isf ? ((const float*)p)[i] : b2f(((const bf16*)p)[i]);
}
__device__ __forceinline__ unsigned ordf(float f) {
    unsigned u = __float_as_uint(f);
    return (u & 0x80000000u) ? ~u : (u | 0x80000000u);
}
__device__ __forceinline__ float iordf(unsigned u) {
    return (u & 0x80000000u) ? __uint_as_float(u ^ 0x80000000u) : __uint_as_float(~u);
}

// per-block dtype detect from first 512 shorts of x (fp32 ~113/256 implausible, bf16 ~0)
__device__ __forceinline__ int detect_isf(const void* xraw, int* cnt) {
    const unsigned short* u = (const unsigned short*)xraw;
    int t = threadIdx.x, c = 0;
    for (int i = t; i < 512; i += 256) {
        unsigned short v = u[i];
        int e = (v >> 7) & 0xFF;
        int m = v & 0x7F;
        if (e == 0xFF || e >= 141 || (e == 0 && m != 0)) c++;
    }
    cnt[t] = c;
    __syncthreads();
    for (int off = 128; off > 0; off >>= 1) {
        if (t < off) cnt[t] += cnt[t + off];
        __syncthreads();
    }
    int isf = (cnt[0] > 30) ? 1 : 0;
    __syncthreads();
    return isf;
}

// ---------------- fused prep: dtype flag + pooled init + weight splits + x pad + sq ----------------
__global__ void k_prep(const void* __restrict__ W1, const void* __restrict__ W2,
                       const void* __restrict__ W3, const void* __restrict__ W4,
                       const void* __restrict__ W5, const void* __restrict__ x,
                       bf16* __restrict__ Whi, bf16* __restrict__ Wlo,
                       bf16* __restrict__ xph, bf16* __restrict__ xpl, float* __restrict__ sq,
                       int* __restrict__ flag, unsigned* __restrict__ pooledU) {
    __shared__ int cnt[256];
    int isf = detect_isf(x, cnt);
    if (blockIdx.x == 0) {
        if (threadIdx.x == 0) *flag = isf;
        for (int i = threadIdx.x; i < 2048; i += 256) pooledU[i] = 0u;  // 0 < ordf(any finite)
    }
    int idx = blockIdx.x * 256 + threadIdx.x;
    if (idx < 839680) {
        const void* src; int C, O, Kpad, two, local;
        if (idx < 4096)        { src = W1; C = 3;   O = 64;  Kpad = 32;  two = 1; local = idx; }
        else if (idx < 20480)  { src = W2; C = 64;  O = 128; Kpad = 64;  two = 1; local = idx - 4096; }
        else if (idx < 86016)  { src = W3; C = 128; O = 256; Kpad = 128; two = 1; local = idx - 20480; }
        else if (idx < 348160) { src = W4; C = 256; O = 512; Kpad = 256; two = 1; local = idx - 86016; }
        else                   { src = W5; C = 960; O = 512; Kpad = 960; two = 0; local = idx - 348160; }
        int r = local / Kpad, c = local % Kpad;
        float wv = 0.f;
        if (c < C) {
            size_t off;
            if (two) off = (r < O) ? (size_t)r * 2 * C + c : (size_t)(r - O) * 2 * C + C + c;
            else     off = (size_t)r * C + c;
            wv = ldw(src, off, isf);
        }
        bf16 h = f2b(wv);
        Whi[idx] = h;
        Wlo[idx] = f2b(wv - b2f(h));
    } else if (idx < 843776) {
        int p = idx - 839680;       // point index: z*1024 + n
        int z = p >> 10, n = p & 1023;
        bf16* ph = xph + (size_t)z * NPTS * 32;
        bf16* pl = xpl + (size_t)z * NPTS * 32;
        float s = 0.f;
        for (int c = 0; c < 32; c++) {
            float v = (c < 3) ? ldw(x, (size_t)z * NPTS * 3 + n * 3 + c, isf) : 0.f;
            bf16 h = f2b(v);
            ph[n * 32 + c] = h;
            pl[n * 32 + c] = f2b(v - b2f(h));
            s += v * v;
        }
        sq[z * NPTS + n] = s;
    }
}

// ---- conflict-free LDS layout: k-quad-major [kq][row][8], XOR-swizzled ----
__device__ __forceinline__ int lidx(int plane, int row) {
    return ((((plane << 7) | row)) ^ (plane << 1)) << 3;
}
// fill a 128x32 bf16 tile (rows stride ld) into LDS [4][128][8]; 256 threads x 2 x 16B
__device__ __forceinline__ void fill128(bf16* dst, const bf16* src, int ld) {
    int t = threadIdx.x;
    int r = t >> 2, kq = t & 3;
    *(float4*)(dst + lidx(kq, r))      = *(const float4*)(src + (size_t)r * ld + kq * 8);
    *(float4*)(dst + lidx(kq, r + 64)) = *(const float4*)(src + (size_t)(r + 64) * ld + kq * 8);
}
// MFMA fragment: sub-tile 'sub' (16 rows of 128), lane l: row=sub*16+(l&15), k=(l>>4)*8..+7
__device__ __forceinline__ v8bf ldf(const bf16* tile, int sub, int l) {
    return *(const v8bf*)(tile + lidx(l >> 4, sub * 16 + (l & 15)));
}

// ---------------- fused layer stage A: dist (upper-tri 128x128 tiles) + st ----------------
// 1D grid, XCD-pinned: z = (i>>1)&3, bi = ((i>>3)<<1)|(i&1)  (batch z -> XCDs {2z,2z+1})
// 128x128 output tile, 4 waves in 2x2, each wave 64x64 (acc[4][4])
__global__ __launch_bounds__(256) void k_layer_a(const bf16* __restrict__ Xhi, const bf16* __restrict__ Xlo,
                                                 int ld, int Kpad, size_t xstride,
                                                 const bf16* __restrict__ Whi, const bf16* __restrict__ Wlo,
                                                 int O, const float* __restrict__ sqg,
                                                 float* __restrict__ Dg, float* __restrict__ Pg,
                                                 const int* __restrict__ flag) {
    int i = blockIdx.x;
    int z = (i >> 1) & 3;
    int bi = ((i >> 3) << 1) | (i & 1);
    const bf16* Xh = Xhi + (size_t)z * xstride;
    const bf16* Xl = Xlo + (size_t)z * xstride;
    __shared__ alignas(16) bf16 Ah[4096], Al[4096], Bh[4096], Bl[4096];
    int w = threadIdx.x >> 6, l = threadIdx.x & 63;
    int wr = w >> 1, wc = w & 1;
    int quad = l >> 4, col = l & 15;
    v4f zero = {0.f, 0.f, 0.f, 0.f};
    v4f acc[4][4] = {{zero, zero, zero, zero}, {zero, zero, zero, zero},
                     {zero, zero, zero, zero}, {zero, zero, zero, zero}};

    if (bi < 36) {
        // ---- dist tile: triangular decode over 8x8, bx >= by ----
        int bx = 0;
        while ((((bx + 1) * (bx + 2)) >> 1) <= bi) bx++;
        int by = bi - ((bx * (bx + 1)) >> 1);
        const float* sq = sqg + z * NPTS;
        float* D = Dg + (size_t)z * NPTS * NPTS;
        int n0 = by * 128, m0 = bx * 128;
        for (int k0 = 0; k0 < Kpad; k0 += 32) {
            __syncthreads();
            fill128(Ah, Xh + (size_t)n0 * ld + k0, ld);
            fill128(Bh, Xh + (size_t)m0 * ld + k0, ld);
            fill128(Al, Xl + (size_t)n0 * ld + k0, ld);
            fill128(Bl, Xl + (size_t)m0 * ld + k0, ld);
            __syncthreads();
            v8bf ah[4], al[4];
#pragma unroll
            for (int mi = 0; mi < 4; mi++) {
                ah[mi] = ldf(Ah, wr * 4 + mi, l);
                al[mi] = ldf(Al, wr * 4 + mi, l);
            }
#pragma unroll
            for (int ni = 0; ni < 4; ni++) {
                v8bf bh = ldf(Bh, wc * 4 + ni, l);
                v8bf bl = ldf(Bl, wc * 4 + ni, l);
#pragma unroll
                for (int mi = 0; mi < 4; mi++) {
                    acc[mi][ni] = __builtin_amdgcn_mfma_f32_16x16x32_bf16(ah[mi], bh, acc[mi][ni], 0, 0, 0);
                    acc[mi][ni] = __builtin_amdgcn_mfma_f32_16x16x32_bf16(ah[mi], bl, acc[mi][ni], 0, 0, 0);
                    acc[mi][ni] = __builtin_amdgcn_mfma_f32_16x16x32_bf16(al[mi], bh, acc[mi][ni], 0, 0, 0);
                }
            }
        }
        int rb = n0 + wr * 64 + quad * 4;
        int cb = m0 + wc * 64 + col;
        float sm[4];
#pragma unroll
        for (int ni = 0; ni < 4; ni++) sm[ni] = sq[cb + ni * 16];
#pragma unroll
        for (int mi = 0; mi < 4; mi++) {
#pragma unroll
            for (int r = 0; r < 4; r++) {
                int row = rb + mi * 16 + r;
                float sn = sq[row];
#pragma unroll
                for (int ni = 0; ni < 4; ni++) {
                    float d = 2.f * acc[mi][ni][r] - sn - sm[ni];
                    int c = cb + ni * 16;
                    D[(size_t)row * NPTS + c] = d;
                    if (bx != by) D[(size_t)c * NPTS + row] = d;
                }
            }
        }
    } else {
        // ---- st tile: P[point m, weight-row n] over 2O cols ----
        int isf = *flag;
        int nCol = (2 * O) >> 7;
        int s = bi - 36;
        int n0 = (s % nCol) * 128;   // weight-row tile (over 2O)
        int m0 = (s / nCol) * 128;   // point tile (over 1024)
        int N2 = 2 * O;
        float* P = Pg + (size_t)z * NPTS * N2;
        for (int k0 = 0; k0 < Kpad; k0 += 32) {
            __syncthreads();
            fill128(Ah, Xh + (size_t)m0 * ld + k0, ld);
            fill128(Al, Xl + (size_t)m0 * ld + k0, ld);
            fill128(Bh, Whi + (size_t)n0 * Kpad + k0, Kpad);
            if (isf) fill128(Bl, Wlo + (size_t)n0 * Kpad + k0, Kpad);
            __syncthreads();
            v8bf ah[4], al[4];
#pragma unroll
            for (int mi = 0; mi < 4; mi++) {
                ah[mi] = ldf(Ah, wr * 4 + mi, l);
                al[mi] = ldf(Al, wr * 4 + mi, l);
            }
#pragma unroll
            for (int ni = 0; ni < 4; ni++) {
                v8bf bh = ldf(Bh, wc * 4 + ni, l);
#pragma unroll
                for (int mi = 0; mi < 4; mi++) {
                    acc[mi][ni] = __builtin_amdgcn_mfma_f32_16x16x32_bf16(ah[mi], bh, acc[mi][ni], 0, 0, 0);
                    acc[mi][ni] = __builtin_amdgcn_mfma_f32_16x16x32_bf16(al[mi], bh, acc[mi][ni], 0, 0, 0);
                }
                if (isf) {
                    v8bf bl = ldf(Bl, wc * 4 + ni, l);
#pragma unroll
                    for (int mi = 0; mi < 4; mi++)
                        acc[mi][ni] = __builtin_amdgcn_mfma_f32_16x16x32_bf16(ah[mi], bl, acc[mi][ni], 0, 0, 0);
                }
            }
        }
        int rb = m0 + wr * 64 + quad * 4;
        int cb = n0 + wc * 64 + col;
#pragma unroll
        for (int mi = 0; mi < 4; mi++)
#pragma unroll
            for (int r = 0; r < 4; r++) {
                int row = rb + mi * 16 + r;
#pragma unroll
                for (int ni = 0; ni < 4; ni++)
                    P[(size_t)row * N2 + cb + ni * 16] = acc[mi][ni][r];
            }
    }
}

// ---- argmax combine steps: (max val, min idx) is associative+commutative ----
template<int PAT>
__device__ __forceinline__ void swz_step(float& bv, int& bi) {
    float ov = __int_as_float(__builtin_amdgcn_ds_swizzle(__float_as_int(bv), PAT));
    int   oi = __builtin_amdgcn_ds_swizzle(bi, PAT);
    if (ov > bv || (ov == bv && oi < bi)) { bv = ov; bi = oi; }
}
__device__ __forceinline__ void shfl_step(float& bv, int& bi, int mask) {
    float ov = __shfl_xor(bv, mask);
    int   oi = __shfl_xor(bi, mask);
    if (ov > bv || (ov == bv && oi < bi)) { bv = ov; bi = oi; }
}
#define PICK(va, ja, vb, jb, vo, jo) { bool t_ = (vb) > (va); vo = t_ ? (vb) : (va); jo = t_ ? (jb) : (ja); }

// one gather body for column o (scl/bb preloaded); FP math identical to prior rounds
#define GATHER_BODY(o, scl, bb, doSq) do { \
    float tv = Pn[O + (o)] - Pn[(o)]; \
    float mx = -__builtin_inff(), mn = __builtin_inff(); \
    _Pragma("unroll") \
    for (int j = 0; j < 20; j++) { \
        float vv = P[offj[j] + (o)]; \
        mx = fmaxf(mx, vv); \
        mn = fminf(mn, vv); \
    } \
    float base = ((scl) >= 0.f ? mx : mn) + tv; \
    float accv = base * (scl) + (bb); \
    accv = accv > 0.f ? accv : 0.2f * accv; \
    bf16 hi = f2b(accv); \
    bf16 lo = f2b(accv - b2f(hi)); \
    xhOut[(size_t)z * NPTS * 960 + (size_t)n * 960 + (o)] = hi; \
    xlOut[(size_t)z * NPTS * 960 + (size_t)n * 960 + (o)] = lo; \
    if (doSq) { \
        float xv = b2f(hi) + b2f(lo); \
        float s2 = xv * xv; \
        _Pragma("unroll") \
        for (int off = 32; off > 0; off >>= 1) s2 += __shfl_down(s2, off); \
        if (l == 0) sqP[r][(o) >> 6] = s2; \
    } \
} while (0)

// ---------------- fused stage B: top-20 (wave per row, 4 rows/block) + gather-max ----------------
// 1D grid 1024, XCD-pinned: z = (i>>1)&3, local = ((i>>3)<<1)|(i&1); rows local*4+q (wave q)
// Selection: group-cached argmax; outcome identical to full rescan. Gather: wave-uniform row
// offsets hoisted to SGPRs; affine/lrelu after max (exact FP-monotone commute); g/bias loads
// hoisted out of the r-loop (o-only dependence; O%64==0 keeps shfl waves fully active).
__global__ __launch_bounds__(256) void k_layer_b(const float* __restrict__ Dg, const float* __restrict__ Pg,
                                                 const void* __restrict__ g, const void* __restrict__ bias,
                                                 int O, bf16* __restrict__ xhOut, bf16* __restrict__ xlOut,
                                                 float* __restrict__ sqOut, int writeSq,
                                                 const int* __restrict__ flag) {
    __shared__ int ids[4][20];
    __shared__ float sqP[4][8];
    int isf = *flag;
    int i = blockIdx.x;
    int z = (i >> 1) & 3;
    int local = ((i >> 3) << 1) | (i & 1);
    int tid = threadIdx.x;
    int wq = tid >> 6, l = tid & 63;
    int row = local * 4 + wq;

    // ---- per-wave register-resident top-20 (lane->index map bi = jj*256+l*4+q bijective
    //      over [0,1024), monotone per lane in scan order -> min-index tie-break) ----
    {
        const float* Dr = Dg + (size_t)z * NPTS * NPTS + (size_t)row * NPTS;
        float v[16];
#pragma unroll
        for (int jj = 0; jj < 4; jj++) {
            float4 f4 = *(const float4*)(Dr + jj * 256 + l * 4);
            v[jj * 4 + 0] = f4.x; v[jj * 4 + 1] = f4.y;
            v[jj * 4 + 2] = f4.z; v[jj * 4 + 3] = f4.w;
        }
        float bmv[4]; int bmj[4];
#pragma unroll
        for (int gg = 0; gg < 4; gg++) {
            float a0, a1; int j0, j1;
            PICK(v[4 * gg + 0], 4 * gg + 0, v[4 * gg + 1], 4 * gg + 1, a0, j0);
            PICK(v[4 * gg + 2], 4 * gg + 2, v[4 * gg + 3], 4 * gg + 3, a1, j1);
            PICK(a0, j0, a1, j1, bmv[gg], bmj[gg]);
        }
        for (int s = 0; s < 20; s++) {
            float t0, t1, bv; int s0, s1, bj;
            PICK(bmv[0], bmj[0], bmv[1], bmj[1], t0, s0);
            PICK(bmv[2], bmj[2], bmv[3], bmj[3], t1, s1);
            PICK(t0, s0, t1, s1, bv, bj);
            int bi = (bj >> 2) * 256 + l * 4 + (bj & 3);
            swz_step<0x041F>(bv, bi);   // xor 1
            swz_step<0x081F>(bv, bi);   // xor 2
            swz_step<0x101F>(bv, bi);   // xor 4
            swz_step<0x201F>(bv, bi);   // xor 8
            swz_step<0x401F>(bv, bi);   // xor 16
            shfl_step(bv, bi, 32);      // xor 32 -> all 64 lanes converged
            if (l == 0) ids[wq][s] = bi;
            if (((bi >> 2) & 63) == l) {               // owning lane: evict + rebuild its group
                int ej = (bi >> 8) * 4 + (bi & 3);
                int eg = ej >> 2, ek = ej & 3;
#pragma unroll
                for (int gg = 0; gg < 4; gg++) if (gg == eg) {
#pragma unroll
                    for (int kk = 0; kk < 4; kk++)
                        if (kk == ek) v[4 * gg + kk] = -__builtin_inff();
                    float a0, a1; int j0, j1;
                    PICK(v[4 * gg + 0], 4 * gg + 0, v[4 * gg + 1], 4 * gg + 1, a0, j0);
                    PICK(v[4 * gg + 2], 4 * gg + 2, v[4 * gg + 3], 4 * gg + 3, a1, j1);
                    PICK(a0, j0, a1, j1, bmv[gg], bmj[gg]);
                }
            }
        }
    }
    __syncthreads();

    // ---- gather + max (affine/lrelu AFTER max: exact FP-monotone commute) ----
    int N2 = 2 * O;
    const float* P = Pg + (size_t)z * NPTS * N2;
    int o0 = tid, o1 = tid + 256;
    int has0 = (o0 < O), has1 = (o1 < O);      // O in {64,128,256,512}: <=2 o-iterations
    float scl0 = 0.f, bb0 = 0.f, scl1 = 0.f, bb1 = 0.f;
    if (has0) { scl0 = ldw(g, o0, isf) * BN_SCALE; bb0 = ldw(bias, o0, isf); }
    if (has1) { scl1 = ldw(g, o1, isf) * BN_SCALE; bb1 = ldw(bias, o1, isf); }
#pragma unroll
    for (int r = 0; r < 4; r++) {
        int offj[20];
#pragma unroll
        for (int j = 0; j < 20; j++)
            offj[j] = __builtin_amdgcn_readfirstlane(ids[r][j]) * N2;  // SGPR row bases
        int n = local * 4 + r;
        const float* Pn = P + (size_t)n * N2;
        if (has0) GATHER_BODY(o0, scl0, bb0, writeSq);
        if (has1) GATHER_BODY(o1, scl1, bb1, 0);   // O=512 only; writeSq=0 there (l==3)
    }
    if (writeSq) {
        __syncthreads();
        if (tid < 4) {
            int nc = O >> 6;
            float tot = 0.f;
            for (int c = 0; c < nc; c++) tot += sqP[tid][c];
            sqOut[z * NPTS + local * 4 + tid] = tot;
        }
    }
}

// ---------------- conv5 via MFMA, K-split x6 (chunks of 160) -> f32 partials ----------------
// 1D grid 768, XCD-pinned: z=(i>>1)&3, rest=((i>>3)<<1)|(i&1) in [0,192):
//   ks = rest>>5 (K-chunk), tile = rest&31: m0=(tile>>2)*128, o0=(tile&3)*128
__global__ __launch_bounds__(256) void k_conv5(const bf16* __restrict__ Xhi, const bf16* __restrict__ Xlo,
                                               const bf16* __restrict__ Whi, const bf16* __restrict__ Wlo,
                                               float* __restrict__ P5,
                                               const int* __restrict__ flag) {
    int isf = *flag;
    int i = blockIdx.x;
    int z = (i >> 1) & 3;
    int rest = ((i >> 3) << 1) | (i & 1);
    int ks = rest >> 5;
    int tile = rest & 31;
    int m0 = (tile >> 2) * 128, o0 = (tile & 3) * 128;
    const bf16* Xh = Xhi + (size_t)z * NPTS * 960;
    const bf16* Xl = Xlo + (size_t)z * NPTS * 960;
    __shared__ alignas(16) bf16 Ah[4096], Al[4096], Bh[4096], Bl[4096];
    int w = threadIdx.x >> 6, l = threadIdx.x & 63;
    int wr = w >> 1, wc = w & 1;
    int quad = l >> 4, col = l & 15;
    v4f zero = {0.f, 0.f, 0.f, 0.f};
    v4f acc[4][4] = {{zero, zero, zero, zero}, {zero, zero, zero, zero},
                     {zero, zero, zero, zero}, {zero, zero, zero, zero}};
    int kbeg = ks * 160, kend = kbeg + 160;
    for (int k0 = kbeg; k0 < kend; k0 += 32) {
        __syncthreads();
        fill128(Ah, Xh + (size_t)m0 * 960 + k0, 960);
        fill128(Al, Xl + (size_t)m0 * 960 + k0, 960);
        fill128(Bh, Whi + (size_t)o0 * 960 + k0, 960);
        if (isf) fill128(Bl, Wlo + (size_t)o0 * 960 + k0, 960);
        __syncthreads();
        v8bf ah[4], al[4];
#pragma unroll
        for (int mi = 0; mi < 4; mi++) {
            ah[mi] = ldf(Ah, wr * 4 + mi, l);
            al[mi] = ldf(Al, wr * 4 + mi, l);
        }
#pragma unroll
        for (int ni = 0; ni < 4; ni++) {
            v8bf bh = ldf(Bh, wc * 4 + ni, l);
#pragma unroll
            for (int mi = 0; mi < 4; mi++) {
                acc[mi][ni] = __builtin_amdgcn_mfma_f32_16x16x32_bf16(ah[mi], bh, acc[mi][ni], 0, 0, 0);
                acc[mi][ni] = __builtin_amdgcn_mfma_f32_16x16x32_bf16(al[mi], bh, acc[mi][ni], 0, 0, 0);
            }
            if (isf) {
                v8bf bl = ldf(Bl, wc * 4 + ni, l);
#pragma unroll
                for (int mi = 0; mi < 4; mi++)
                    acc[mi][ni] = __builtin_amdgcn_mfma_f32_16x16x32_bf16(ah[mi], bl, acc[mi][ni], 0, 0, 0);
            }
        }
    }
    // write f32 partial tile (disjoint per (ks,z,tile) -> no atomics)
    float* Pw = P5 + (size_t)ks * CH5 + (size_t)z * NPTS * 512;
    int rb = m0 + wr * 64 + quad * 4;
    int cb = o0 + wc * 64 + col;
#pragma unroll
    for (int mi = 0; mi < 4; mi++)
#pragma unroll
        for (int r = 0; r < 4; r++) {
            int row = rb + mi * 16 + r;
#pragma unroll
            for (int ni = 0; ni < 4; ni++)
                Pw[(size_t)row * 512 + cb + ni * 16] = acc[mi][ni][r];
        }
}

// ---------------- pool5: sum 6 K-chunks + affine + lrelu + max over rows -> pooled ----------------
// 1D grid 512, XCD-pinned: z=(i>>1)&3, rest=((i>>3)<<1)|(i&1) in [0,128):
//   oc=(rest&3)*128 cols, mc=(rest>>2)*32 rows; thread: col=t&127, half=t>>7 (16 rows each)
__global__ __launch_bounds__(256) void k_pool5(const float* __restrict__ P5,
                                               const void* __restrict__ g, const void* __restrict__ bias,
                                               unsigned* __restrict__ pooledU,
                                               const int* __restrict__ flag) {
    __shared__ float red2[128];
    int isf = *flag;
    int i = blockIdx.x;
    int z = (i >> 1) & 3;
    int rest = ((i >> 3) << 1) | (i & 1);
    int oc = (rest & 3) * 128, mc = (rest >> 2) * 32;
    int t = threadIdx.x;
    int c = t & 127, h = t >> 7;
    int o = oc + c;
    float scl = ldw(g, o, isf) * BN_SCALE;
    float bb = ldw(bias, o, isf);
    const float* p0 = P5 + (size_t)z * NPTS * 512 + (size_t)(mc + h * 16) * 512 + o;
    float ym = -__builtin_inff();
    for (int r = 0; r < 16; r++) {
        const float* p = p0 + (size_t)r * 512;
        float s = p[0];
#pragma unroll
        for (int ks = 1; ks < 6; ks++) s += p[(size_t)ks * CH5];
        float v = s * scl + bb;
        v = v > 0.f ? v : 0.2f * v;
        ym = fmaxf(ym, v);
    }
    if (h == 1) red2[c] = ym;
    __syncthreads();
    if (h == 0) {
        float m = fmaxf(ym, red2[c]);
        atomicMax(&pooledU[z * 512 + o], ordf(m));
    }
}

// ---------------- final linear: coalesced wave-per-output ----------------
__global__ void k_final(const unsigned* __restrict__ pooledU, const void* __restrict__ We,
                        void* __restrict__ out, const int* __restrict__ flag) {
    __shared__ float p[512];
    int isf = *flag;
    int b = blockIdx.x >> 2, fb = blockIdx.x & 3;
    int t = threadIdx.x, w = t >> 6, l = t & 63;
    for (int i = t; i < 512; i += 256) p[i] = iordf(pooledU[b * 512 + i]);
    __syncthreads();
    for (int it = 0; it < 16; it++) {
        int f = fb * 64 + w * 16 + it;
        float s = 0.f;
        size_t base = (size_t)f * 512 + l * 8;
#pragma unroll
        for (int j = 0; j < 8; j++) s += p[l * 8 + j] * ldw(We, base + j, isf);
#pragma unroll
        for (int off = 32; off > 0; off >>= 1) s += __shfl_down(s, off);
        if (l == 0) {
            if (isf) ((float*)out)[b * 256 + f] = s;
            else     ((bf16*)out)[b * 256 + f] = f2b(s);
        }
    }
}

extern "C" void kernel_launch(void* const* d_in, const int* in_sizes, int n_in,
                              void* d_out, int out_size, void* d_ws, size_t ws_size,
                              hipStream_t stream) {
    const void* x  = d_in[0];
    const void* Wl[4] = { d_in[1], d_in[4], d_in[7], d_in[10] };
    const void* gl[4] = { d_in[2], d_in[5], d_in[8], d_in[11] };
    const void* bl[4] = { d_in[3], d_in[6], d_in[9], d_in[12] };
    const void* W5 = d_in[13];
    const void* g5 = d_in[14];
    const void* b5 = d_in[15];
    const void* We = d_in[16];

    // workspace layout (bytes), ~103.9 MB total
    char* base = (char*)d_ws;
    bf16*     xc_hi   = (bf16*)(base);                  // 7,864,320
    bf16*     xc_lo   = (bf16*)(base + 7864320);        // 7,864,320
    bf16*     xpadh   = (bf16*)(base + 15728640);       // 262,144
    bf16*     xpadl   = (bf16*)(base + 15990784);       // 262,144
    float*    Dbuf    = (float*)(base + 16252928);      // 16,777,216
    float*    Pbuf    = (float*)(base + 33030144);      // 16,777,216
    bf16*     Whi     = (bf16*)(base + 49807360);       // 1,679,360
    bf16*     Wlo     = (bf16*)(base + 51486720);       // 1,679,360
    unsigned* pooledU = (unsigned*)(base + 53493760);   // 8,192
    float*    sq      = (float*)(base + 53501952);      // 16,384
    int*      flag    = (int*)(base + 53518336);        // 4
    float*    P5      = (float*)(base + 53520384);      // 50,331,648 (6 x 8 MB conv5 partials)

    const int Kpad[4]   = { 32, 64, 128, 256 };
    const int Os[4]     = { 64, 128, 256, 512 };
    const int Woff[5]   = { 0, 4096, 20480, 86016, 348160 };
    const int colIn[4]  = { 0, 0, 64, 192 };
    const int colOut[4] = { 0, 64, 192, 448 };

    k_prep<<<3296, 256, 0, stream>>>(Wl[0], Wl[1], Wl[2], Wl[3], W5, x,
                                     Whi, Wlo, xpadh, xpadl, sq, flag, pooledU);

    for (int l = 0; l < 4; l++) {
        int O = Os[l];
        int nCol = (2 * O) >> 7;
        int nBlk = 36 + 8 * nCol;  // 44/52/68/100 -> *4 divisible by 8 for XCD decode
        const bf16* Xh = (l == 0) ? xpadh : (xc_hi + colIn[l]);
        const bf16* Xl = (l == 0) ? xpadl : (xc_lo + colIn[l]);
        int ld = (l == 0) ? 32 : 960;
        size_t xstr = (l == 0) ? (size_t)NPTS * 32 : (size_t)NPTS * 960;
        k_layer_a<<<nBlk * NB, 256, 0, stream>>>(
            Xh, Xl, ld, Kpad[l], xstr, Whi + Woff[l], Wlo + Woff[l], O, sq, Dbuf, Pbuf, flag);
        k_layer_b<<<NPTS * NB / 4, 256, 0, stream>>>(
            Dbuf, Pbuf, gl[l], bl[l], O, xc_hi + colOut[l], xc_lo + colOut[l], sq, l < 3, flag);
    }
    k_conv5<<<768, 256, 0, stream>>>(xc_hi, xc_lo, Whi + Woff[4], Wlo + Woff[4], P5, flag);
    k_pool5<<<512, 256, 0, stream>>>(P5, g5, b5, pooledU, flag);
    k_final<<<16, 256, 0, stream>>>(pooledU, We, d_out, flag);
}

// Round 11
// 318.798 us; speedup vs baseline: 1.0597x; 1.0068x over previous
//
#include <hip/hip_runtime.h>
#include <hip/hip_bf16.h>
#include <math.h>

typedef __hip_bfloat16 bf16;
typedef __bf16 v8bf __attribute__((ext_vector_type(8)));
typedef float v4f __attribute__((ext_vector_type(4)));

#define BN_SCALE 0.9999950000374997f
#define NPTS 1024
#define NB 4
#define CH5 ((size_t)4 * 1024 * 512)   // conv5 partial-chunk stride (floats)

__device__ __forceinline__ float b2f(bf16 v) { return __bfloat162float(v); }
__device__ __forceinline__ bf16 f2b(float v) { return __float2bfloat16(v); }
__device__ __forceinline__ float ldw(const void* p, size_t i, int isf) {
    return isf ? ((const float*)p)[i] : b2f(((const bf16*)p)[i]);
}
__device__ __forceinline__ unsigned ordf(float f) {
    unsigned u = __float_as_uint(f);
    return (u & 0x80000000u) ? ~u : (u | 0x80000000u);
}
__device__ __forceinline__ float iordf(unsigned u) {
    return (u & 0x80000000u) ? __uint_as_float(u ^ 0x80000000u) : __uint_as_float(~u);
}

// per-block dtype detect from first 512 shorts of x (fp32 ~113/256 implausible, bf16 ~0)
__device__ __forceinline__ int detect_isf(const void* xraw, int* cnt) {
    const unsigned short* u = (const unsigned short*)xraw;
    int t = threadIdx.x, c = 0;
    for (int i = t; i < 512; i += 256) {
        unsigned short v = u[i];
        int e = (v >> 7) & 0xFF;
        int m = v & 0x7F;
        if (e == 0xFF || e >= 141 || (e == 0 && m != 0)) c++;
    }
    cnt[t] = c;
    __syncthreads();
    for (int off = 128; off > 0; off >>= 1) {
        if (t < off) cnt[t] += cnt[t + off];
        __syncthreads();
    }
    int isf = (cnt[0] > 30) ? 1 : 0;
    __syncthreads();
    return isf;
}

// ---------------- fused prep: dtype flag + pooled init + weight splits + x pad + sq ----------------
__global__ void k_prep(const void* __restrict__ W1, const void* __restrict__ W2,
                       const void* __restrict__ W3, const void* __restrict__ W4,
                       const void* __restrict__ W5, const void* __restrict__ x,
                       bf16* __restrict__ Whi, bf16* __restrict__ Wlo,
                       bf16* __restrict__ xph, bf16* __restrict__ xpl, float* __restrict__ sq,
                       int* __restrict__ flag, unsigned* __restrict__ pooledU) {
    __shared__ int cnt[256];
    int isf = detect_isf(x, cnt);
    if (blockIdx.x == 0) {
        if (threadIdx.x == 0) *flag = isf;
        for (int i = threadIdx.x; i < 2048; i += 256) pooledU[i] = 0u;  // 0 < ordf(any finite)
    }
    int idx = blockIdx.x * 256 + threadIdx.x;
    if (idx < 839680) {
        const void* src; int C, O, Kpad, two, local;
        if (idx < 4096)        { src = W1; C = 3;   O = 64;  Kpad = 32;  two = 1; local = idx; }
        else if (idx < 20480)  { src = W2; C = 64;  O = 128; Kpad = 64;  two = 1; local = idx - 4096; }
        else if (idx < 86016)  { src = W3; C = 128; O = 256; Kpad = 128; two = 1; local = idx - 20480; }
        else if (idx < 348160) { src = W4; C = 256; O = 512; Kpad = 256; two = 1; local = idx - 86016; }
        else                   { src = W5; C = 960; O = 512; Kpad = 960; two = 0; local = idx - 348160; }
        int r = local / Kpad, c = local % Kpad;
        float wv = 0.f;
        if (c < C) {
            size_t off;
            if (two) off = (r < O) ? (size_t)r * 2 * C + c : (size_t)(r - O) * 2 * C + C + c;
            else     off = (size_t)r * C + c;
            wv = ldw(src, off, isf);
        }
        bf16 h = f2b(wv);
        Whi[idx] = h;
        Wlo[idx] = f2b(wv - b2f(h));
    } else if (idx < 843776) {
        int p = idx - 839680;       // point index: z*1024 + n
        int z = p >> 10, n = p & 1023;
        bf16* ph = xph + (size_t)z * NPTS * 32;
        bf16* pl = xpl + (size_t)z * NPTS * 32;
        float s = 0.f;
        for (int c = 0; c < 32; c++) {
            float v = (c < 3) ? ldw(x, (size_t)z * NPTS * 3 + n * 3 + c, isf) : 0.f;
            bf16 h = f2b(v);
            ph[n * 32 + c] = h;
            pl[n * 32 + c] = f2b(v - b2f(h));
            s += v * v;
        }
        sq[z * NPTS + n] = s;
    }
}

// ---- conflict-free LDS layout: k-quad-major [kq][row][8], XOR-swizzled ----
__device__ __forceinline__ int lidx(int plane, int row) {
    return ((((plane << 7) | row)) ^ (plane << 1)) << 3;
}
// staged fill split: global->regs (issue early) then regs->LDS (write late) for dbuf pipelining
struct St2 { float4 a, b; };
__device__ __forceinline__ St2 ldStage(const bf16* src, int ld) {
    int t = threadIdx.x; int r = t >> 2, kq = t & 3;
    St2 s;
    s.a = *(const float4*)(src + (size_t)r * ld + kq * 8);
    s.b = *(const float4*)(src + (size_t)(r + 64) * ld + kq * 8);
    return s;
}
__device__ __forceinline__ void stStage(bf16* dst, const St2& s) {
    int t = threadIdx.x; int r = t >> 2, kq = t & 3;
    *(float4*)(dst + lidx(kq, r)) = s.a;
    *(float4*)(dst + lidx(kq, r + 64)) = s.b;
}
// single-shot fill (conv5 keeps the proven 2-barrier structure)
__device__ __forceinline__ void fill128(bf16* dst, const bf16* src, int ld) {
    int t = threadIdx.x;
    int r = t >> 2, kq = t & 3;
    *(float4*)(dst + lidx(kq, r))      = *(const float4*)(src + (size_t)r * ld + kq * 8);
    *(float4*)(dst + lidx(kq, r + 64)) = *(const float4*)(src + (size_t)(r + 64) * ld + kq * 8);
}
// MFMA fragment: sub-tile 'sub' (16 rows of 128), lane l: row=sub*16+(l&15), k=(l>>4)*8..+7
__device__ __forceinline__ v8bf ldf(const bf16* tile, int sub, int l) {
    return *(const v8bf*)(tile + lidx(l >> 4, sub * 16 + (l & 15)));
}

// ---------------- fused layer stage A: dist (upper-tri 128x128 tiles) + st ----------------
// 1D grid, XCD-pinned: z = (i>>1)&3, bi = ((i>>3)<<1)|(i&1)  (batch z -> XCDs {2z,2z+1})
// 128x128 output tile, 4 waves in 2x2, each wave 64x64 (acc[4][4]).
// DOUBLE-BUFFERED K-loop (1 barrier/step, loads issued one step ahead): at 1 block/CU the
// 4 waves run in lockstep -> no TLP to hide HBM/L2 latency; SW pipelining is the only overlap.
__global__ __launch_bounds__(256) void k_layer_a(const bf16* __restrict__ Xhi, const bf16* __restrict__ Xlo,
                                                 int ld, int Kpad, size_t xstride,
                                                 const bf16* __restrict__ Whi, const bf16* __restrict__ Wlo,
                                                 int O, const float* __restrict__ sqg,
                                                 float* __restrict__ Dg, float* __restrict__ Pg,
                                                 const int* __restrict__ flag) {
    int i = blockIdx.x;
    int z = (i >> 1) & 3;
    int bi = ((i >> 3) << 1) | (i & 1);
    const bf16* Xh = Xhi + (size_t)z * xstride;
    const bf16* Xl = Xlo + (size_t)z * xstride;
    __shared__ alignas(16) bf16 Ah[2][4096], Al[2][4096], Bh[2][4096], Bl[2][4096];
    int w = threadIdx.x >> 6, l = threadIdx.x & 63;
    int wr = w >> 1, wc = w & 1;
    int quad = l >> 4, col = l & 15;
    v4f zero = {0.f, 0.f, 0.f, 0.f};
    v4f acc[4][4] = {{zero, zero, zero, zero}, {zero, zero, zero, zero},
                     {zero, zero, zero, zero}, {zero, zero, zero, zero}};

    if (bi < 36) {
        // ---- dist tile: triangular decode over 8x8, bx >= by ----
        int bx = 0;
        while ((((bx + 1) * (bx + 2)) >> 1) <= bi) bx++;
        int by = bi - ((bx * (bx + 1)) >> 1);
        const float* sq = sqg + z * NPTS;
        float* D = Dg + (size_t)z * NPTS * NPTS;
        int n0 = by * 128, m0 = bx * 128;
        const bf16* pAn = Xh + (size_t)n0 * ld;
        const bf16* pAm = Xh + (size_t)m0 * ld;
        const bf16* pLn = Xl + (size_t)n0 * ld;
        const bf16* pLm = Xl + (size_t)m0 * ld;
        St2 sA = ldStage(pAn, ld), sB = ldStage(pAm, ld);
        St2 sC = ldStage(pLn, ld), sD = ldStage(pLm, ld);
        stStage(Ah[0], sA); stStage(Bh[0], sB);
        stStage(Al[0], sC); stStage(Bl[0], sD);
        __syncthreads();
        int cur = 0;
        for (int k0 = 0; k0 < Kpad; k0 += 32) {
            bool more = (k0 + 32 < Kpad);
            if (more) {
                sA = ldStage(pAn + k0 + 32, ld);
                sB = ldStage(pAm + k0 + 32, ld);
                sC = ldStage(pLn + k0 + 32, ld);
                sD = ldStage(pLm + k0 + 32, ld);
            }
            v8bf ah[4], al[4];
#pragma unroll
            for (int mi = 0; mi < 4; mi++) {
                ah[mi] = ldf(Ah[cur], wr * 4 + mi, l);
                al[mi] = ldf(Al[cur], wr * 4 + mi, l);
            }
#pragma unroll
            for (int ni = 0; ni < 4; ni++) {
                v8bf bh = ldf(Bh[cur], wc * 4 + ni, l);
                v8bf bl = ldf(Bl[cur], wc * 4 + ni, l);
#pragma unroll
                for (int mi = 0; mi < 4; mi++) {
                    acc[mi][ni] = __builtin_amdgcn_mfma_f32_16x16x32_bf16(ah[mi], bh, acc[mi][ni], 0, 0, 0);
                    acc[mi][ni] = __builtin_amdgcn_mfma_f32_16x16x32_bf16(ah[mi], bl, acc[mi][ni], 0, 0, 0);
                    acc[mi][ni] = __builtin_amdgcn_mfma_f32_16x16x32_bf16(al[mi], bh, acc[mi][ni], 0, 0, 0);
                }
            }
            if (more) {
                stStage(Ah[cur ^ 1], sA); stStage(Bh[cur ^ 1], sB);
                stStage(Al[cur ^ 1], sC); stStage(Bl[cur ^ 1], sD);
            }
            __syncthreads();
            cur ^= 1;
        }
        int rb = n0 + wr * 64 + quad * 4;
        int cb = m0 + wc * 64 + col;
        float sm[4];
#pragma unroll
        for (int ni = 0; ni < 4; ni++) sm[ni] = sq[cb + ni * 16];
#pragma unroll
        for (int mi = 0; mi < 4; mi++) {
#pragma unroll
            for (int r = 0; r < 4; r++) {
                int row = rb + mi * 16 + r;
                float sn = sq[row];
#pragma unroll
                for (int ni = 0; ni < 4; ni++) {
                    float d = 2.f * acc[mi][ni][r] - sn - sm[ni];
                    int c = cb + ni * 16;
                    D[(size_t)row * NPTS + c] = d;
                    if (bx != by) D[(size_t)c * NPTS + row] = d;
                }
            }
        }
    } else {
        // ---- st tile: P[point m, weight-row n] over 2O cols ----
        int isf = *flag;
        int nCol = (2 * O) >> 7;
        int s = bi - 36;
        int n0 = (s % nCol) * 128;   // weight-row tile (over 2O)
        int m0 = (s / nCol) * 128;   // point tile (over 1024)
        int N2 = 2 * O;
        float* P = Pg + (size_t)z * NPTS * N2;
        const bf16* pXh = Xh + (size_t)m0 * ld;
        const bf16* pXl = Xl + (size_t)m0 * ld;
        const bf16* pWh = Whi + (size_t)n0 * Kpad;
        const bf16* pWl = Wlo + (size_t)n0 * Kpad;
        St2 sA = ldStage(pXh, ld), sC = ldStage(pXl, ld);
        St2 sB = ldStage(pWh, Kpad), sD;
        if (isf) sD = ldStage(pWl, Kpad);
        stStage(Ah[0], sA); stStage(Al[0], sC); stStage(Bh[0], sB);
        if (isf) stStage(Bl[0], sD);
        __syncthreads();
        int cur = 0;
        for (int k0 = 0; k0 < Kpad; k0 += 32) {
            bool more = (k0 + 32 < Kpad);
            if (more) {
                sA = ldStage(pXh + k0 + 32, ld);
                sC = ldStage(pXl + k0 + 32, ld);
                sB = ldStage(pWh + k0 + 32, Kpad);
                if (isf) sD = ldStage(pWl + k0 + 32, Kpad);
            }
            v8bf ah[4], al[4];
#pragma unroll
            for (int mi = 0; mi < 4; mi++) {
                ah[mi] = ldf(Ah[cur], wr * 4 + mi, l);
                al[mi] = ldf(Al[cur], wr * 4 + mi, l);
            }
#pragma unroll
            for (int ni = 0; ni < 4; ni++) {
                v8bf bh = ldf(Bh[cur], wc * 4 + ni, l);
#pragma unroll
                for (int mi = 0; mi < 4; mi++) {
                    acc[mi][ni] = __builtin_amdgcn_mfma_f32_16x16x32_bf16(ah[mi], bh, acc[mi][ni], 0, 0, 0);
                    acc[mi][ni] = __builtin_amdgcn_mfma_f32_16x16x32_bf16(al[mi], bh, acc[mi][ni], 0, 0, 0);
                }
                if (isf) {
                    v8bf bl = ldf(Bl[cur], wc * 4 + ni, l);
#pragma unroll
                    for (int mi = 0; mi < 4; mi++)
                        acc[mi][ni] = __builtin_amdgcn_mfma_f32_16x16x32_bf16(ah[mi], bl, acc[mi][ni], 0, 0, 0);
                }
            }
            if (more) {
                stStage(Ah[cur ^ 1], sA); stStage(Al[cur ^ 1], sC);
                stStage(Bh[cur ^ 1], sB);
                if (isf) stStage(Bl[cur ^ 1], sD);
            }
            __syncthreads();
            cur ^= 1;
        }
        int rb = m0 + wr * 64 + quad * 4;
        int cb = n0 + wc * 64 + col;
#pragma unroll
        for (int mi = 0; mi < 4; mi++)
#pragma unroll
            for (int r = 0; r < 4; r++) {
                int row = rb + mi * 16 + r;
#pragma unroll
                for (int ni = 0; ni < 4; ni++)
                    P[(size_t)row * N2 + cb + ni * 16] = acc[mi][ni][r];
            }
    }
}

// ---- argmax combine steps: (max val, min idx) is associative+commutative ----
template<int PAT>
__device__ __forceinline__ void swz_step(float& bv, int& bi) {
    float ov = __int_as_float(__builtin_amdgcn_ds_swizzle(__float_as_int(bv), PAT));
    int   oi = __builtin_amdgcn_ds_swizzle(bi, PAT);
    if (ov > bv || (ov == bv && oi < bi)) { bv = ov; bi = oi; }
}
__device__ __forceinline__ void shfl_step(float& bv, int& bi, int mask) {
    float ov = __shfl_xor(bv, mask);
    int   oi = __shfl_xor(bi, mask);
    if (ov > bv || (ov == bv && oi < bi)) { bv = ov; bi = oi; }
}
#define PICK(va, ja, vb, jb, vo, jo) { bool t_ = (vb) > (va); vo = t_ ? (vb) : (va); jo = t_ ? (jb) : (ja); }

// one gather body for column o (scl/bb preloaded); FP math identical to prior rounds
#define GATHER_BODY(o, scl, bb, doSq) do { \
    float tv = Pn[O + (o)] - Pn[(o)]; \
    float mx = -__builtin_inff(), mn = __builtin_inff(); \
    _Pragma("unroll") \
    for (int j = 0; j < 20; j++) { \
        float vv = P[offj[j] + (o)]; \
        mx = fmaxf(mx, vv); \
        mn = fminf(mn, vv); \
    } \
    float base = ((scl) >= 0.f ? mx : mn) + tv; \
    float accv = base * (scl) + (bb); \
    accv = accv > 0.f ? accv : 0.2f * accv; \
    bf16 hi = f2b(accv); \
    bf16 lo = f2b(accv - b2f(hi)); \
    xhOut[(size_t)z * NPTS * 960 + (size_t)n * 960 + (o)] = hi; \
    xlOut[(size_t)z * NPTS * 960 + (size_t)n * 960 + (o)] = lo; \
    if (doSq) { \
        float xv = b2f(hi) + b2f(lo); \
        float s2 = xv * xv; \
        _Pragma("unroll") \
        for (int off = 32; off > 0; off >>= 1) s2 += __shfl_down(s2, off); \
        if (l == 0) sqP[r][(o) >> 6] = s2; \
    } \
} while (0)

// ---------------- fused stage B: top-20 (wave per row, 4 rows/block) + gather-max ----------------
// 1D grid 1024, XCD-pinned: z = (i>>1)&3, local = ((i>>3)<<1)|(i&1); rows local*4+q (wave q)
// Selection: group-cached argmax; outcome identical to full rescan. Gather: wave-uniform row
// offsets hoisted to SGPRs; affine/lrelu after max (exact FP-monotone commute); g/bias loads
// hoisted out of the r-loop (o-only dependence; O%64==0 keeps shfl waves fully active).
__global__ __launch_bounds__(256) void k_layer_b(const float* __restrict__ Dg, const float* __restrict__ Pg,
                                                 const void* __restrict__ g, const void* __restrict__ bias,
                                                 int O, bf16* __restrict__ xhOut, bf16* __restrict__ xlOut,
                                                 float* __restrict__ sqOut, int writeSq,
                                                 const int* __restrict__ flag) {
    __shared__ int ids[4][20];
    __shared__ float sqP[4][8];
    int isf = *flag;
    int i = blockIdx.x;
    int z = (i >> 1) & 3;
    int local = ((i >> 3) << 1) | (i & 1);
    int tid = threadIdx.x;
    int wq = tid >> 6, l = tid & 63;
    int row = local * 4 + wq;

    // ---- per-wave register-resident top-20 (lane->index map bi = jj*256+l*4+q bijective
    //      over [0,1024), monotone per lane in scan order -> min-index tie-break) ----
    {
        const float* Dr = Dg + (size_t)z * NPTS * NPTS + (size_t)row * NPTS;
        float v[16];
#pragma unroll
        for (int jj = 0; jj < 4; jj++) {
            float4 f4 = *(const float4*)(Dr + jj * 256 + l * 4);
            v[jj * 4 + 0] = f4.x; v[jj * 4 + 1] = f4.y;
            v[jj * 4 + 2] = f4.z; v[jj * 4 + 3] = f4.w;
        }
        float bmv[4]; int bmj[4];
#pragma unroll
        for (int gg = 0; gg < 4; gg++) {
            float a0, a1; int j0, j1;
            PICK(v[4 * gg + 0], 4 * gg + 0, v[4 * gg + 1], 4 * gg + 1, a0, j0);
            PICK(v[4 * gg + 2], 4 * gg + 2, v[4 * gg + 3], 4 * gg + 3, a1, j1);
            PICK(a0, j0, a1, j1, bmv[gg], bmj[gg]);
        }
        for (int s = 0; s < 20; s++) {
            float t0, t1, bv; int s0, s1, bj;
            PICK(bmv[0], bmj[0], bmv[1], bmj[1], t0, s0);
            PICK(bmv[2], bmj[2], bmv[3], bmj[3], t1, s1);
            PICK(t0, s0, t1, s1, bv, bj);
            int bi = (bj >> 2) * 256 + l * 4 + (bj & 3);
            swz_step<0x041F>(bv, bi);   // xor 1
            swz_step<0x081F>(bv, bi);   // xor 2
            swz_step<0x101F>(bv, bi);   // xor 4
            swz_step<0x201F>(bv, bi);   // xor 8
            swz_step<0x401F>(bv, bi);   // xor 16
            shfl_step(bv, bi, 32);      // xor 32 -> all 64 lanes converged
            if (l == 0) ids[wq][s] = bi;
            if (((bi >> 2) & 63) == l) {               // owning lane: evict + rebuild its group
                int ej = (bi >> 8) * 4 + (bi & 3);
                int eg = ej >> 2, ek = ej & 3;
#pragma unroll
                for (int gg = 0; gg < 4; gg++) if (gg == eg) {
#pragma unroll
                    for (int kk = 0; kk < 4; kk++)
                        if (kk == ek) v[4 * gg + kk] = -__builtin_inff();
                    float a0, a1; int j0, j1;
                    PICK(v[4 * gg + 0], 4 * gg + 0, v[4 * gg + 1], 4 * gg + 1, a0, j0);
                    PICK(v[4 * gg + 2], 4 * gg + 2, v[4 * gg + 3], 4 * gg + 3, a1, j1);
                    PICK(a0, j0, a1, j1, bmv[gg], bmj[gg]);
                }
            }
        }
    }
    __syncthreads();

    // ---- gather + max (affine/lrelu AFTER max: exact FP-monotone commute) ----
    int N2 = 2 * O;
    const float* P = Pg + (size_t)z * NPTS * N2;
    int o0 = tid, o1 = tid + 256;
    int has0 = (o0 < O), has1 = (o1 < O);      // O in {64,128,256,512}: <=2 o-iterations
    float scl0 = 0.f, bb0 = 0.f, scl1 = 0.f, bb1 = 0.f;
    if (has0) { scl0 = ldw(g, o0, isf) * BN_SCALE; bb0 = ldw(bias, o0, isf); }
    if (has1) { scl1 = ldw(g, o1, isf) * BN_SCALE; bb1 = ldw(bias, o1, isf); }
#pragma unroll
    for (int r = 0; r < 4; r++) {
        int offj[20];
#pragma unroll
        for (int j = 0; j < 20; j++)
            offj[j] = __builtin_amdgcn_readfirstlane(ids[r][j]) * N2;  // SGPR row bases
        int n = local * 4 + r;
        const float* Pn = P + (size_t)n * N2;
        if (has0) GATHER_BODY(o0, scl0, bb0, writeSq);
        if (has1) GATHER_BODY(o1, scl1, bb1, 0);   // O=512 only; writeSq=0 there (l==3)
    }
    if (writeSq) {
        __syncthreads();
        if (tid < 4) {
            int nc = O >> 6;
            float tot = 0.f;
            for (int c = 0; c < nc; c++) tot += sqP[tid][c];
            sqOut[z * NPTS + local * 4 + tid] = tot;
        }
    }
}

// ---------------- conv5 via MFMA, K-split x6 (chunks of 160) -> f32 partials ----------------
// 1D grid 768, XCD-pinned: z=(i>>1)&3, rest=((i>>3)<<1)|(i&1) in [0,192):
//   ks = rest>>5 (K-chunk), tile = rest&31: m0=(tile>>2)*128, o0=(tile&3)*128
__global__ __launch_bounds__(256) void k_conv5(const bf16* __restrict__ Xhi, const bf16* __restrict__ Xlo,
                                               const bf16* __restrict__ Whi, const bf16* __restrict__ Wlo,
                                               float* __restrict__ P5,
                                               const int* __restrict__ flag) {
    int isf = *flag;
    int i = blockIdx.x;
    int z = (i >> 1) & 3;
    int rest = ((i >> 3) << 1) | (i & 1);
    int ks = rest >> 5;
    int tile = rest & 31;
    int m0 = (tile >> 2) * 128, o0 = (tile & 3) * 128;
    const bf16* Xh = Xhi + (size_t)z * NPTS * 960;
    const bf16* Xl = Xlo + (size_t)z * NPTS * 960;
    __shared__ alignas(16) bf16 Ah[4096], Al[4096], Bh[4096], Bl[4096];
    int w = threadIdx.x >> 6, l = threadIdx.x & 63;
    int wr = w >> 1, wc = w & 1;
    int quad = l >> 4, col = l & 15;
    v4f zero = {0.f, 0.f, 0.f, 0.f};
    v4f acc[4][4] = {{zero, zero, zero, zero}, {zero, zero, zero, zero},
                     {zero, zero, zero, zero}, {zero, zero, zero, zero}};
    int kbeg = ks * 160, kend = kbeg + 160;
    for (int k0 = kbeg; k0 < kend; k0 += 32) {
        __syncthreads();
        fill128(Ah, Xh + (size_t)m0 * 960 + k0, 960);
        fill128(Al, Xl + (size_t)m0 * 960 + k0, 960);
        fill128(Bh, Whi + (size_t)o0 * 960 + k0, 960);
        if (isf) fill128(Bl, Wlo + (size_t)o0 * 960 + k0, 960);
        __syncthreads();
        v8bf ah[4], al[4];
#pragma unroll
        for (int mi = 0; mi < 4; mi++) {
            ah[mi] = ldf(Ah, wr * 4 + mi, l);
            al[mi] = ldf(Al, wr * 4 + mi, l);
        }
#pragma unroll
        for (int ni = 0; ni < 4; ni++) {
            v8bf bh = ldf(Bh, wc * 4 + ni, l);
#pragma unroll
            for (int mi = 0; mi < 4; mi++) {
                acc[mi][ni] = __builtin_amdgcn_mfma_f32_16x16x32_bf16(ah[mi], bh, acc[mi][ni], 0, 0, 0);
                acc[mi][ni] = __builtin_amdgcn_mfma_f32_16x16x32_bf16(al[mi], bh, acc[mi][ni], 0, 0, 0);
            }
            if (isf) {
                v8bf bl = ldf(Bl, wc * 4 + ni, l);
#pragma unroll
                for (int mi = 0; mi < 4; mi++)
                    acc[mi][ni] = __builtin_amdgcn_mfma_f32_16x16x32_bf16(ah[mi], bl, acc[mi][ni], 0, 0, 0);
            }
        }
    }
    // write f32 partial tile (disjoint per (ks,z,tile) -> no atomics)
    float* Pw = P5 + (size_t)ks * CH5 + (size_t)z * NPTS * 512;
    int rb = m0 + wr * 64 + quad * 4;
    int cb = o0 + wc * 64 + col;
#pragma unroll
    for (int mi = 0; mi < 4; mi++)
#pragma unroll
        for (int r = 0; r < 4; r++) {
            int row = rb + mi * 16 + r;
#pragma unroll
            for (int ni = 0; ni < 4; ni++)
                Pw[(size_t)row * 512 + cb + ni * 16] = acc[mi][ni][r];
        }
}

// ---------------- pool5: sum 6 K-chunks + affine + lrelu + max over rows -> pooled ----------------
// 1D grid 512, XCD-pinned: z=(i>>1)&3, rest=((i>>3)<<1)|(i&1) in [0,128):
//   oc=(rest&3)*128 cols, mc=(rest>>2)*32 rows; thread: col=t&127, half=t>>7 (16 rows each)
__global__ __launch_bounds__(256) void k_pool5(const float* __restrict__ P5,
                                               const void* __restrict__ g, const void* __restrict__ bias,
                                               unsigned* __restrict__ pooledU,
                                               const int* __restrict__ flag) {
    __shared__ float red2[128];
    int isf = *flag;
    int i = blockIdx.x;
    int z = (i >> 1) & 3;
    int rest = ((i >> 3) << 1) | (i & 1);
    int oc = (rest & 3) * 128, mc = (rest >> 2) * 32;
    int t = threadIdx.x;
    int c = t & 127, h = t >> 7;
    int o = oc + c;
    float scl = ldw(g, o, isf) * BN_SCALE;
    float bb = ldw(bias, o, isf);
    const float* p0 = P5 + (size_t)z * NPTS * 512 + (size_t)(mc + h * 16) * 512 + o;
    float ym = -__builtin_inff();
    for (int r = 0; r < 16; r++) {
        const float* p = p0 + (size_t)r * 512;
        float s = p[0];
#pragma unroll
        for (int ks = 1; ks < 6; ks++) s += p[(size_t)ks * CH5];
        float v = s * scl + bb;
        v = v > 0.f ? v : 0.2f * v;
        ym = fmaxf(ym, v);
    }
    if (h == 1) red2[c] = ym;
    __syncthreads();
    if (h == 0) {
        float m = fmaxf(ym, red2[c]);
        atomicMax(&pooledU[z * 512 + o], ordf(m));
    }
}

// ---------------- final linear: coalesced wave-per-output ----------------
__global__ void k_final(const unsigned* __restrict__ pooledU, const void* __restrict__ We,
                        void* __restrict__ out, const int* __restrict__ flag) {
    __shared__ float p[512];
    int isf = *flag;
    int b = blockIdx.x >> 2, fb = blockIdx.x & 3;
    int t = threadIdx.x, w = t >> 6, l = t & 63;
    for (int i = t; i < 512; i += 256) p[i] = iordf(pooledU[b * 512 + i]);
    __syncthreads();
    for (int it = 0; it < 16; it++) {
        int f = fb * 64 + w * 16 + it;
        float s = 0.f;
        size_t base = (size_t)f * 512 + l * 8;
#pragma unroll
        for (int j = 0; j < 8; j++) s += p[l * 8 + j] * ldw(We, base + j, isf);
#pragma unroll
        for (int off = 32; off > 0; off >>= 1) s += __shfl_down(s, off);
        if (l == 0) {
            if (isf) ((float*)out)[b * 256 + f] = s;
            else     ((bf16*)out)[b * 256 + f] = f2b(s);
        }
    }
}

extern "C" void kernel_launch(void* const* d_in, const int* in_sizes, int n_in,
                              void* d_out, int out_size, void* d_ws, size_t ws_size,
                              hipStream_t stream) {
    const void* x  = d_in[0];
    const void* Wl[4] = { d_in[1], d_in[4], d_in[7], d_in[10] };
    const void* gl[4] = { d_in[2], d_in[5], d_in[8], d_in[11] };
    const void* bl[4] = { d_in[3], d_in[6], d_in[9], d_in[12] };
    const void* W5 = d_in[13];
    const void* g5 = d_in[14];
    const void* b5 = d_in[15];
    const void* We = d_in[16];

    // workspace layout (bytes), ~103.9 MB total
    char* base = (char*)d_ws;
    bf16*     xc_hi   = (bf16*)(base);                  // 7,864,320
    bf16*     xc_lo   = (bf16*)(base + 7864320);        // 7,864,320
    bf16*     xpadh   = (bf16*)(base + 15728640);       // 262,144
    bf16*     xpadl   = (bf16*)(base + 15990784);       // 262,144
    float*    Dbuf    = (float*)(base + 16252928);      // 16,777,216
    float*    Pbuf    = (float*)(base + 33030144);      // 16,777,216
    bf16*     Whi     = (bf16*)(base + 49807360);       // 1,679,360
    bf16*     Wlo     = (bf16*)(base + 51486720);       // 1,679,360
    unsigned* pooledU = (unsigned*)(base + 53493760);   // 8,192
    float*    sq      = (float*)(base + 53501952);      // 16,384
    int*      flag    = (int*)(base + 53518336);        // 4
    float*    P5      = (float*)(base + 53520384);      // 50,331,648 (6 x 8 MB conv5 partials)

    const int Kpad[4]   = { 32, 64, 128, 256 };
    const int Os[4]     = { 64, 128, 256, 512 };
    const int Woff[5]   = { 0, 4096, 20480, 86016, 348160 };
    const int colIn[4]  = { 0, 0, 64, 192 };
    const int colOut[4] = { 0, 64, 192, 448 };

    k_prep<<<3296, 256, 0, stream>>>(Wl[0], Wl[1], Wl[2], Wl[3], W5, x,
                                     Whi, Wlo, xpadh, xpadl, sq, flag, pooledU);

    for (int l = 0; l < 4; l++) {
        int O = Os[l];
        int nCol = (2 * O) >> 7;
        int nBlk = 36 + 8 * nCol;  // 44/52/68/100 -> *4 divisible by 8 for XCD decode
        const bf16* Xh = (l == 0) ? xpadh : (xc_hi + colIn[l]);
        const bf16* Xl = (l == 0) ? xpadl : (xc_lo + colIn[l]);
        int ld = (l == 0) ? 32 : 960;
        size_t xstr = (l == 0) ? (size_t)NPTS * 32 : (size_t)NPTS * 960;
        k_layer_a<<<nBlk * NB, 256, 0, stream>>>(
            Xh, Xl, ld, Kpad[l], xstr, Whi + Woff[l], Wlo + Woff[l], O, sq, Dbuf, Pbuf, flag);
        k_layer_b<<<NPTS * NB / 4, 256, 0, stream>>>(
            Dbuf, Pbuf, gl[l], bl[l], O, xc_hi + colOut[l], xc_lo + colOut[l], sq, l < 3, flag);
    }
    k_conv5<<<768, 256, 0, stream>>>(xc_hi, xc_lo, Whi + Woff[4], Wlo + Woff[4], P5, flag);
    k_pool5<<<512, 256, 0, stream>>>(P5, g5, b5, pooledU, flag);
    k_final<<<16, 256, 0, stream>>>(pooledU, We, d_out, flag);
}

// Round 12
// 314.779 us; speedup vs baseline: 1.0733x; 1.0128x over previous
//
#include <hip/hip_runtime.h>
#include <hip/hip_bf16.h>
#include <math.h>

typedef __hip_bfloat16 bf16;
typedef __bf16 v8bf __attribute__((ext_vector_type(8)));
typedef float v4f __attribute__((ext_vector_type(4)));

#define BN_SCALE 0.9999950000374997f
#define NPTS 1024
#define NB 4
#define CH5 ((size_t)4 * 1024 * 512)   // conv5 partial-chunk stride (floats)

__device__ __forceinline__ float b2f(bf16 v) { return __bfloat162float(v); }
__device__ __forceinline__ bf16 f2b(float v) { return __float2bfloat16(v); }
__device__ __forceinline__ float ldw(const void* p, size_t i, int isf) {
    return isf ? ((const float*)p)[i] : b2f(((const bf16*)p)[i]);
}
__device__ __forceinline__ unsigned ordf(float f) {
    unsigned u = __float_as_uint(f);
    return (u & 0x80000000u) ? ~u : (u | 0x80000000u);
}
__device__ __forceinline__ float iordf(unsigned u) {
    return (u & 0x80000000u) ? __uint_as_float(u ^ 0x80000000u) : __uint_as_float(~u);
}

// per-block dtype detect from first 512 shorts of x (fp32 ~113/256 implausible, bf16 ~0)
__device__ __forceinline__ int detect_isf(const void* xraw, int* cnt) {
    const unsigned short* u = (const unsigned short*)xraw;
    int t = threadIdx.x, c = 0;
    for (int i = t; i < 512; i += 256) {
        unsigned short v = u[i];
        int e = (v >> 7) & 0xFF;
        int m = v & 0x7F;
        if (e == 0xFF || e >= 141 || (e == 0 && m != 0)) c++;
    }
    cnt[t] = c;
    __syncthreads();
    for (int off = 128; off > 0; off >>= 1) {
        if (t < off) cnt[t] += cnt[t + off];
        __syncthreads();
    }
    int isf = (cnt[0] > 30) ? 1 : 0;
    __syncthreads();
    return isf;
}

// ---------------- fused prep: dtype flag + pooled init + weight splits + x pad + sq ----------------
__global__ void k_prep(const void* __restrict__ W1, const void* __restrict__ W2,
                       const void* __restrict__ W3, const void* __restrict__ W4,
                       const void* __restrict__ W5, const void* __restrict__ x,
                       bf16* __restrict__ Whi, bf16* __restrict__ Wlo,
                       bf16* __restrict__ xph, bf16* __restrict__ xpl, float* __restrict__ sq,
                       int* __restrict__ flag, unsigned* __restrict__ pooledU) {
    __shared__ int cnt[256];
    int isf = detect_isf(x, cnt);
    if (blockIdx.x == 0) {
        if (threadIdx.x == 0) *flag = isf;
        for (int i = threadIdx.x; i < 2048; i += 256) pooledU[i] = 0u;  // 0 < ordf(any finite)
    }
    int idx = blockIdx.x * 256 + threadIdx.x;
    if (idx < 839680) {
        const void* src; int C, O, Kpad, two, local;
        if (idx < 4096)        { src = W1; C = 3;   O = 64;  Kpad = 32;  two = 1; local = idx; }
        else if (idx < 20480)  { src = W2; C = 64;  O = 128; Kpad = 64;  two = 1; local = idx - 4096; }
        else if (idx < 86016)  { src = W3; C = 128; O = 256; Kpad = 128; two = 1; local = idx - 20480; }
        else if (idx < 348160) { src = W4; C = 256; O = 512; Kpad = 256; two = 1; local = idx - 86016; }
        else                   { src = W5; C = 960; O = 512; Kpad = 960; two = 0; local = idx - 348160; }
        int r = local / Kpad, c = local % Kpad;
        float wv = 0.f;
        if (c < C) {
            size_t off;
            if (two) off = (r < O) ? (size_t)r * 2 * C + c : (size_t)(r - O) * 2 * C + C + c;
            else     off = (size_t)r * C + c;
            wv = ldw(src, off, isf);
        }
        bf16 h = f2b(wv);
        Whi[idx] = h;
        Wlo[idx] = f2b(wv - b2f(h));
    } else if (idx < 843776) {
        int p = idx - 839680;       // point index: z*1024 + n
        int z = p >> 10, n = p & 1023;
        bf16* ph = xph + (size_t)z * NPTS * 32;
        bf16* pl = xpl + (size_t)z * NPTS * 32;
        float s = 0.f;
        for (int c = 0; c < 32; c++) {
            float v = (c < 3) ? ldw(x, (size_t)z * NPTS * 3 + n * 3 + c, isf) : 0.f;
            bf16 h = f2b(v);
            ph[n * 32 + c] = h;
            pl[n * 32 + c] = f2b(v - b2f(h));
            s += v * v;
        }
        sq[z * NPTS + n] = s;
    }
}

// ---- conflict-free LDS layout: k-quad-major [kq][row][8], XOR-swizzled ----
__device__ __forceinline__ int lidx(int plane, int row) {
    return ((((plane << 7) | row)) ^ (plane << 1)) << 3;
}
// staged fill split: global->regs (issue early) then regs->LDS (write late) for dbuf pipelining
struct St2 { float4 a, b; };
__device__ __forceinline__ St2 ldStage(const bf16* src, int ld) {
    int t = threadIdx.x; int r = t >> 2, kq = t & 3;
    St2 s;
    s.a = *(const float4*)(src + (size_t)r * ld + kq * 8);
    s.b = *(const float4*)(src + (size_t)(r + 64) * ld + kq * 8);
    return s;
}
__device__ __forceinline__ void stStage(bf16* dst, const St2& s) {
    int t = threadIdx.x; int r = t >> 2, kq = t & 3;
    *(float4*)(dst + lidx(kq, r)) = s.a;
    *(float4*)(dst + lidx(kq, r + 64)) = s.b;
}
// single-shot fill (conv5 keeps the proven 2-barrier structure)
__device__ __forceinline__ void fill128(bf16* dst, const bf16* src, int ld) {
    int t = threadIdx.x;
    int r = t >> 2, kq = t & 3;
    *(float4*)(dst + lidx(kq, r))      = *(const float4*)(src + (size_t)r * ld + kq * 8);
    *(float4*)(dst + lidx(kq, r + 64)) = *(const float4*)(src + (size_t)(r + 64) * ld + kq * 8);
}
// MFMA fragment: sub-tile 'sub' (16 rows of 128), lane l: row=sub*16+(l&15), k=(l>>4)*8..+7
__device__ __forceinline__ v8bf ldf(const bf16* tile, int sub, int l) {
    return *(const v8bf*)(tile + lidx(l >> 4, sub * 16 + (l & 15)));
}

// ---------------- fused layer stage A: dist (upper-tri 128x128 tiles) + st ----------------
// 1D grid, XCD-pinned: z = (i>>1)&3, bi = ((i>>3)<<1)|(i&1)  (batch z -> XCDs {2z,2z+1})
// 128x128 output tile, 4 waves in 2x2, each wave 64x64 (acc[4][4]).
// Double-buffered K-loop (1 barrier/step, loads issued one step ahead).
__global__ __launch_bounds__(256) void k_layer_a(const bf16* __restrict__ Xhi, const bf16* __restrict__ Xlo,
                                                 int ld, int Kpad, size_t xstride,
                                                 const bf16* __restrict__ Whi, const bf16* __restrict__ Wlo,
                                                 int O, const float* __restrict__ sqg,
                                                 float* __restrict__ Dg, float* __restrict__ Pg,
                                                 const int* __restrict__ flag) {
    int i = blockIdx.x;
    int z = (i >> 1) & 3;
    int bi = ((i >> 3) << 1) | (i & 1);
    const bf16* Xh = Xhi + (size_t)z * xstride;
    const bf16* Xl = Xlo + (size_t)z * xstride;
    __shared__ alignas(16) bf16 Ah[2][4096], Al[2][4096], Bh[2][4096], Bl[2][4096];
    int w = threadIdx.x >> 6, l = threadIdx.x & 63;
    int wr = w >> 1, wc = w & 1;
    int quad = l >> 4, col = l & 15;
    v4f zero = {0.f, 0.f, 0.f, 0.f};
    v4f acc[4][4] = {{zero, zero, zero, zero}, {zero, zero, zero, zero},
                     {zero, zero, zero, zero}, {zero, zero, zero, zero}};

    if (bi < 36) {
        // ---- dist tile: triangular decode over 8x8, bx >= by ----
        int bx = 0;
        while ((((bx + 1) * (bx + 2)) >> 1) <= bi) bx++;
        int by = bi - ((bx * (bx + 1)) >> 1);
        const float* sq = sqg + z * NPTS;
        float* D = Dg + (size_t)z * NPTS * NPTS;
        int n0 = by * 128, m0 = bx * 128;
        const bf16* pAn = Xh + (size_t)n0 * ld;
        const bf16* pAm = Xh + (size_t)m0 * ld;
        const bf16* pLn = Xl + (size_t)n0 * ld;
        const bf16* pLm = Xl + (size_t)m0 * ld;
        St2 sA = ldStage(pAn, ld), sB = ldStage(pAm, ld);
        St2 sC = ldStage(pLn, ld), sD = ldStage(pLm, ld);
        stStage(Ah[0], sA); stStage(Bh[0], sB);
        stStage(Al[0], sC); stStage(Bl[0], sD);
        __syncthreads();
        int cur = 0;
        for (int k0 = 0; k0 < Kpad; k0 += 32) {
            bool more = (k0 + 32 < Kpad);
            if (more) {
                sA = ldStage(pAn + k0 + 32, ld);
                sB = ldStage(pAm + k0 + 32, ld);
                sC = ldStage(pLn + k0 + 32, ld);
                sD = ldStage(pLm + k0 + 32, ld);
            }
            v8bf ah[4], al[4];
#pragma unroll
            for (int mi = 0; mi < 4; mi++) {
                ah[mi] = ldf(Ah[cur], wr * 4 + mi, l);
                al[mi] = ldf(Al[cur], wr * 4 + mi, l);
            }
#pragma unroll
            for (int ni = 0; ni < 4; ni++) {
                v8bf bh = ldf(Bh[cur], wc * 4 + ni, l);
                v8bf bl = ldf(Bl[cur], wc * 4 + ni, l);
#pragma unroll
                for (int mi = 0; mi < 4; mi++) {
                    acc[mi][ni] = __builtin_amdgcn_mfma_f32_16x16x32_bf16(ah[mi], bh, acc[mi][ni], 0, 0, 0);
                    acc[mi][ni] = __builtin_amdgcn_mfma_f32_16x16x32_bf16(ah[mi], bl, acc[mi][ni], 0, 0, 0);
                    acc[mi][ni] = __builtin_amdgcn_mfma_f32_16x16x32_bf16(al[mi], bh, acc[mi][ni], 0, 0, 0);
                }
            }
            if (more) {
                stStage(Ah[cur ^ 1], sA); stStage(Bh[cur ^ 1], sB);
                stStage(Al[cur ^ 1], sC); stStage(Bl[cur ^ 1], sD);
            }
            __syncthreads();
            cur ^= 1;
        }
        int rb = n0 + wr * 64 + quad * 4;
        int cb = m0 + wc * 64 + col;
        float sm[4];
#pragma unroll
        for (int ni = 0; ni < 4; ni++) sm[ni] = sq[cb + ni * 16];
#pragma unroll
        for (int mi = 0; mi < 4; mi++) {
#pragma unroll
            for (int r = 0; r < 4; r++) {
                int row = rb + mi * 16 + r;
                float sn = sq[row];
#pragma unroll
                for (int ni = 0; ni < 4; ni++) {
                    float d = 2.f * acc[mi][ni][r] - sn - sm[ni];
                    int c = cb + ni * 16;
                    D[(size_t)row * NPTS + c] = d;
                    if (bx != by) D[(size_t)c * NPTS + row] = d;
                }
            }
        }
    } else {
        // ---- st tile: P[point m, weight-row n] over 2O cols ----
        int isf = *flag;
        int nCol = (2 * O) >> 7;
        int s = bi - 36;
        int n0 = (s % nCol) * 128;   // weight-row tile (over 2O)
        int m0 = (s / nCol) * 128;   // point tile (over 1024)
        int N2 = 2 * O;
        float* P = Pg + (size_t)z * NPTS * N2;
        const bf16* pXh = Xh + (size_t)m0 * ld;
        const bf16* pXl = Xl + (size_t)m0 * ld;
        const bf16* pWh = Whi + (size_t)n0 * Kpad;
        const bf16* pWl = Wlo + (size_t)n0 * Kpad;
        St2 sA = ldStage(pXh, ld), sC = ldStage(pXl, ld);
        St2 sB = ldStage(pWh, Kpad), sD;
        if (isf) sD = ldStage(pWl, Kpad);
        stStage(Ah[0], sA); stStage(Al[0], sC); stStage(Bh[0], sB);
        if (isf) stStage(Bl[0], sD);
        __syncthreads();
        int cur = 0;
        for (int k0 = 0; k0 < Kpad; k0 += 32) {
            bool more = (k0 + 32 < Kpad);
            if (more) {
                sA = ldStage(pXh + k0 + 32, ld);
                sC = ldStage(pXl + k0 + 32, ld);
                sB = ldStage(pWh + k0 + 32, Kpad);
                if (isf) sD = ldStage(pWl + k0 + 32, Kpad);
            }
            v8bf ah[4], al[4];
#pragma unroll
            for (int mi = 0; mi < 4; mi++) {
                ah[mi] = ldf(Ah[cur], wr * 4 + mi, l);
                al[mi] = ldf(Al[cur], wr * 4 + mi, l);
            }
#pragma unroll
            for (int ni = 0; ni < 4; ni++) {
                v8bf bh = ldf(Bh[cur], wc * 4 + ni, l);
#pragma unroll
                for (int mi = 0; mi < 4; mi++) {
                    acc[mi][ni] = __builtin_amdgcn_mfma_f32_16x16x32_bf16(ah[mi], bh, acc[mi][ni], 0, 0, 0);
                    acc[mi][ni] = __builtin_amdgcn_mfma_f32_16x16x32_bf16(al[mi], bh, acc[mi][ni], 0, 0, 0);
                }
                if (isf) {
                    v8bf bl = ldf(Bl[cur], wc * 4 + ni, l);
#pragma unroll
                    for (int mi = 0; mi < 4; mi++)
                        acc[mi][ni] = __builtin_amdgcn_mfma_f32_16x16x32_bf16(ah[mi], bl, acc[mi][ni], 0, 0, 0);
                }
            }
            if (more) {
                stStage(Ah[cur ^ 1], sA); stStage(Al[cur ^ 1], sC);
                stStage(Bh[cur ^ 1], sB);
                if (isf) stStage(Bl[cur ^ 1], sD);
            }
            __syncthreads();
            cur ^= 1;
        }
        int rb = m0 + wr * 64 + quad * 4;
        int cb = n0 + wc * 64 + col;
#pragma unroll
        for (int mi = 0; mi < 4; mi++)
#pragma unroll
            for (int r = 0; r < 4; r++) {
                int row = rb + mi * 16 + r;
#pragma unroll
                for (int ni = 0; ni < 4; ni++)
                    P[(size_t)row * N2 + cb + ni * 16] = acc[mi][ni][r];
            }
    }
}

// ---- argmax combine steps: (max val, min idx) is associative+commutative ----
template<int PAT>
__device__ __forceinline__ void swz_step(float& bv, int& bi) {
    float ov = __int_as_float(__builtin_amdgcn_ds_swizzle(__float_as_int(bv), PAT));
    int   oi = __builtin_amdgcn_ds_swizzle(bi, PAT);
    if (ov > bv || (ov == bv && oi < bi)) { bv = ov; bi = oi; }
}
__device__ __forceinline__ void shfl_step(float& bv, int& bi, int mask) {
    float ov = __shfl_xor(bv, mask);
    int   oi = __shfl_xor(bi, mask);
    if (ov > bv || (ov == bv && oi < bi)) { bv = ov; bi = oi; }
}
#define PICK(va, ja, vb, jb, vo, jo) { bool t_ = (vb) > (va); vo = t_ ? (vb) : (va); jo = t_ ? (jb) : (ja); }

// ---------------- fused stage B: top-20 + gather-max, WAVE-PER-ROW end-to-end ----------------
// 1D grid 1024, XCD-pinned: z = (i>>1)&3, local = ((i>>3)<<1)|(i&1); wave q owns row local*4+q.
// No inter-wave barriers: each wave selects its row's top-20 (ids slot wave-private in LDS),
// then gathers its own row over 64-col chunks. Waves desynchronize -> selection(VALU) overlaps
// gather(loads) across waves. sq chunk-tree + ascending-chunk serial sum: FP order identical
// to the previous layout (same 64-lane shfl_down tree over the same values, same chunk order).
__global__ __launch_bounds__(256) void k_layer_b(const float* __restrict__ Dg, const float* __restrict__ Pg,
                                                 const void* __restrict__ g, const void* __restrict__ bias,
                                                 int O, bf16* __restrict__ xhOut, bf16* __restrict__ xlOut,
                                                 float* __restrict__ sqOut, int writeSq,
                                                 const int* __restrict__ flag) {
    __shared__ int ids[4][20];
    int isf = *flag;
    int i = blockIdx.x;
    int z = (i >> 1) & 3;
    int local = ((i >> 3) << 1) | (i & 1);
    int tid = threadIdx.x;
    int wq = tid >> 6, l = tid & 63;
    int row = local * 4 + wq;

    // ---- per-wave register-resident top-20 (lane->index map bi = jj*256+l*4+q bijective
    //      over [0,1024), monotone per lane in scan order -> min-index tie-break) ----
    {
        const float* Dr = Dg + (size_t)z * NPTS * NPTS + (size_t)row * NPTS;
        float v[16];
#pragma unroll
        for (int jj = 0; jj < 4; jj++) {
            float4 f4 = *(const float4*)(Dr + jj * 256 + l * 4);
            v[jj * 4 + 0] = f4.x; v[jj * 4 + 1] = f4.y;
            v[jj * 4 + 2] = f4.z; v[jj * 4 + 3] = f4.w;
        }
        float bmv[4]; int bmj[4];
#pragma unroll
        for (int gg = 0; gg < 4; gg++) {
            float a0, a1; int j0, j1;
            PICK(v[4 * gg + 0], 4 * gg + 0, v[4 * gg + 1], 4 * gg + 1, a0, j0);
            PICK(v[4 * gg + 2], 4 * gg + 2, v[4 * gg + 3], 4 * gg + 3, a1, j1);
            PICK(a0, j0, a1, j1, bmv[gg], bmj[gg]);
        }
        for (int s = 0; s < 20; s++) {
            float t0, t1, bv; int s0, s1, bj;
            PICK(bmv[0], bmj[0], bmv[1], bmj[1], t0, s0);
            PICK(bmv[2], bmj[2], bmv[3], bmj[3], t1, s1);
            PICK(t0, s0, t1, s1, bv, bj);
            int bi = (bj >> 2) * 256 + l * 4 + (bj & 3);
            swz_step<0x041F>(bv, bi);   // xor 1
            swz_step<0x081F>(bv, bi);   // xor 2
            swz_step<0x101F>(bv, bi);   // xor 4
            swz_step<0x201F>(bv, bi);   // xor 8
            swz_step<0x401F>(bv, bi);   // xor 16
            shfl_step(bv, bi, 32);      // xor 32 -> all 64 lanes converged
            if (l == 0) ids[wq][s] = bi;   // wave-private slot: no cross-wave barrier needed
            if (((bi >> 2) & 63) == l) {   // owning lane: evict + rebuild its group
                int ej = (bi >> 8) * 4 + (bi & 3);
                int eg = ej >> 2, ek = ej & 3;
#pragma unroll
                for (int gg = 0; gg < 4; gg++) if (gg == eg) {
#pragma unroll
                    for (int kk = 0; kk < 4; kk++)
                        if (kk == ek) v[4 * gg + kk] = -__builtin_inff();
                    float a0, a1; int j0, j1;
                    PICK(v[4 * gg + 0], 4 * gg + 0, v[4 * gg + 1], 4 * gg + 1, a0, j0);
                    PICK(v[4 * gg + 2], 4 * gg + 2, v[4 * gg + 3], 4 * gg + 3, a1, j1);
                    PICK(a0, j0, a1, j1, bmv[gg], bmj[gg]);
                }
            }
        }
    }

    // ---- gather + max for THIS wave's row (affine/lrelu AFTER max: exact FP-monotone commute) ----
    int N2 = 2 * O;
    const float* P = Pg + (size_t)z * NPTS * N2;
    int offj[20];
#pragma unroll
    for (int j = 0; j < 20; j++)
        offj[j] = __builtin_amdgcn_readfirstlane(ids[wq][j]) * N2;  // SGPR row bases
    int n = row;
    const float* Pn = P + (size_t)n * N2;
    float tot = 0.f;
    int nc = O >> 6;
    for (int c = 0; c < nc; c++) {
        int o = c * 64 + l;
        float tv = Pn[O + o] - Pn[o];
        float mx = -__builtin_inff(), mn = __builtin_inff();
#pragma unroll
        for (int j = 0; j < 20; j++) {
            float vv = P[offj[j] + o];
            mx = fmaxf(mx, vv);
            mn = fminf(mn, vv);
        }
        float scl = ldw(g, o, isf) * BN_SCALE;
        float bb = ldw(bias, o, isf);
        float base = (scl >= 0.f ? mx : mn) + tv;
        float accv = base * scl + bb;
        accv = accv > 0.f ? accv : 0.2f * accv;
        bf16 hi = f2b(accv);
        bf16 lo = f2b(accv - b2f(hi));
        xhOut[(size_t)z * NPTS * 960 + (size_t)n * 960 + o] = hi;
        xlOut[(size_t)z * NPTS * 960 + (size_t)n * 960 + o] = lo;
        if (writeSq) {
            float xv = b2f(hi) + b2f(lo);
            float s2 = xv * xv;
#pragma unroll
            for (int off = 32; off > 0; off >>= 1) s2 += __shfl_down(s2, off);
            if (l == 0) tot += s2;       // ascending chunk order: same serial FP sum as before
        }
    }
    if (writeSq && l == 0) sqOut[z * NPTS + row] = tot;
}

// ---------------- conv5 via MFMA, K-split x6 (chunks of 160) -> f32 partials ----------------
// 1D grid 768, XCD-pinned: z=(i>>1)&3, rest=((i>>3)<<1)|(i&1) in [0,192):
//   ks = rest>>5 (K-chunk), tile = rest&31: m0=(tile>>2)*128, o0=(tile&3)*128
__global__ __launch_bounds__(256) void k_conv5(const bf16* __restrict__ Xhi, const bf16* __restrict__ Xlo,
                                               const bf16* __restrict__ Whi, const bf16* __restrict__ Wlo,
                                               float* __restrict__ P5,
                                               const int* __restrict__ flag) {
    int isf = *flag;
    int i = blockIdx.x;
    int z = (i >> 1) & 3;
    int rest = ((i >> 3) << 1) | (i & 1);
    int ks = rest >> 5;
    int tile = rest & 31;
    int m0 = (tile >> 2) * 128, o0 = (tile & 3) * 128;
    const bf16* Xh = Xhi + (size_t)z * NPTS * 960;
    const bf16* Xl = Xlo + (size_t)z * NPTS * 960;
    __shared__ alignas(16) bf16 Ah[4096], Al[4096], Bh[4096], Bl[4096];
    int w = threadIdx.x >> 6, l = threadIdx.x & 63;
    int wr = w >> 1, wc = w & 1;
    int quad = l >> 4, col = l & 15;
    v4f zero = {0.f, 0.f, 0.f, 0.f};
    v4f acc[4][4] = {{zero, zero, zero, zero}, {zero, zero, zero, zero},
                     {zero, zero, zero, zero}, {zero, zero, zero, zero}};
    int kbeg = ks * 160, kend = kbeg + 160;
    for (int k0 = kbeg; k0 < kend; k0 += 32) {
        __syncthreads();
        fill128(Ah, Xh + (size_t)m0 * 960 + k0, 960);
        fill128(Al, Xl + (size_t)m0 * 960 + k0, 960);
        fill128(Bh, Whi + (size_t)o0 * 960 + k0, 960);
        if (isf) fill128(Bl, Wlo + (size_t)o0 * 960 + k0, 960);
        __syncthreads();
        v8bf ah[4], al[4];
#pragma unroll
        for (int mi = 0; mi < 4; mi++) {
            ah[mi] = ldf(Ah, wr * 4 + mi, l);
            al[mi] = ldf(Al, wr * 4 + mi, l);
        }
#pragma unroll
        for (int ni = 0; ni < 4; ni++) {
            v8bf bh = ldf(Bh, wc * 4 + ni, l);
#pragma unroll
            for (int mi = 0; mi < 4; mi++) {
                acc[mi][ni] = __builtin_amdgcn_mfma_f32_16x16x32_bf16(ah[mi], bh, acc[mi][ni], 0, 0, 0);
                acc[mi][ni] = __builtin_amdgcn_mfma_f32_16x16x32_bf16(al[mi], bh, acc[mi][ni], 0, 0, 0);
            }
            if (isf) {
                v8bf bl = ldf(Bl, wc * 4 + ni, l);
#pragma unroll
                for (int mi = 0; mi < 4; mi++)
                    acc[mi][ni] = __builtin_amdgcn_mfma_f32_16x16x32_bf16(ah[mi], bl, acc[mi][ni], 0, 0, 0);
            }
        }
    }
    // write f32 partial tile (disjoint per (ks,z,tile) -> no atomics)
    float* Pw = P5 + (size_t)ks * CH5 + (size_t)z * NPTS * 512;
    int rb = m0 + wr * 64 + quad * 4;
    int cb = o0 + wc * 64 + col;
#pragma unroll
    for (int mi = 0; mi < 4; mi++)
#pragma unroll
        for (int r = 0; r < 4; r++) {
            int row = rb + mi * 16 + r;
#pragma unroll
            for (int ni = 0; ni < 4; ni++)
                Pw[(size_t)row * 512 + cb + ni * 16] = acc[mi][ni][r];
        }
}

// ---------------- pool5: sum 6 K-chunks + affine + lrelu + max over rows -> pooled ----------------
// 1D grid 512, XCD-pinned: z=(i>>1)&3, rest=((i>>3)<<1)|(i&1) in [0,128):
//   oc=(rest&3)*128 cols, mc=(rest>>2)*32 rows; thread: col=t&127, half=t>>7 (16 rows each)
__global__ __launch_bounds__(256) void k_pool5(const float* __restrict__ P5,
                                               const void* __restrict__ g, const void* __restrict__ bias,
                                               unsigned* __restrict__ pooledU,
                                               const int* __restrict__ flag) {
    __shared__ float red2[128];
    int isf = *flag;
    int i = blockIdx.x;
    int z = (i >> 1) & 3;
    int rest = ((i >> 3) << 1) | (i & 1);
    int oc = (rest & 3) * 128, mc = (rest >> 2) * 32;
    int t = threadIdx.x;
    int c = t & 127, h = t >> 7;
    int o = oc + c;
    float scl = ldw(g, o, isf) * BN_SCALE;
    float bb = ldw(bias, o, isf);
    const float* p0 = P5 + (size_t)z * NPTS * 512 + (size_t)(mc + h * 16) * 512 + o;
    float ym = -__builtin_inff();
    for (int r = 0; r < 16; r++) {
        const float* p = p0 + (size_t)r * 512;
        float s = p[0];
#pragma unroll
        for (int ks = 1; ks < 6; ks++) s += p[(size_t)ks * CH5];
        float v = s * scl + bb;
        v = v > 0.f ? v : 0.2f * v;
        ym = fmaxf(ym, v);
    }
    if (h == 1) red2[c] = ym;
    __syncthreads();
    if (h == 0) {
        float m = fmaxf(ym, red2[c]);
        atomicMax(&pooledU[z * 512 + o], ordf(m));
    }
}

// ---------------- final linear: coalesced wave-per-output ----------------
__global__ void k_final(const unsigned* __restrict__ pooledU, const void* __restrict__ We,
                        void* __restrict__ out, const int* __restrict__ flag) {
    __shared__ float p[512];
    int isf = *flag;
    int b = blockIdx.x >> 2, fb = blockIdx.x & 3;
    int t = threadIdx.x, w = t >> 6, l = t & 63;
    for (int i = t; i < 512; i += 256) p[i] = iordf(pooledU[b * 512 + i]);
    __syncthreads();
    for (int it = 0; it < 16; it++) {
        int f = fb * 64 + w * 16 + it;
        float s = 0.f;
        size_t base = (size_t)f * 512 + l * 8;
#pragma unroll
        for (int j = 0; j < 8; j++) s += p[l * 8 + j] * ldw(We, base + j, isf);
#pragma unroll
        for (int off = 32; off > 0; off >>= 1) s += __shfl_down(s, off);
        if (l == 0) {
            if (isf) ((float*)out)[b * 256 + f] = s;
            else     ((bf16*)out)[b * 256 + f] = f2b(s);
        }
    }
}

extern "C" void kernel_launch(void* const* d_in, const int* in_sizes, int n_in,
                              void* d_out, int out_size, void* d_ws, size_t ws_size,
                              hipStream_t stream) {
    const void* x  = d_in[0];
    const void* Wl[4] = { d_in[1], d_in[4], d_in[7], d_in[10] };
    const void* gl[4] = { d_in[2], d_in[5], d_in[8], d_in[11] };
    const void* bl[4] = { d_in[3], d_in[6], d_in[9], d_in[12] };
    const void* W5 = d_in[13];
    const void* g5 = d_in[14];
    const void* b5 = d_in[15];
    const void* We = d_in[16];

    // workspace layout (bytes), ~103.9 MB total
    char* base = (char*)d_ws;
    bf16*     xc_hi   = (bf16*)(base);                  // 7,864,320
    bf16*     xc_lo   = (bf16*)(base + 7864320);        // 7,864,320
    bf16*     xpadh   = (bf16*)(base + 15728640);       // 262,144
    bf16*     xpadl   = (bf16*)(base + 15990784);       // 262,144
    float*    Dbuf    = (float*)(base + 16252928);      // 16,777,216
    float*    Pbuf    = (float*)(base + 33030144);      // 16,777,216
    bf16*     Whi     = (bf16*)(base + 49807360);       // 1,679,360
    bf16*     Wlo     = (bf16*)(base + 51486720);       // 1,679,360
    unsigned* pooledU = (unsigned*)(base + 53493760);   // 8,192
    float*    sq      = (float*)(base + 53501952);      // 16,384
    int*      flag    = (int*)(base + 53518336);        // 4
    float*    P5      = (float*)(base + 53520384);      // 50,331,648 (6 x 8 MB conv5 partials)

    const int Kpad[4]   = { 32, 64, 128, 256 };
    const int Os[4]     = { 64, 128, 256, 512 };
    const int Woff[5]   = { 0, 4096, 20480, 86016, 348160 };
    const int colIn[4]  = { 0, 0, 64, 192 };
    const int colOut[4] = { 0, 64, 192, 448 };

    k_prep<<<3296, 256, 0, stream>>>(Wl[0], Wl[1], Wl[2], Wl[3], W5, x,
                                     Whi, Wlo, xpadh, xpadl, sq, flag, pooledU);

    for (int l = 0; l < 4; l++) {
        int O = Os[l];
        int nCol = (2 * O) >> 7;
        int nBlk = 36 + 8 * nCol;  // 44/52/68/100 -> *4 divisible by 8 for XCD decode
        const bf16* Xh = (l == 0) ? xpadh : (xc_hi + colIn[l]);
        const bf16* Xl = (l == 0) ? xpadl : (xc_lo + colIn[l]);
        int ld = (l == 0) ? 32 : 960;
        size_t xstr = (l == 0) ? (size_t)NPTS * 32 : (size_t)NPTS * 960;
        k_layer_a<<<nBlk * NB, 256, 0, stream>>>(
            Xh, Xl, ld, Kpad[l], xstr, Whi + Woff[l], Wlo + Woff[l], O, sq, Dbuf, Pbuf, flag);
        k_layer_b<<<NPTS * NB / 4, 256, 0, stream>>>(
            Dbuf, Pbuf, gl[l], bl[l], O, xc_hi + colOut[l], xc_lo + colOut[l], sq, l < 3, flag);
    }
    k_conv5<<<768, 256, 0, stream>>>(xc_hi, xc_lo, Whi + Woff[4], Wlo + Woff[4], P5, flag);
    k_pool5<<<512, 256, 0, stream>>>(P5, g5, b5, pooledU, flag);
    k_final<<<16, 256, 0, stream>>>(pooledU, We, d_out, flag);
}

// Round 14
// 302.444 us; speedup vs baseline: 1.1170x; 1.0408x over previous
//
#include <hip/hip_runtime.h>
#include <hip/hip_bf16.h>
#include <math.h>

typedef __hip_bfloat16 bf16;
typedef __bf16 v8bf __attribute__((ext_vector_type(8)));
typedef float v4f __attribute__((ext_vector_type(4)));

#define BN_SCALE 0.9999950000374997f
#define NPTS 1024
#define NB 4
#define CH5 ((size_t)4 * 1024 * 512)   // conv5 partial-chunk stride (floats)

__device__ __forceinline__ float b2f(bf16 v) { return __bfloat162float(v); }
__device__ __forceinline__ bf16 f2b(float v) { return __float2bfloat16(v); }
__device__ __forceinline__ float ldw(const void* p, size_t i, int isf) {
    return isf ? ((const float*)p)[i] : b2f(((const bf16*)p)[i]);
}
__device__ __forceinline__ unsigned ordf(float f) {
    unsigned u = __float_as_uint(f);
    return (u & 0x80000000u) ? ~u : (u | 0x80000000u);
}
__device__ __forceinline__ float iordf(unsigned u) {
    return (u & 0x80000000u) ? __uint_as_float(u ^ 0x80000000u) : __uint_as_float(~u);
}

// per-block dtype detect from first 512 shorts of x (fp32 ~113/256 implausible, bf16 ~0)
__device__ __forceinline__ int detect_isf(const void* xraw, int* cnt) {
    const unsigned short* u = (const unsigned short*)xraw;
    int t = threadIdx.x, c = 0;
    for (int i = t; i < 512; i += 256) {
        unsigned short v = u[i];
        int e = (v >> 7) & 0xFF;
        int m = v & 0x7F;
        if (e == 0xFF || e >= 141 || (e == 0 && m != 0)) c++;
    }
    cnt[t] = c;
    __syncthreads();
    for (int off = 128; off > 0; off >>= 1) {
        if (t < off) cnt[t] += cnt[t + off];
        __syncthreads();
    }
    int isf = (cnt[0] > 30) ? 1 : 0;
    __syncthreads();
    return isf;
}

// ---------------- fused prep: dtype flag + pooled init + weight splits + x pad + sq ----------------
__global__ void k_prep(const void* __restrict__ W1, const void* __restrict__ W2,
                       const void* __restrict__ W3, const void* __restrict__ W4,
                       const void* __restrict__ W5, const void* __restrict__ x,
                       bf16* __restrict__ Whi, bf16* __restrict__ Wlo,
                       bf16* __restrict__ xph, bf16* __restrict__ xpl, float* __restrict__ sq,
                       int* __restrict__ flag, unsigned* __restrict__ pooledU) {
    __shared__ int cnt[256];
    int isf = detect_isf(x, cnt);
    if (blockIdx.x == 0) {
        if (threadIdx.x == 0) *flag = isf;
        for (int i = threadIdx.x; i < 2048; i += 256) pooledU[i] = 0u;  // 0 < ordf(any finite)
    }
    int idx = blockIdx.x * 256 + threadIdx.x;
    if (idx < 839680) {
        const void* src; int C, O, Kpad, two, local;
        if (idx < 4096)        { src = W1; C = 3;   O = 64;  Kpad = 32;  two = 1; local = idx; }
        else if (idx < 20480)  { src = W2; C = 64;  O = 128; Kpad = 64;  two = 1; local = idx - 4096; }
        else if (idx < 86016)  { src = W3; C = 128; O = 256; Kpad = 128; two = 1; local = idx - 20480; }
        else if (idx < 348160) { src = W4; C = 256; O = 512; Kpad = 256; two = 1; local = idx - 86016; }
        else                   { src = W5; C = 960; O = 512; Kpad = 960; two = 0; local = idx - 348160; }
        int r = local / Kpad, c = local % Kpad;
        float wv = 0.f;
        if (c < C) {
            size_t off;
            if (two) off = (r < O) ? (size_t)r * 2 * C + c : (size_t)(r - O) * 2 * C + C + c;
            else     off = (size_t)r * C + c;
            wv = ldw(src, off, isf);
        }
        bf16 h = f2b(wv);
        Whi[idx] = h;
        Wlo[idx] = f2b(wv - b2f(h));
    } else if (idx < 843776) {
        int p = idx - 839680;       // point index: z*1024 + n
        int z = p >> 10, n = p & 1023;
        bf16* ph = xph + (size_t)z * NPTS * 32;
        bf16* pl = xpl + (size_t)z * NPTS * 32;
        float s = 0.f;
        for (int c = 0; c < 32; c++) {
            float v = (c < 3) ? ldw(x, (size_t)z * NPTS * 3 + n * 3 + c, isf) : 0.f;
            bf16 h = f2b(v);
            ph[n * 32 + c] = h;
            pl[n * 32 + c] = f2b(v - b2f(h));
            s += v * v;
        }
        sq[z * NPTS + n] = s;
    }
}

// ---- conflict-free LDS layout: k-quad-major [kq][row][8], XOR-swizzled ----
__device__ __forceinline__ int lidx(int plane, int row) {
    return ((((plane << 7) | row)) ^ (plane << 1)) << 3;
}
// staged fill split: global->regs (issue early) then regs->LDS (write late) for dbuf pipelining
struct St2 { float4 a, b; };
__device__ __forceinline__ St2 ldStage(const bf16* src, int ld) {
    int t = threadIdx.x; int r = t >> 2, kq = t & 3;
    St2 s;
    s.a = *(const float4*)(src + (size_t)r * ld + kq * 8);
    s.b = *(const float4*)(src + (size_t)(r + 64) * ld + kq * 8);
    return s;
}
__device__ __forceinline__ void stStage(bf16* dst, const St2& s) {
    int t = threadIdx.x; int r = t >> 2, kq = t & 3;
    *(float4*)(dst + lidx(kq, r)) = s.a;
    *(float4*)(dst + lidx(kq, r + 64)) = s.b;
}
// single-shot fill (conv5 keeps the proven 2-barrier structure)
__device__ __forceinline__ void fill128(bf16* dst, const bf16* src, int ld) {
    int t = threadIdx.x;
    int r = t >> 2, kq = t & 3;
    *(float4*)(dst + lidx(kq, r))      = *(const float4*)(src + (size_t)r * ld + kq * 8);
    *(float4*)(dst + lidx(kq, r + 64)) = *(const float4*)(src + (size_t)(r + 64) * ld + kq * 8);
}
// MFMA fragment: sub-tile 'sub' (16 rows of 128), lane l: row=sub*16+(l&15), k=(l>>4)*8..+7
__device__ __forceinline__ v8bf ldf(const bf16* tile, int sub, int l) {
    return *(const v8bf*)(tile + lidx(l >> 4, sub * 16 + (l & 15)));
}

// ---------------- fused layer stage A: dist (upper-tri 128x128 tiles) + st ----------------
// 1D grid, XCD-pinned: z = (i>>1)&3, bi = ((i>>3)<<1)|(i&1)  (batch z -> XCDs {2z,2z+1})
// 128x128 output tile, 4 waves in 2x2, each wave 64x64 (acc[4][4]).
// Double-buffered K-loop (1 barrier/step, loads issued one step ahead).
__global__ __launch_bounds__(256) void k_layer_a(const bf16* __restrict__ Xhi, const bf16* __restrict__ Xlo,
                                                 int ld, int Kpad, size_t xstride,
                                                 const bf16* __restrict__ Whi, const bf16* __restrict__ Wlo,
                                                 int O, const float* __restrict__ sqg,
                                                 float* __restrict__ Dg, float* __restrict__ Pg,
                                                 const int* __restrict__ flag) {
    int i = blockIdx.x;
    int z = (i >> 1) & 3;
    int bi = ((i >> 3) << 1) | (i & 1);
    const bf16* Xh = Xhi + (size_t)z * xstride;
    const bf16* Xl = Xlo + (size_t)z * xstride;
    __shared__ alignas(16) bf16 Ah[2][4096], Al[2][4096], Bh[2][4096], Bl[2][4096];
    int w = threadIdx.x >> 6, l = threadIdx.x & 63;
    int wr = w >> 1, wc = w & 1;
    int quad = l >> 4, col = l & 15;
    v4f zero = {0.f, 0.f, 0.f, 0.f};
    v4f acc[4][4] = {{zero, zero, zero, zero}, {zero, zero, zero, zero},
                     {zero, zero, zero, zero}, {zero, zero, zero, zero}};

    if (bi < 36) {
        // ---- dist tile: triangular decode over 8x8, bx >= by ----
        int bx = 0;
        while ((((bx + 1) * (bx + 2)) >> 1) <= bi) bx++;
        int by = bi - ((bx * (bx + 1)) >> 1);
        const float* sq = sqg + z * NPTS;
        float* D = Dg + (size_t)z * NPTS * NPTS;
        int n0 = by * 128, m0 = bx * 128;
        const bf16* pAn = Xh + (size_t)n0 * ld;
        const bf16* pAm = Xh + (size_t)m0 * ld;
        const bf16* pLn = Xl + (size_t)n0 * ld;
        const bf16* pLm = Xl + (size_t)m0 * ld;
        St2 sA = ldStage(pAn, ld), sB = ldStage(pAm, ld);
        St2 sC = ldStage(pLn, ld), sD = ldStage(pLm, ld);
        stStage(Ah[0], sA); stStage(Bh[0], sB);
        stStage(Al[0], sC); stStage(Bl[0], sD);
        __syncthreads();
        int cur = 0;
        for (int k0 = 0; k0 < Kpad; k0 += 32) {
            bool more = (k0 + 32 < Kpad);
            if (more) {
                sA = ldStage(pAn + k0 + 32, ld);
                sB = ldStage(pAm + k0 + 32, ld);
                sC = ldStage(pLn + k0 + 32, ld);
                sD = ldStage(pLm + k0 + 32, ld);
            }
            v8bf ah[4], al[4];
#pragma unroll
            for (int mi = 0; mi < 4; mi++) {
                ah[mi] = ldf(Ah[cur], wr * 4 + mi, l);
                al[mi] = ldf(Al[cur], wr * 4 + mi, l);
            }
#pragma unroll
            for (int ni = 0; ni < 4; ni++) {
                v8bf bh = ldf(Bh[cur], wc * 4 + ni, l);
                v8bf bl = ldf(Bl[cur], wc * 4 + ni, l);
#pragma unroll
                for (int mi = 0; mi < 4; mi++) {
                    acc[mi][ni] = __builtin_amdgcn_mfma_f32_16x16x32_bf16(ah[mi], bh, acc[mi][ni], 0, 0, 0);
                    acc[mi][ni] = __builtin_amdgcn_mfma_f32_16x16x32_bf16(ah[mi], bl, acc[mi][ni], 0, 0, 0);
                    acc[mi][ni] = __builtin_amdgcn_mfma_f32_16x16x32_bf16(al[mi], bh, acc[mi][ni], 0, 0, 0);
                }
            }
            if (more) {
                stStage(Ah[cur ^ 1], sA); stStage(Bh[cur ^ 1], sB);
                stStage(Al[cur ^ 1], sC); stStage(Bl[cur ^ 1], sD);
            }
            __syncthreads();
            cur ^= 1;
        }
        int rb = n0 + wr * 64 + quad * 4;
        int cb = m0 + wc * 64 + col;
        float sm[4];
#pragma unroll
        for (int ni = 0; ni < 4; ni++) sm[ni] = sq[cb + ni * 16];
#pragma unroll
        for (int mi = 0; mi < 4; mi++) {
#pragma unroll
            for (int r = 0; r < 4; r++) {
                int row = rb + mi * 16 + r;
                float sn = sq[row];
#pragma unroll
                for (int ni = 0; ni < 4; ni++) {
                    float d = 2.f * acc[mi][ni][r] - sn - sm[ni];
                    int c = cb + ni * 16;
                    D[(size_t)row * NPTS + c] = d;
                    if (bx != by) D[(size_t)c * NPTS + row] = d;
                }
            }
        }
    } else {
        // ---- st tile: P[point m, weight-row n] over 2O cols ----
        int isf = *flag;
        int nCol = (2 * O) >> 7;
        int s = bi - 36;
        int n0 = (s % nCol) * 128;   // weight-row tile (over 2O)
        int m0 = (s / nCol) * 128;   // point tile (over 1024)
        int N2 = 2 * O;
        float* P = Pg + (size_t)z * NPTS * N2;
        const bf16* pXh = Xh + (size_t)m0 * ld;
        const bf16* pXl = Xl + (size_t)m0 * ld;
        const bf16* pWh = Whi + (size_t)n0 * Kpad;
        const bf16* pWl = Wlo + (size_t)n0 * Kpad;
        St2 sA = ldStage(pXh, ld), sC = ldStage(pXl, ld);
        St2 sB = ldStage(pWh, Kpad), sD;
        if (isf) sD = ldStage(pWl, Kpad);
        stStage(Ah[0], sA); stStage(Al[0], sC); stStage(Bh[0], sB);
        if (isf) stStage(Bl[0], sD);
        __syncthreads();
        int cur = 0;
        for (int k0 = 0; k0 < Kpad; k0 += 32) {
            bool more = (k0 + 32 < Kpad);
            if (more) {
                sA = ldStage(pXh + k0 + 32, ld);
                sC = ldStage(pXl + k0 + 32, ld);
                sB = ldStage(pWh + k0 + 32, Kpad);
                if (isf) sD = ldStage(pWl + k0 + 32, Kpad);
            }
            v8bf ah[4], al[4];
#pragma unroll
            for (int mi = 0; mi < 4; mi++) {
                ah[mi] = ldf(Ah[cur], wr * 4 + mi, l);
                al[mi] = ldf(Al[cur], wr * 4 + mi, l);
            }
#pragma unroll
            for (int ni = 0; ni < 4; ni++) {
                v8bf bh = ldf(Bh[cur], wc * 4 + ni, l);
#pragma unroll
                for (int mi = 0; mi < 4; mi++) {
                    acc[mi][ni] = __builtin_amdgcn_mfma_f32_16x16x32_bf16(ah[mi], bh, acc[mi][ni], 0, 0, 0);
                    acc[mi][ni] = __builtin_amdgcn_mfma_f32_16x16x32_bf16(al[mi], bh, acc[mi][ni], 0, 0, 0);
                }
                if (isf) {
                    v8bf bl = ldf(Bl[cur], wc * 4 + ni, l);
#pragma unroll
                    for (int mi = 0; mi < 4; mi++)
                        acc[mi][ni] = __builtin_amdgcn_mfma_f32_16x16x32_bf16(ah[mi], bl, acc[mi][ni], 0, 0, 0);
                }
            }
            if (more) {
                stStage(Ah[cur ^ 1], sA); stStage(Al[cur ^ 1], sC);
                stStage(Bh[cur ^ 1], sB);
                if (isf) stStage(Bl[cur ^ 1], sD);
            }
            __syncthreads();
            cur ^= 1;
        }
        int rb = m0 + wr * 64 + quad * 4;
        int cb = n0 + wc * 64 + col;
#pragma unroll
        for (int mi = 0; mi < 4; mi++)
#pragma unroll
            for (int r = 0; r < 4; r++) {
                int row = rb + mi * 16 + r;
#pragma unroll
                for (int ni = 0; ni < 4; ni++)
                    P[(size_t)row * N2 + cb + ni * 16] = acc[mi][ni][r];
            }
    }
}

// ---- argmax combine via DPP (VALU pipe, ~5cy/step vs ~100cy ds_swizzle) ----
// (max val, min idx) is a total-order max: associative+commutative+idempotent, so any
// full-coverage mixing converges to the unique winner. update_dpp(old=self,...) makes
// non-receiving lanes self-combine (no-op).
template<int CTRL>
__device__ __forceinline__ void dpp_step(float& bv, int& bi) {
    int ov_i = __builtin_amdgcn_update_dpp(__float_as_int(bv), __float_as_int(bv), CTRL, 0xF, 0xF, false);
    int oi   = __builtin_amdgcn_update_dpp(bi, bi, CTRL, 0xF, 0xF, false);
    float ov = __int_as_float(ov_i);
    if (ov > bv || (ov == bv && oi < bi)) { bv = ov; bi = oi; }
}
#define PICK(va, ja, vb, jb, vo, jo) { bool t_ = (vb) > (va); vo = t_ ? (vb) : (va); jo = t_ ? (jb) : (ja); }

// ---------------- fused stage B: top-20 + gather-max, WAVE-PER-ROW end-to-end ----------------
// 1D grid 1024, XCD-pinned: z = (i>>1)&3, local = ((i>>3)<<1)|(i&1); wave q owns row local*4+q.
// Selection butterfly entirely on DPP: quad xor1/xor2 + row_ror4/8 (16-lane converge, all lanes)
// + row_bcast15 + row_bcast31 (lane 63 = full 64-lane winner) + readlane(63) -> SGPR broadcast.
// Outcome identical to the ds_swizzle version (same unique total-order max).
__global__ __launch_bounds__(256) void k_layer_b(const float* __restrict__ Dg, const float* __restrict__ Pg,
                                                 const void* __restrict__ g, const void* __restrict__ bias,
                                                 int O, bf16* __restrict__ xhOut, bf16* __restrict__ xlOut,
                                                 float* __restrict__ sqOut, int writeSq,
                                                 const int* __restrict__ flag) {
    __shared__ int ids[4][20];
    int isf = *flag;
    int i = blockIdx.x;
    int z = (i >> 1) & 3;
    int local = ((i >> 3) << 1) | (i & 1);
    int tid = threadIdx.x;
    int wq = tid >> 6, l = tid & 63;
    int row = local * 4 + wq;

    // ---- per-wave register-resident top-20 (lane->index map bi = jj*256+l*4+q bijective
    //      over [0,1024), monotone per lane in scan order -> min-index tie-break) ----
    {
        const float* Dr = Dg + (size_t)z * NPTS * NPTS + (size_t)row * NPTS;
        float v[16];
#pragma unroll
        for (int jj = 0; jj < 4; jj++) {
            float4 f4 = *(const float4*)(Dr + jj * 256 + l * 4);
            v[jj * 4 + 0] = f4.x; v[jj * 4 + 1] = f4.y;
            v[jj * 4 + 2] = f4.z; v[jj * 4 + 3] = f4.w;
        }
        float bmv[4]; int bmj[4];
#pragma unroll
        for (int gg = 0; gg < 4; gg++) {
            float a0, a1; int j0, j1;
            PICK(v[4 * gg + 0], 4 * gg + 0, v[4 * gg + 1], 4 * gg + 1, a0, j0);
            PICK(v[4 * gg + 2], 4 * gg + 2, v[4 * gg + 3], 4 * gg + 3, a1, j1);
            PICK(a0, j0, a1, j1, bmv[gg], bmj[gg]);
        }
        for (int s = 0; s < 20; s++) {
            float t0, t1, bv; int s0, s1, bj;
            PICK(bmv[0], bmj[0], bmv[1], bmj[1], t0, s0);
            PICK(bmv[2], bmj[2], bmv[3], bmj[3], t1, s1);
            PICK(t0, s0, t1, s1, bv, bj);
            int bi = (bj >> 2) * 256 + l * 4 + (bj & 3);
            dpp_step<0xB1>(bv, bi);    // quad_perm [1,0,3,2] = xor1
            dpp_step<0x4E>(bv, bi);    // quad_perm [2,3,0,1] = xor2
            dpp_step<0x124>(bv, bi);   // row_ror:4
            dpp_step<0x128>(bv, bi);   // row_ror:8  -> every lane has its 16-row winner
            dpp_step<0x142>(bv, bi);   // row_bcast15: row r combines row r-1's max
            dpp_step<0x143>(bv, bi);   // row_bcast31: lanes32-63 combine rows01 -> lane63 global
            int bii = __builtin_amdgcn_readlane(bi, 63);   // SGPR broadcast of winner idx
            if (l == 0) ids[wq][s] = bii;
            if (((bii >> 2) & 63) == l) {  // owning lane: evict + rebuild its group
                int ej = (bii >> 8) * 4 + (bii & 3);
                int eg = ej >> 2, ek = ej & 3;
#pragma unroll
                for (int gg = 0; gg < 4; gg++) if (gg == eg) {
#pragma unroll
                    for (int kk = 0; kk < 4; kk++)
                        if (kk == ek) v[4 * gg + kk] = -__builtin_inff();
                    float a0, a1; int j0, j1;
                    PICK(v[4 * gg + 0], 4 * gg + 0, v[4 * gg + 1], 4 * gg + 1, a0, j0);
                    PICK(v[4 * gg + 2], 4 * gg + 2, v[4 * gg + 3], 4 * gg + 3, a1, j1);
                    PICK(a0, j0, a1, j1, bmv[gg], bmj[gg]);
                }
            }
        }
    }

    // ---- gather + max for THIS wave's row (affine/lrelu AFTER max: exact FP-monotone commute) ----
    int N2 = 2 * O;
    const float* P = Pg + (size_t)z * NPTS * N2;
    int offj[20];
#pragma unroll
    for (int j = 0; j < 20; j++)
        offj[j] = __builtin_amdgcn_readfirstlane(ids[wq][j]) * N2;  // SGPR row bases
    int n = row;
    const float* Pn = P + (size_t)n * N2;
    float tot = 0.f;
    int nc = O >> 6;
    for (int c = 0; c < nc; c++) {
        int o = c * 64 + l;
        float tv = Pn[O + o] - Pn[o];
        float mx = -__builtin_inff(), mn = __builtin_inff();
#pragma unroll
        for (int j = 0; j < 20; j++) {
            float vv = P[offj[j] + o];
            mx = fmaxf(mx, vv);
            mn = fminf(mn, vv);
        }
        float scl = ldw(g, o, isf) * BN_SCALE;
        float bb = ldw(bias, o, isf);
        float base = (scl >= 0.f ? mx : mn) + tv;
        float accv = base * scl + bb;
        accv = accv > 0.f ? accv : 0.2f * accv;
        bf16 hi = f2b(accv);
        bf16 lo = f2b(accv - b2f(hi));
        xhOut[(size_t)z * NPTS * 960 + (size_t)n * 960 + o] = hi;
        xlOut[(size_t)z * NPTS * 960 + (size_t)n * 960 + o] = lo;
        if (writeSq) {
            float xv = b2f(hi) + b2f(lo);
            float s2 = xv * xv;
#pragma unroll
            for (int off = 32; off > 0; off >>= 1) s2 += __shfl_down(s2, off);
            if (l == 0) tot += s2;       // ascending chunk order: same serial FP sum as before
        }
    }
    if (writeSq && l == 0) sqOut[z * NPTS + row] = tot;
}

// ---------------- conv5 via MFMA, K-split x6 (chunks of 160) -> f32 partials ----------------
// 1D grid 768, XCD-pinned: z=(i>>1)&3, rest=((i>>3)<<1)|(i&1) in [0,192):
//   ks = rest>>5 (K-chunk), tile = rest&31: m0=(tile>>2)*128, o0=(tile&3)*128
__global__ __launch_bounds__(256) void k_conv5(const bf16* __restrict__ Xhi, const bf16* __restrict__ Xlo,
                                               const bf16* __restrict__ Whi, const bf16* __restrict__ Wlo,
                                               float* __restrict__ P5,
                                               const int* __restrict__ flag) {
    int isf = *flag;
    int i = blockIdx.x;
    int z = (i >> 1) & 3;
    int rest = ((i >> 3) << 1) | (i & 1);
    int ks = rest >> 5;
    int tile = rest & 31;
    int m0 = (tile >> 2) * 128, o0 = (tile & 3) * 128;
    const bf16* Xh = Xhi + (size_t)z * NPTS * 960;
    const bf16* Xl = Xlo + (size_t)z * NPTS * 960;
    __shared__ alignas(16) bf16 Ah[4096], Al[4096], Bh[4096], Bl[4096];
    int w = threadIdx.x >> 6, l = threadIdx.x & 63;
    int wr = w >> 1, wc = w & 1;
    int quad = l >> 4, col = l & 15;
    v4f zero = {0.f, 0.f, 0.f, 0.f};
    v4f acc[4][4] = {{zero, zero, zero, zero}, {zero, zero, zero, zero},
                     {zero, zero, zero, zero}, {zero, zero, zero, zero}};
    int kbeg = ks * 160, kend = kbeg + 160;
    for (int k0 = kbeg; k0 < kend; k0 += 32) {
        __syncthreads();
        fill128(Ah, Xh + (size_t)m0 * 960 + k0, 960);
        fill128(Al, Xl + (size_t)m0 * 960 + k0, 960);
        fill128(Bh, Whi + (size_t)o0 * 960 + k0, 960);
        if (isf) fill128(Bl, Wlo + (size_t)o0 * 960 + k0, 960);
        __syncthreads();
        v8bf ah[4], al[4];
#pragma unroll
        for (int mi = 0; mi < 4; mi++) {
            ah[mi] = ldf(Ah, wr * 4 + mi, l);
            al[mi] = ldf(Al, wr * 4 + mi, l);
        }
#pragma unroll
        for (int ni = 0; ni < 4; ni++) {
            v8bf bh = ldf(Bh, wc * 4 + ni, l);
#pragma unroll
            for (int mi = 0; mi < 4; mi++) {
                acc[mi][ni] = __builtin_amdgcn_mfma_f32_16x16x32_bf16(ah[mi], bh, acc[mi][ni], 0, 0, 0);
                acc[mi][ni] = __builtin_amdgcn_mfma_f32_16x16x32_bf16(al[mi], bh, acc[mi][ni], 0, 0, 0);
            }
            if (isf) {
                v8bf bl = ldf(Bl, wc * 4 + ni, l);
#pragma unroll
                for (int mi = 0; mi < 4; mi++)
                    acc[mi][ni] = __builtin_amdgcn_mfma_f32_16x16x32_bf16(ah[mi], bl, acc[mi][ni], 0, 0, 0);
            }
        }
    }
    // write f32 partial tile (disjoint per (ks,z,tile) -> no atomics)
    float* Pw = P5 + (size_t)ks * CH5 + (size_t)z * NPTS * 512;
    int rb = m0 + wr * 64 + quad * 4;
    int cb = o0 + wc * 64 + col;
#pragma unroll
    for (int mi = 0; mi < 4; mi++)
#pragma unroll
        for (int r = 0; r < 4; r++) {
            int row = rb + mi * 16 + r;
#pragma unroll
            for (int ni = 0; ni < 4; ni++)
                Pw[(size_t)row * 512 + cb + ni * 16] = acc[mi][ni][r];
        }
}

// ---------------- pool5: sum 6 K-chunks + affine + lrelu + max over rows -> pooled ----------------
// 1D grid 512, XCD-pinned: z=(i>>1)&3, rest=((i>>3)<<1)|(i&1) in [0,128):
//   oc=(rest&3)*128 cols, mc=(rest>>2)*32 rows; thread: col=t&127, half=t>>7 (16 rows each)
__global__ __launch_bounds__(256) void k_pool5(const float* __restrict__ P5,
                                               const void* __restrict__ g, const void* __restrict__ bias,
                                               unsigned* __restrict__ pooledU,
                                               const int* __restrict__ flag) {
    __shared__ float red2[128];
    int isf = *flag;
    int i = blockIdx.x;
    int z = (i >> 1) & 3;
    int rest = ((i >> 3) << 1) | (i & 1);
    int oc = (rest & 3) * 128, mc = (rest >> 2) * 32;
    int t = threadIdx.x;
    int c = t & 127, h = t >> 7;
    int o = oc + c;
    float scl = ldw(g, o, isf) * BN_SCALE;
    float bb = ldw(bias, o, isf);
    const float* p0 = P5 + (size_t)z * NPTS * 512 + (size_t)(mc + h * 16) * 512 + o;
    float ym = -__builtin_inff();
    for (int r = 0; r < 16; r++) {
        const float* p = p0 + (size_t)r * 512;
        float s = p[0];
#pragma unroll
        for (int ks = 1; ks < 6; ks++) s += p[(size_t)ks * CH5];
        float v = s * scl + bb;
        v = v > 0.f ? v : 0.2f * v;
        ym = fmaxf(ym, v);
    }
    if (h == 1) red2[c] = ym;
    __syncthreads();
    if (h == 0) {
        float m = fmaxf(ym, red2[c]);
        atomicMax(&pooledU[z * 512 + o], ordf(m));
    }
}

// ---------------- final linear: coalesced wave-per-output ----------------
__global__ void k_final(const unsigned* __restrict__ pooledU, const void* __restrict__ We,
                        void* __restrict__ out, const int* __restrict__ flag) {
    __shared__ float p[512];
    int isf = *flag;
    int b = blockIdx.x >> 2, fb = blockIdx.x & 3;
    int t = threadIdx.x, w = t >> 6, l = t & 63;
    for (int i = t; i < 512; i += 256) p[i] = iordf(pooledU[b * 512 + i]);
    __syncthreads();
    for (int it = 0; it < 16; it++) {
        int f = fb * 64 + w * 16 + it;
        float s = 0.f;
        size_t base = (size_t)f * 512 + l * 8;
#pragma unroll
        for (int j = 0; j < 8; j++) s += p[l * 8 + j] * ldw(We, base + j, isf);
#pragma unroll
        for (int off = 32; off > 0; off >>= 1) s += __shfl_down(s, off);
        if (l == 0) {
            if (isf) ((float*)out)[b * 256 + f] = s;
            else     ((bf16*)out)[b * 256 + f] = f2b(s);
        }
    }
}

extern "C" void kernel_launch(void* const* d_in, const int* in_sizes, int n_in,
                              void* d_out, int out_size, void* d_ws, size_t ws_size,
                              hipStream_t stream) {
    const void* x  = d_in[0];
    const void* Wl[4] = { d_in[1], d_in[4], d_in[7], d_in[10] };
    const void* gl[4] = { d_in[2], d_in[5], d_in[8], d_in[11] };
    const void* bl[4] = { d_in[3], d_in[6], d_in[9], d_in[12] };
    const void* W5 = d_in[13];
    const void* g5 = d_in[14];
    const void* b5 = d_in[15];
    const void* We = d_in[16];

    // workspace layout (bytes), ~103.9 MB total
    char* base = (char*)d_ws;
    bf16*     xc_hi   = (bf16*)(base);                  // 7,864,320
    bf16*     xc_lo   = (bf16*)(base + 7864320);        // 7,864,320
    bf16*     xpadh   = (bf16*)(base + 15728640);       // 262,144
    bf16*     xpadl   = (bf16*)(base + 15990784);       // 262,144
    float*    Dbuf    = (float*)(base + 16252928);      // 16,777,216
    float*    Pbuf    = (float*)(base + 33030144);      // 16,777,216
    bf16*     Whi     = (bf16*)(base + 49807360);       // 1,679,360
    bf16*     Wlo     = (bf16*)(base + 51486720);       // 1,679,360
    unsigned* pooledU = (unsigned*)(base + 53493760);   // 8,192
    float*    sq      = (float*)(base + 53501952);      // 16,384
    int*      flag    = (int*)(base + 53518336);        // 4
    float*    P5      = (float*)(base + 53520384);      // 50,331,648 (6 x 8 MB conv5 partials)

    const int Kpad[4]   = { 32, 64, 128, 256 };
    const int Os[4]     = { 64, 128, 256, 512 };
    const int Woff[5]   = { 0, 4096, 20480, 86016, 348160 };
    const int colIn[4]  = { 0, 0, 64, 192 };
    const int colOut[4] = { 0, 64, 192, 448 };

    k_prep<<<3296, 256, 0, stream>>>(Wl[0], Wl[1], Wl[2], Wl[3], W5, x,
                                     Whi, Wlo, xpadh, xpadl, sq, flag, pooledU);

    for (int l = 0; l < 4; l++) {
        int O = Os[l];
        int nCol = (2 * O) >> 7;
        int nBlk = 36 + 8 * nCol;  // 44/52/68/100 -> *4 divisible by 8 for XCD decode
        const bf16* Xh = (l == 0) ? xpadh : (xc_hi + colIn[l]);
        const bf16* Xl = (l == 0) ? xpadl : (xc_lo + colIn[l]);
        int ld = (l == 0) ? 32 : 960;
        size_t xstr = (l == 0) ? (size_t)NPTS * 32 : (size_t)NPTS * 960;
        k_layer_a<<<nBlk * NB, 256, 0, stream>>>(
            Xh, Xl, ld, Kpad[l], xstr, Whi + Woff[l], Wlo + Woff[l], O, sq, Dbuf, Pbuf, flag);
        k_layer_b<<<NPTS * NB / 4, 256, 0, stream>>>(
            Dbuf, Pbuf, gl[l], bl[l], O, xc_hi + colOut[l], xc_lo + colOut[l], sq, l < 3, flag);
    }
    k_conv5<<<768, 256, 0, stream>>>(xc_hi, xc_lo, Whi + Woff[4], Wlo + Woff[4], P5, flag);
    k_pool5<<<512, 256, 0, stream>>>(P5, g5, b5, pooledU, flag);
    k_final<<<16, 256, 0, stream>>>(pooledU, We, d_out, flag);
}

// Round 15
// 296.684 us; speedup vs baseline: 1.1387x; 1.0194x over previous
//
#include <hip/hip_runtime.h>
#include <hip/hip_bf16.h>
#include <math.h>

typedef __hip_bfloat16 bf16;
typedef __bf16 v8bf __attribute__((ext_vector_type(8)));
typedef float v4f __attribute__((ext_vector_type(4)));

#define BN_SCALE 0.9999950000374997f
#define NPTS 1024
#define NB 4
#define CH5 ((size_t)4 * 1024 * 512)   // conv5 partial-chunk stride (floats)

__device__ __forceinline__ float b2f(bf16 v) { return __bfloat162float(v); }
__device__ __forceinline__ bf16 f2b(float v) { return __float2bfloat16(v); }
__device__ __forceinline__ float ldw(const void* p, size_t i, int isf) {
    return isf ? ((const float*)p)[i] : b2f(((const bf16*)p)[i]);
}
__device__ __forceinline__ unsigned ordf(float f) {
    unsigned u = __float_as_uint(f);
    return (u & 0x80000000u) ? ~u : (u | 0x80000000u);
}
__device__ __forceinline__ float iordf(unsigned u) {
    return (u & 0x80000000u) ? __uint_as_float(u ^ 0x80000000u) : __uint_as_float(~u);
}

// per-block dtype detect from first 512 shorts of x (fp32 ~113/256 implausible, bf16 ~0)
__device__ __forceinline__ int detect_isf(const void* xraw, int* cnt) {
    const unsigned short* u = (const unsigned short*)xraw;
    int t = threadIdx.x, c = 0;
    for (int i = t; i < 512; i += 256) {
        unsigned short v = u[i];
        int e = (v >> 7) & 0xFF;
        int m = v & 0x7F;
        if (e == 0xFF || e >= 141 || (e == 0 && m != 0)) c++;
    }
    cnt[t] = c;
    __syncthreads();
    for (int off = 128; off > 0; off >>= 1) {
        if (t < off) cnt[t] += cnt[t + off];
        __syncthreads();
    }
    int isf = (cnt[0] > 30) ? 1 : 0;
    __syncthreads();
    return isf;
}

// ---------------- fused prep: dtype flag + pooled init + weight splits + x pad + sq ----------------
__global__ void k_prep(const void* __restrict__ W1, const void* __restrict__ W2,
                       const void* __restrict__ W3, const void* __restrict__ W4,
                       const void* __restrict__ W5, const void* __restrict__ x,
                       bf16* __restrict__ Whi, bf16* __restrict__ Wlo,
                       bf16* __restrict__ xph, bf16* __restrict__ xpl, float* __restrict__ sq,
                       int* __restrict__ flag, unsigned* __restrict__ pooledU) {
    __shared__ int cnt[256];
    int isf = detect_isf(x, cnt);
    if (blockIdx.x == 0) {
        if (threadIdx.x == 0) *flag = isf;
        for (int i = threadIdx.x; i < 2048; i += 256) pooledU[i] = 0u;  // 0 < ordf(any finite)
    }
    int idx = blockIdx.x * 256 + threadIdx.x;
    if (idx < 839680) {
        const void* src; int C, O, Kpad, two, local;
        if (idx < 4096)        { src = W1; C = 3;   O = 64;  Kpad = 32;  two = 1; local = idx; }
        else if (idx < 20480)  { src = W2; C = 64;  O = 128; Kpad = 64;  two = 1; local = idx - 4096; }
        else if (idx < 86016)  { src = W3; C = 128; O = 256; Kpad = 128; two = 1; local = idx - 20480; }
        else if (idx < 348160) { src = W4; C = 256; O = 512; Kpad = 256; two = 1; local = idx - 86016; }
        else                   { src = W5; C = 960; O = 512; Kpad = 960; two = 0; local = idx - 348160; }
        int r = local / Kpad, c = local % Kpad;
        float wv = 0.f;
        if (c < C) {
            size_t off;
            if (two) off = (r < O) ? (size_t)r * 2 * C + c : (size_t)(r - O) * 2 * C + C + c;
            else     off = (size_t)r * C + c;
            wv = ldw(src, off, isf);
        }
        bf16 h = f2b(wv);
        Whi[idx] = h;
        Wlo[idx] = f2b(wv - b2f(h));
    } else if (idx < 843776) {
        int p = idx - 839680;       // point index: z*1024 + n
        int z = p >> 10, n = p & 1023;
        bf16* ph = xph + (size_t)z * NPTS * 32;
        bf16* pl = xpl + (size_t)z * NPTS * 32;
        float s = 0.f;
        for (int c = 0; c < 32; c++) {
            float v = (c < 3) ? ldw(x, (size_t)z * NPTS * 3 + n * 3 + c, isf) : 0.f;
            bf16 h = f2b(v);
            ph[n * 32 + c] = h;
            pl[n * 32 + c] = f2b(v - b2f(h));
            s += v * v;
        }
        sq[z * NPTS + n] = s;
    }
}

// ---- conflict-free LDS layout: k-quad-major [kq][row][8], XOR-swizzled ----
__device__ __forceinline__ int lidx(int plane, int row) {
    return ((((plane << 7) | row)) ^ (plane << 1)) << 3;
}
// staged fill split: global->regs (issue early) then regs->LDS (write late) for dbuf pipelining
struct St2 { float4 a, b; };
__device__ __forceinline__ St2 ldStage(const bf16* src, int ld) {
    int t = threadIdx.x; int r = t >> 2, kq = t & 3;
    St2 s;
    s.a = *(const float4*)(src + (size_t)r * ld + kq * 8);
    s.b = *(const float4*)(src + (size_t)(r + 64) * ld + kq * 8);
    return s;
}
__device__ __forceinline__ void stStage(bf16* dst, const St2& s) {
    int t = threadIdx.x; int r = t >> 2, kq = t & 3;
    *(float4*)(dst + lidx(kq, r)) = s.a;
    *(float4*)(dst + lidx(kq, r + 64)) = s.b;
}
// single-shot fill (conv5 keeps the proven 2-barrier structure)
__device__ __forceinline__ void fill128(bf16* dst, const bf16* src, int ld) {
    int t = threadIdx.x;
    int r = t >> 2, kq = t & 3;
    *(float4*)(dst + lidx(kq, r))      = *(const float4*)(src + (size_t)r * ld + kq * 8);
    *(float4*)(dst + lidx(kq, r + 64)) = *(const float4*)(src + (size_t)(r + 64) * ld + kq * 8);
}
// MFMA fragment: sub-tile 'sub' (16 rows of 128), lane l: row=sub*16+(l&15), k=(l>>4)*8..+7
__device__ __forceinline__ v8bf ldf(const bf16* tile, int sub, int l) {
    return *(const v8bf*)(tile + lidx(l >> 4, sub * 16 + (l & 15)));
}

#define TSTRIDE 129   // f32 transpose tile stride (128+1: conflict-free row reads)

// ---------------- fused layer stage A: dist (upper-tri 128x128 tiles) + st ----------------
// 1D grid, XCD-pinned: z = (i>>1)&3, bi = ((i>>3)<<1)|(i&1)  (batch z -> XCDs {2z,2z+1})
// 128x128 output tile, 4 waves in 2x2, each wave 64x64 (acc[4][4]).
// Double-buffered K-loop (1 barrier/step). Dist mirror write goes through an LDS transpose
// (aliasing the dead staging buffers) so both D orientations are written COALESCED -- the
// direct per-lane mirror scatter (64 lines/instr) was the epilogue bottleneck.
__global__ __launch_bounds__(256) void k_layer_a(const bf16* __restrict__ Xhi, const bf16* __restrict__ Xlo,
                                                 int ld, int Kpad, size_t xstride,
                                                 const bf16* __restrict__ Whi, const bf16* __restrict__ Wlo,
                                                 int O, const float* __restrict__ sqg,
                                                 float* __restrict__ Dg, float* __restrict__ Pg,
                                                 const int* __restrict__ flag) {
    int i = blockIdx.x;
    int z = (i >> 1) & 3;
    int bi = ((i >> 3) << 1) | (i & 1);
    const bf16* Xh = Xhi + (size_t)z * xstride;
    const bf16* Xl = Xlo + (size_t)z * xstride;
    __shared__ alignas(16) char smem[128 * TSTRIDE * 4];   // 66,048 B >= 64 KB staging
    bf16* Ah = (bf16*)smem;                 // [2][4096]
    bf16* Al = (bf16*)(smem + 16384);       // [2][4096]
    bf16* Bh = (bf16*)(smem + 32768);       // [2][4096]
    bf16* Bl = (bf16*)(smem + 49152);       // [2][4096]
    int w = threadIdx.x >> 6, l = threadIdx.x & 63;
    int wr = w >> 1, wc = w & 1;
    int quad = l >> 4, col = l & 15;
    v4f zero = {0.f, 0.f, 0.f, 0.f};
    v4f acc[4][4] = {{zero, zero, zero, zero}, {zero, zero, zero, zero},
                     {zero, zero, zero, zero}, {zero, zero, zero, zero}};

    if (bi < 36) {
        // ---- dist tile: triangular decode over 8x8, bx >= by ----
        int bx = 0;
        while ((((bx + 1) * (bx + 2)) >> 1) <= bi) bx++;
        int by = bi - ((bx * (bx + 1)) >> 1);
        const float* sq = sqg + z * NPTS;
        float* D = Dg + (size_t)z * NPTS * NPTS;
        int n0 = by * 128, m0 = bx * 128;
        const bf16* pAn = Xh + (size_t)n0 * ld;
        const bf16* pAm = Xh + (size_t)m0 * ld;
        const bf16* pLn = Xl + (size_t)n0 * ld;
        const bf16* pLm = Xl + (size_t)m0 * ld;
        St2 sA = ldStage(pAn, ld), sB = ldStage(pAm, ld);
        St2 sC = ldStage(pLn, ld), sD = ldStage(pLm, ld);
        stStage(Ah, sA); stStage(Bh, sB);
        stStage(Al, sC); stStage(Bl, sD);
        __syncthreads();
        int cur = 0;
        for (int k0 = 0; k0 < Kpad; k0 += 32) {
            bool more = (k0 + 32 < Kpad);
            if (more) {
                sA = ldStage(pAn + k0 + 32, ld);
                sB = ldStage(pAm + k0 + 32, ld);
                sC = ldStage(pLn + k0 + 32, ld);
                sD = ldStage(pLm + k0 + 32, ld);
            }
            v8bf ah[4], al[4];
#pragma unroll
            for (int mi = 0; mi < 4; mi++) {
                ah[mi] = ldf(Ah + cur * 4096, wr * 4 + mi, l);
                al[mi] = ldf(Al + cur * 4096, wr * 4 + mi, l);
            }
#pragma unroll
            for (int ni = 0; ni < 4; ni++) {
                v8bf bh = ldf(Bh + cur * 4096, wc * 4 + ni, l);
                v8bf bl = ldf(Bl + cur * 4096, wc * 4 + ni, l);
#pragma unroll
                for (int mi = 0; mi < 4; mi++) {
                    acc[mi][ni] = __builtin_amdgcn_mfma_f32_16x16x32_bf16(ah[mi], bh, acc[mi][ni], 0, 0, 0);
                    acc[mi][ni] = __builtin_amdgcn_mfma_f32_16x16x32_bf16(ah[mi], bl, acc[mi][ni], 0, 0, 0);
                    acc[mi][ni] = __builtin_amdgcn_mfma_f32_16x16x32_bf16(al[mi], bh, acc[mi][ni], 0, 0, 0);
                }
            }
            if (more) {
                stStage(Ah + (cur ^ 1) * 4096, sA); stStage(Bh + (cur ^ 1) * 4096, sB);
                stStage(Al + (cur ^ 1) * 4096, sC); stStage(Bl + (cur ^ 1) * 4096, sD);
            }
            __syncthreads();
            cur ^= 1;
        }
        int rb = n0 + wr * 64 + quad * 4;
        int cb = m0 + wc * 64 + col;
        int rloc = wr * 64 + quad * 4;       // row index within tile
        int cloc = wc * 64 + col;            // col index within tile
        float* Tt = (float*)smem;            // [128][TSTRIDE] f32, aliases dead staging
        float sm[4];
#pragma unroll
        for (int ni = 0; ni < 4; ni++) sm[ni] = sq[cb + ni * 16];
#pragma unroll
        for (int mi = 0; mi < 4; mi++) {
#pragma unroll
            for (int r = 0; r < 4; r++) {
                int row = rb + mi * 16 + r;
                float sn = sq[row];
#pragma unroll
                for (int ni = 0; ni < 4; ni++) {
                    float d = 2.f * acc[mi][ni][r] - sn - sm[ni];
                    D[(size_t)row * NPTS + cb + ni * 16] = d;
                    if (bx != by)
                        Tt[(cloc + ni * 16) * TSTRIDE + rloc + mi * 16 + r] = d;
                }
            }
        }
        if (bx != by) {                      // coalesced transposed write of the mirror
            __syncthreads();
            int t = threadIdx.x;
            int rl = t & 127, ch = t >> 7;
            float* Dm = D + (size_t)m0 * NPTS + n0;
#pragma unroll 4
            for (int it = 0; it < 64; it++) {
                int cl = it * 2 + ch;
                Dm[(size_t)cl * NPTS + rl] = Tt[cl * TSTRIDE + rl];
            }
        }
    } else {
        // ---- st tile: P[point m, weight-row n] over 2O cols ----
        int isf = *flag;
        int nCol = (2 * O) >> 7;
        int s = bi - 36;
        int n0 = (s % nCol) * 128;   // weight-row tile (over 2O)
        int m0 = (s / nCol) * 128;   // point tile (over 1024)
        int N2 = 2 * O;
        float* P = Pg + (size_t)z * NPTS * N2;
        const bf16* pXh = Xh + (size_t)m0 * ld;
        const bf16* pXl = Xl + (size_t)m0 * ld;
        const bf16* pWh = Whi + (size_t)n0 * Kpad;
        const bf16* pWl = Wlo + (size_t)n0 * Kpad;
        St2 sA = ldStage(pXh, ld), sC = ldStage(pXl, ld);
        St2 sB = ldStage(pWh, Kpad), sD;
        if (isf) sD = ldStage(pWl, Kpad);
        stStage(Ah, sA); stStage(Al, sC); stStage(Bh, sB);
        if (isf) stStage(Bl, sD);
        __syncthreads();
        int cur = 0;
        for (int k0 = 0; k0 < Kpad; k0 += 32) {
            bool more = (k0 + 32 < Kpad);
            if (more) {
                sA = ldStage(pXh + k0 + 32, ld);
                sC = ldStage(pXl + k0 + 32, ld);
                sB = ldStage(pWh + k0 + 32, Kpad);
                if (isf) sD = ldStage(pWl + k0 + 32, Kpad);
            }
            v8bf ah[4], al[4];
#pragma unroll
            for (int mi = 0; mi < 4; mi++) {
                ah[mi] = ldf(Ah + cur * 4096, wr * 4 + mi, l);
                al[mi] = ldf(Al + cur * 4096, wr * 4 + mi, l);
            }
#pragma unroll
            for (int ni = 0; ni < 4; ni++) {
                v8bf bh = ldf(Bh + cur * 4096, wc * 4 + ni, l);
#pragma unroll
                for (int mi = 0; mi < 4; mi++) {
                    acc[mi][ni] = __builtin_amdgcn_mfma_f32_16x16x32_bf16(ah[mi], bh, acc[mi][ni], 0, 0, 0);
                    acc[mi][ni] = __builtin_amdgcn_mfma_f32_16x16x32_bf16(al[mi], bh, acc[mi][ni], 0, 0, 0);
                }
                if (isf) {
                    v8bf bl = ldf(Bl + cur * 4096, wc * 4 + ni, l);
#pragma unroll
                    for (int mi = 0; mi < 4; mi++)
                        acc[mi][ni] = __builtin_amdgcn_mfma_f32_16x16x32_bf16(ah[mi], bl, acc[mi][ni], 0, 0, 0);
                }
            }
            if (more) {
                stStage(Ah + (cur ^ 1) * 4096, sA); stStage(Al + (cur ^ 1) * 4096, sC);
                stStage(Bh + (cur ^ 1) * 4096, sB);
                if (isf) stStage(Bl + (cur ^ 1) * 4096, sD);
            }
            __syncthreads();
            cur ^= 1;
        }
        int rb = m0 + wr * 64 + quad * 4;
        int cb = n0 + wc * 64 + col;
#pragma unroll
        for (int mi = 0; mi < 4; mi++)
#pragma unroll
            for (int r = 0; r < 4; r++) {
                int row = rb + mi * 16 + r;
#pragma unroll
                for (int ni = 0; ni < 4; ni++)
                    P[(size_t)row * N2 + cb + ni * 16] = acc[mi][ni][r];
            }
    }
}

// ---- argmax combine via DPP (VALU pipe, ~5cy/step vs ~100cy ds_swizzle) ----
// (max val, min idx) is a total-order max: associative+commutative+idempotent, so any
// full-coverage mixing converges to the unique winner. update_dpp(old=self,...) makes
// non-receiving lanes self-combine (no-op).
template<int CTRL>
__device__ __forceinline__ void dpp_step(float& bv, int& bi) {
    int ov_i = __builtin_amdgcn_update_dpp(__float_as_int(bv), __float_as_int(bv), CTRL, 0xF, 0xF, false);
    int oi   = __builtin_amdgcn_update_dpp(bi, bi, CTRL, 0xF, 0xF, false);
    float ov = __int_as_float(ov_i);
    if (ov > bv || (ov == bv && oi < bi)) { bv = ov; bi = oi; }
}
#define PICK(va, ja, vb, jb, vo, jo) { bool t_ = (vb) > (va); vo = t_ ? (vb) : (va); jo = t_ ? (jb) : (ja); }

// ---------------- fused stage B: top-20 + gather-max, WAVE-PER-ROW end-to-end ----------------
// 1D grid 1024, XCD-pinned: z = (i>>1)&3, local = ((i>>3)<<1)|(i&1); wave q owns row local*4+q.
// Selection butterfly entirely on DPP: quad xor1/xor2 + row_ror4/8 (16-lane converge, all lanes)
// + row_bcast15 + row_bcast31 (lane 63 = full 64-lane winner) + readlane(63) -> SGPR broadcast.
__global__ __launch_bounds__(256) void k_layer_b(const float* __restrict__ Dg, const float* __restrict__ Pg,
                                                 const void* __restrict__ g, const void* __restrict__ bias,
                                                 int O, bf16* __restrict__ xhOut, bf16* __restrict__ xlOut,
                                                 float* __restrict__ sqOut, int writeSq,
                                                 const int* __restrict__ flag) {
    __shared__ int ids[4][20];
    int isf = *flag;
    int i = blockIdx.x;
    int z = (i >> 1) & 3;
    int local = ((i >> 3) << 1) | (i & 1);
    int tid = threadIdx.x;
    int wq = tid >> 6, l = tid & 63;
    int row = local * 4 + wq;

    // ---- per-wave register-resident top-20 (lane->index map bi = jj*256+l*4+q bijective
    //      over [0,1024), monotone per lane in scan order -> min-index tie-break) ----
    {
        const float* Dr = Dg + (size_t)z * NPTS * NPTS + (size_t)row * NPTS;
        float v[16];
#pragma unroll
        for (int jj = 0; jj < 4; jj++) {
            float4 f4 = *(const float4*)(Dr + jj * 256 + l * 4);
            v[jj * 4 + 0] = f4.x; v[jj * 4 + 1] = f4.y;
            v[jj * 4 + 2] = f4.z; v[jj * 4 + 3] = f4.w;
        }
        float bmv[4]; int bmj[4];
#pragma unroll
        for (int gg = 0; gg < 4; gg++) {
            float a0, a1; int j0, j1;
            PICK(v[4 * gg + 0], 4 * gg + 0, v[4 * gg + 1], 4 * gg + 1, a0, j0);
            PICK(v[4 * gg + 2], 4 * gg + 2, v[4 * gg + 3], 4 * gg + 3, a1, j1);
            PICK(a0, j0, a1, j1, bmv[gg], bmj[gg]);
        }
        for (int s = 0; s < 20; s++) {
            float t0, t1, bv; int s0, s1, bj;
            PICK(bmv[0], bmj[0], bmv[1], bmj[1], t0, s0);
            PICK(bmv[2], bmj[2], bmv[3], bmj[3], t1, s1);
            PICK(t0, s0, t1, s1, bv, bj);
            int bi = (bj >> 2) * 256 + l * 4 + (bj & 3);
            dpp_step<0xB1>(bv, bi);    // quad_perm [1,0,3,2] = xor1
            dpp_step<0x4E>(bv, bi);    // quad_perm [2,3,0,1] = xor2
            dpp_step<0x124>(bv, bi);   // row_ror:4
            dpp_step<0x128>(bv, bi);   // row_ror:8  -> every lane has its 16-row winner
            dpp_step<0x142>(bv, bi);   // row_bcast15: row r combines row r-1's max
            dpp_step<0x143>(bv, bi);   // row_bcast31: lanes32-63 combine rows01 -> lane63 global
            int bii = __builtin_amdgcn_readlane(bi, 63);   // SGPR broadcast of winner idx
            if (l == 0) ids[wq][s] = bii;
            if (((bii >> 2) & 63) == l) {  // owning lane: evict + rebuild its group
                int ej = (bii >> 8) * 4 + (bii & 3);
                int eg = ej >> 2, ek = ej & 3;
#pragma unroll
                for (int gg = 0; gg < 4; gg++) if (gg == eg) {
#pragma unroll
                    for (int kk = 0; kk < 4; kk++)
                        if (kk == ek) v[4 * gg + kk] = -__builtin_inff();
                    float a0, a1; int j0, j1;
                    PICK(v[4 * gg + 0], 4 * gg + 0, v[4 * gg + 1], 4 * gg + 1, a0, j0);
                    PICK(v[4 * gg + 2], 4 * gg + 2, v[4 * gg + 3], 4 * gg + 3, a1, j1);
                    PICK(a0, j0, a1, j1, bmv[gg], bmj[gg]);
                }
            }
        }
    }

    // ---- gather + max for THIS wave's row (affine/lrelu AFTER max: exact FP-monotone commute) ----
    int N2 = 2 * O;
    const float* P = Pg + (size_t)z * NPTS * N2;
    int offj[20];
#pragma unroll
    for (int j = 0; j < 20; j++)
        offj[j] = __builtin_amdgcn_readfirstlane(ids[wq][j]) * N2;  // SGPR row bases
    int n = row;
    const float* Pn = P + (size_t)n * N2;
    float tot = 0.f;
    int nc = O >> 6;
    for (int c = 0; c < nc; c++) {
        int o = c * 64 + l;
        float tv = Pn[O + o] - Pn[o];
        float mx = -__builtin_inff(), mn = __builtin_inff();
#pragma unroll
        for (int j = 0; j < 20; j++) {
            float vv = P[offj[j] + o];
            mx = fmaxf(mx, vv);
            mn = fminf(mn, vv);
        }
        float scl = ldw(g, o, isf) * BN_SCALE;
        float bb = ldw(bias, o, isf);
        float base = (scl >= 0.f ? mx : mn) + tv;
        float accv = base * scl + bb;
        accv = accv > 0.f ? accv : 0.2f * accv;
        bf16 hi = f2b(accv);
        bf16 lo = f2b(accv - b2f(hi));
        xhOut[(size_t)z * NPTS * 960 + (size_t)n * 960 + o] = hi;
        xlOut[(size_t)z * NPTS * 960 + (size_t)n * 960 + o] = lo;
        if (writeSq) {
            float xv = b2f(hi) + b2f(lo);
            float s2 = xv * xv;
#pragma unroll
            for (int off = 32; off > 0; off >>= 1) s2 += __shfl_down(s2, off);
            if (l == 0) tot += s2;       // ascending chunk order: same serial FP sum as before
        }
    }
    if (writeSq && l == 0) sqOut[z * NPTS + row] = tot;
}

// ---------------- conv5 via MFMA, K-split x6 (chunks of 160) -> f32 partials ----------------
// 1D grid 768, XCD-pinned: z=(i>>1)&3, rest=((i>>3)<<1)|(i&1) in [0,192):
//   ks = rest>>5 (K-chunk), tile = rest&31: m0=(tile>>2)*128, o0=(tile&3)*128
__global__ __launch_bounds__(256) void k_conv5(const bf16* __restrict__ Xhi, const bf16* __restrict__ Xlo,
                                               const bf16* __restrict__ Whi, const bf16* __restrict__ Wlo,
                                               float* __restrict__ P5,
                                               const int* __restrict__ flag) {
    int isf = *flag;
    int i = blockIdx.x;
    int z = (i >> 1) & 3;
    int rest = ((i >> 3) << 1) | (i & 1);
    int ks = rest >> 5;
    int tile = rest & 31;
    int m0 = (tile >> 2) * 128, o0 = (tile & 3) * 128;
    const bf16* Xh = Xhi + (size_t)z * NPTS * 960;
    const bf16* Xl = Xlo + (size_t)z * NPTS * 960;
    __shared__ alignas(16) bf16 Ah[4096], Al[4096], Bh[4096], Bl[4096];
    int w = threadIdx.x >> 6, l = threadIdx.x & 63;
    int wr = w >> 1, wc = w & 1;
    int quad = l >> 4, col = l & 15;
    v4f zero = {0.f, 0.f, 0.f, 0.f};
    v4f acc[4][4] = {{zero, zero, zero, zero}, {zero, zero, zero, zero},
                     {zero, zero, zero, zero}, {zero, zero, zero, zero}};
    int kbeg = ks * 160, kend = kbeg + 160;
    for (int k0 = kbeg; k0 < kend; k0 += 32) {
        __syncthreads();
        fill128(Ah, Xh + (size_t)m0 * 960 + k0, 960);
        fill128(Al, Xl + (size_t)m0 * 960 + k0, 960);
        fill128(Bh, Whi + (size_t)o0 * 960 + k0, 960);
        if (isf) fill128(Bl, Wlo + (size_t)o0 * 960 + k0, 960);
        __syncthreads();
        v8bf ah[4], al[4];
#pragma unroll
        for (int mi = 0; mi < 4; mi++) {
            ah[mi] = ldf(Ah, wr * 4 + mi, l);
            al[mi] = ldf(Al, wr * 4 + mi, l);
        }
#pragma unroll
        for (int ni = 0; ni < 4; ni++) {
            v8bf bh = ldf(Bh, wc * 4 + ni, l);
#pragma unroll
            for (int mi = 0; mi < 4; mi++) {
                acc[mi][ni] = __builtin_amdgcn_mfma_f32_16x16x32_bf16(ah[mi], bh, acc[mi][ni], 0, 0, 0);
                acc[mi][ni] = __builtin_amdgcn_mfma_f32_16x16x32_bf16(al[mi], bh, acc[mi][ni], 0, 0, 0);
            }
            if (isf) {
                v8bf bl = ldf(Bl, wc * 4 + ni, l);
#pragma unroll
                for (int mi = 0; mi < 4; mi++)
                    acc[mi][ni] = __builtin_amdgcn_mfma_f32_16x16x32_bf16(ah[mi], bl, acc[mi][ni], 0, 0, 0);
            }
        }
    }
    // write f32 partial tile (disjoint per (ks,z,tile) -> no atomics)
    float* Pw = P5 + (size_t)ks * CH5 + (size_t)z * NPTS * 512;
    int rb = m0 + wr * 64 + quad * 4;
    int cb = o0 + wc * 64 + col;
#pragma unroll
    for (int mi = 0; mi < 4; mi++)
#pragma unroll
        for (int r = 0; r < 4; r++) {
            int row = rb + mi * 16 + r;
#pragma unroll
            for (int ni = 0; ni < 4; ni++)
                Pw[(size_t)row * 512 + cb + ni * 16] = acc[mi][ni][r];
        }
}

// ---------------- pool5: sum 6 K-chunks + affine + lrelu + max over rows -> pooled ----------------
// 1D grid 512, XCD-pinned: z=(i>>1)&3, rest=((i>>3)<<1)|(i&1) in [0,128):
//   oc=(rest&3)*128 cols, mc=(rest>>2)*32 rows; thread: col=t&127, half=t>>7 (16 rows each)
__global__ __launch_bounds__(256) void k_pool5(const float* __restrict__ P5,
                                               const void* __restrict__ g, const void* __restrict__ bias,
                                               unsigned* __restrict__ pooledU,
                                               const int* __restrict__ flag) {
    __shared__ float red2[128];
    int isf = *flag;
    int i = blockIdx.x;
    int z = (i >> 1) & 3;
    int rest = ((i >> 3) << 1) | (i & 1);
    int oc = (rest & 3) * 128, mc = (rest >> 2) * 32;
    int t = threadIdx.x;
    int c = t & 127, h = t >> 7;
    int o = oc + c;
    float scl = ldw(g, o, isf) * BN_SCALE;
    float bb = ldw(bias, o, isf);
    const float* p0 = P5 + (size_t)z * NPTS * 512 + (size_t)(mc + h * 16) * 512 + o;
    float ym = -__builtin_inff();
    for (int r = 0; r < 16; r++) {
        const float* p = p0 + (size_t)r * 512;
        float s = p[0];
#pragma unroll
        for (int ks = 1; ks < 6; ks++) s += p[(size_t)ks * CH5];
        float v = s * scl + bb;
        v = v > 0.f ? v : 0.2f * v;
        ym = fmaxf(ym, v);
    }
    if (h == 1) red2[c] = ym;
    __syncthreads();
    if (h == 0) {
        float m = fmaxf(ym, red2[c]);
        atomicMax(&pooledU[z * 512 + o], ordf(m));
    }
}

// ---------------- final linear: coalesced wave-per-output ----------------
__global__ void k_final(const unsigned* __restrict__ pooledU, const void* __restrict__ We,
                        void* __restrict__ out, const int* __restrict__ flag) {
    __shared__ float p[512];
    int isf = *flag;
    int b = blockIdx.x >> 2, fb = blockIdx.x & 3;
    int t = threadIdx.x, w = t >> 6, l = t & 63;
    for (int i = t; i < 512; i += 256) p[i] = iordf(pooledU[b * 512 + i]);
    __syncthreads();
    for (int it = 0; it < 16; it++) {
        int f = fb * 64 + w * 16 + it;
        float s = 0.f;
        size_t base = (size_t)f * 512 + l * 8;
#pragma unroll
        for (int j = 0; j < 8; j++) s += p[l * 8 + j] * ldw(We, base + j, isf);
#pragma unroll
        for (int off = 32; off > 0; off >>= 1) s += __shfl_down(s, off);
        if (l == 0) {
            if (isf) ((float*)out)[b * 256 + f] = s;
            else     ((bf16*)out)[b * 256 + f] = f2b(s);
        }
    }
}

extern "C" void kernel_launch(void* const* d_in, const int* in_sizes, int n_in,
                              void* d_out, int out_size, void* d_ws, size_t ws_size,
                              hipStream_t stream) {
    const void* x  = d_in[0];
    const void* Wl[4] = { d_in[1], d_in[4], d_in[7], d_in[10] };
    const void* gl[4] = { d_in[2], d_in[5], d_in[8], d_in[11] };
    const void* bl[4] = { d_in[3], d_in[6], d_in[9], d_in[12] };
    const void* W5 = d_in[13];
    const void* g5 = d_in[14];
    const void* b5 = d_in[15];
    const void* We = d_in[16];

    // workspace layout (bytes), ~103.9 MB total
    char* base = (char*)d_ws;
    bf16*     xc_hi   = (bf16*)(base);                  // 7,864,320
    bf16*     xc_lo   = (bf16*)(base + 7864320);        // 7,864,320
    bf16*     xpadh   = (bf16*)(base + 15728640);       // 262,144
    bf16*     xpadl   = (bf16*)(base + 15990784);       // 262,144
    float*    Dbuf    = (float*)(base + 16252928);      // 16,777,216
    float*    Pbuf    = (float*)(base + 33030144);      // 16,777,216
    bf16*     Whi     = (bf16*)(base + 49807360);       // 1,679,360
    bf16*     Wlo     = (bf16*)(base + 51486720);       // 1,679,360
    unsigned* pooledU = (unsigned*)(base + 53493760);   // 8,192
    float*    sq      = (float*)(base + 53501952);      // 16,384
    int*      flag    = (int*)(base + 53518336);        // 4
    float*    P5      = (float*)(base + 53520384);      // 50,331,648 (6 x 8 MB conv5 partials)

    const int Kpad[4]   = { 32, 64, 128, 256 };
    const int Os[4]     = { 64, 128, 256, 512 };
    const int Woff[5]   = { 0, 4096, 20480, 86016, 348160 };
    const int colIn[4]  = { 0, 0, 64, 192 };
    const int colOut[4] = { 0, 64, 192, 448 };

    k_prep<<<3296, 256, 0, stream>>>(Wl[0], Wl[1], Wl[2], Wl[3], W5, x,
                                     Whi, Wlo, xpadh, xpadl, sq, flag, pooledU);

    for (int l = 0; l < 4; l++) {
        int O = Os[l];
        int nCol = (2 * O) >> 7;
        int nBlk = 36 + 8 * nCol;  // 44/52/68/100 -> *4 divisible by 8 for XCD decode
        const bf16* Xh = (l == 0) ? xpadh : (xc_hi + colIn[l]);
        const bf16* Xl = (l == 0) ? xpadl : (xc_lo + colIn[l]);
        int ld = (l == 0) ? 32 : 960;
        size_t xstr = (l == 0) ? (size_t)NPTS * 32 : (size_t)NPTS * 960;
        k_layer_a<<<nBlk * NB, 256, 0, stream>>>(
            Xh, Xl, ld, Kpad[l], xstr, Whi + Woff[l], Wlo + Woff[l], O, sq, Dbuf, Pbuf, flag);
        k_layer_b<<<NPTS * NB / 4, 256, 0, stream>>>(
            Dbuf, Pbuf, gl[l], bl[l], O, xc_hi + colOut[l], xc_lo + colOut[l], sq, l < 3, flag);
    }
    k_conv5<<<768, 256, 0, stream>>>(xc_hi, xc_lo, Whi + Woff[4], Wlo + Woff[4], P5, flag);
    k_pool5<<<512, 256, 0, stream>>>(P5, g5, b5, pooledU, flag);
    k_final<<<16, 256, 0, stream>>>(pooledU, We, d_out, flag);
}